// Round 2
// baseline (761.725 us; speedup 1.0000x reference)
//
#include <hip/hip_runtime.h>
#include <hip/hip_bf16.h>

// Problem constants (ConceptGNN): V nodes, D emb dim, G hidden, E edges, B*S word ids.
#define NV 50000
#define ND 300
#define NG 256
#define NE 1600000
#define NBS 4096  // B*S = 64*64

// ---------------- histogram of dst (in-degree) ----------------
__global__ __launch_bounds__(256) void hist_kernel(const int* __restrict__ dst,
                                                   int* __restrict__ deg) {
    int i = blockIdx.x * blockDim.x + threadIdx.x;
    if (i < NE) atomicAdd(&deg[dst[i]], 1);
}

// ---------------- exclusive scan of deg -> off/cursor, inv_sqrt ----------------
__global__ __launch_bounds__(1024) void scan_kernel(const int* __restrict__ deg,
                                                    int* __restrict__ off,
                                                    int* __restrict__ cursor,
                                                    float* __restrict__ inv_sqrt) {
    const int T = 1024;
    const int CH = (NV + T - 1) / T;  // 49
    int t = threadIdx.x;
    int begin = t * CH;
    int end = begin + CH; if (end > NV) end = NV;
    int sum = 0;
    for (int i = begin; i < end; ++i) sum += deg[i];
    __shared__ int s[T];
    s[t] = sum;
    __syncthreads();
    for (int d = 1; d < T; d <<= 1) {
        int v = (t >= d) ? s[t - d] : 0;
        __syncthreads();
        s[t] += v;
        __syncthreads();
    }
    int run = s[t] - sum;  // exclusive prefix of this thread's chunk
    for (int i = begin; i < end; ++i) {
        int dv = deg[i];
        off[i] = run;
        cursor[i] = run;
        inv_sqrt[i] = rsqrtf((float)(dv + 1));  // deg = 1 (self loop) + in-degree
        run += dv;
    }
    if (t == 0) off[NV] = NE;
}

// ---------------- CSR build (counting-sort placement) ----------------
__global__ __launch_bounds__(256) void csr_kernel(const int* __restrict__ ei,
                                                  const float* __restrict__ inv_sqrt,
                                                  int* __restrict__ cursor,
                                                  int* __restrict__ csr_src,
                                                  float* __restrict__ csr_w) {
    int i = blockIdx.x * blockDim.x + threadIdx.x;
    if (i >= NE) return;
    int s = ei[i];        // src row of edge_index
    int d = ei[NE + i];   // dst row
    int pos = atomicAdd(&cursor[d], 1);
    csr_src[pos] = s;
    csr_w[pos] = inv_sqrt[s];
}

// ---------------- fp32 tiled GEMM: C[M x N] = A[M x K] * B[K x N] ----------------
#define BM 64
#define BN 64
#define BK 16
__global__ __launch_bounds__(256) void gemm_kernel(const float* __restrict__ A,
                                                   const float* __restrict__ Bm,
                                                   float* __restrict__ C,
                                                   int M, int K, int N) {
    __shared__ float As[BK][BM];
    __shared__ float Bs[BK][BN];
    int t = threadIdx.x;
    int bm = blockIdx.x * BM;
    int bn = blockIdx.y * BN;
    int tx = t & 15, ty = t >> 4;
    float acc[4][4] = {};
    for (int k0 = 0; k0 < K; k0 += BK) {
        // A tile: 64 rows x 16 k; thread t loads float4 of row (t>>2), ks (t&3)*4
        {
            int r = t >> 2, kq = (t & 3) * 4;
            int gr = bm + r, gk = k0 + kq;
            float4 v = make_float4(0.f, 0.f, 0.f, 0.f);
            if (gr < M && gk < K)  // K%4==0 in all uses, so gk<K implies gk+3<K
                v = *(const float4*)(A + (size_t)gr * K + gk);
            As[kq + 0][r] = v.x;
            As[kq + 1][r] = v.y;
            As[kq + 2][r] = v.z;
            As[kq + 3][r] = v.w;
        }
        // B tile: 16 k x 64 n; thread t loads float4 of k (t>>4), ns (t&15)*4
        {
            int kr = t >> 4, nq = (t & 15) * 4;
            int gk = k0 + kr, gn = bn + nq;
            float4 v = make_float4(0.f, 0.f, 0.f, 0.f);
            if (gk < K) v = *(const float4*)(Bm + (size_t)gk * N + gn);
            *(float4*)(&Bs[kr][nq]) = v;
        }
        __syncthreads();
#pragma unroll
        for (int kk = 0; kk < BK; ++kk) {
            float a[4], b[4];
            *(float4*)a = *(const float4*)(&As[kk][ty * 4]);
            *(float4*)b = *(const float4*)(&Bs[kk][tx * 4]);
#pragma unroll
            for (int i = 0; i < 4; ++i)
#pragma unroll
                for (int j = 0; j < 4; ++j) acc[i][j] += a[i] * b[j];
        }
        __syncthreads();
    }
#pragma unroll
    for (int i = 0; i < 4; ++i) {
        int gr = bm + ty * 4 + i;
        if (gr < M) {
            float4 v = make_float4(acc[i][0], acc[i][1], acc[i][2], acc[i][3]);
            *(float4*)(C + (size_t)gr * N + bn + tx * 4) = v;
        }
    }
}

// ---------------- layer-1 aggregation + bias + ReLU (all nodes) ----------------
__global__ __launch_bounds__(256) void agg1_kernel(const float* __restrict__ h1,
                                                   const int* __restrict__ off,
                                                   const int* __restrict__ csr_src,
                                                   const float* __restrict__ csr_w,
                                                   const float* __restrict__ inv_sqrt,
                                                   const float* __restrict__ b1,
                                                   float* __restrict__ x1) {
    int i = blockIdx.x;
    int c = threadIdx.x;
    int s0 = off[i], s1 = off[i + 1];
    float acc = 0.f;
    int j = s0;
    for (; j + 4 <= s1; j += 4) {
        int sA = csr_src[j], sB = csr_src[j + 1], sC = csr_src[j + 2], sD = csr_src[j + 3];
        float wA = csr_w[j], wB = csr_w[j + 1], wC = csr_w[j + 2], wD = csr_w[j + 3];
        float vA = h1[(size_t)sA * NG + c];
        float vB = h1[(size_t)sB * NG + c];
        float vC = h1[(size_t)sC * NG + c];
        float vD = h1[(size_t)sD * NG + c];
        acc += wA * vA;
        acc += wB * vB;
        acc += wC * vC;
        acc += wD * vD;
    }
    for (; j < s1; ++j) acc += csr_w[j] * h1[(size_t)csr_src[j] * NG + c];
    float is = inv_sqrt[i];
    float v = is * acc + h1[(size_t)i * NG + c] * (is * is) + b1[c];
    x1[(size_t)i * NG + c] = fmaxf(v, 0.f);
}

// ---------------- layer-2 aggregation + bias, only word_id nodes, fp32 out ----------------
__global__ __launch_bounds__(256) void agg2_kernel(const float* __restrict__ h2,
                                                   const int* __restrict__ off,
                                                   const int* __restrict__ csr_src,
                                                   const float* __restrict__ csr_w,
                                                   const float* __restrict__ inv_sqrt,
                                                   const float* __restrict__ b2,
                                                   const int* __restrict__ word_ids,
                                                   float* __restrict__ out) {
    int p = blockIdx.x;
    int n = word_ids[p];
    int c = threadIdx.x;
    int s0 = off[n], s1 = off[n + 1];
    float acc = 0.f;
    int j = s0;
    for (; j + 4 <= s1; j += 4) {
        int sA = csr_src[j], sB = csr_src[j + 1], sC = csr_src[j + 2], sD = csr_src[j + 3];
        float wA = csr_w[j], wB = csr_w[j + 1], wC = csr_w[j + 2], wD = csr_w[j + 3];
        float vA = h2[(size_t)sA * NG + c];
        float vB = h2[(size_t)sB * NG + c];
        float vC = h2[(size_t)sC * NG + c];
        float vD = h2[(size_t)sD * NG + c];
        acc += wA * vA;
        acc += wB * vB;
        acc += wC * vC;
        acc += wD * vD;
    }
    for (; j < s1; ++j) acc += csr_w[j] * h2[(size_t)csr_src[j] * NG + c];
    float is = inv_sqrt[n];
    float v = is * acc + h2[(size_t)n * NG + c] * (is * is) + b2[c];
    out[(size_t)p * NG + c] = v;
}

extern "C" void kernel_launch(void* const* d_in, const int* in_sizes, int n_in,
                              void* d_out, int out_size, void* d_ws, size_t ws_size,
                              hipStream_t stream) {
    const float* emb = (const float*)d_in[0];       // V x D
    const float* W1  = (const float*)d_in[1];       // D x G
    const float* b1  = (const float*)d_in[2];       // G
    const float* W2  = (const float*)d_in[3];       // G x G
    const float* b2  = (const float*)d_in[4];       // G
    const int*   ei  = (const int*)d_in[5];         // 2 x E (row0 src, row1 dst)
    const int*   wid = (const int*)d_in[6];         // B x S
    float* out = (float*)d_out;

    // workspace carve-up
    char* w = (char*)d_ws;
    auto alloc = [&](size_t bytes) {
        void* p = (void*)w;
        w += (bytes + 255) & ~(size_t)255;
        return p;
    };
    int*   deg      = (int*)alloc((size_t)NV * 4);
    int*   off      = (int*)alloc((size_t)(NV + 1) * 4);
    int*   cursor   = (int*)alloc((size_t)NV * 4);
    float* inv_sqrt = (float*)alloc((size_t)NV * 4);
    int*   csr_src  = (int*)alloc((size_t)NE * 4);
    float* csr_w    = (float*)alloc((size_t)NE * 4);
    float* h1       = (float*)alloc((size_t)NV * NG * 4);  // reused as h2 after agg1
    float* x1       = (float*)alloc((size_t)NV * NG * 4);

    hipMemsetAsync(deg, 0, (size_t)NV * 4, stream);

    hist_kernel<<<(NE + 255) / 256, 256, 0, stream>>>(ei + NE, deg);
    scan_kernel<<<1, 1024, 0, stream>>>(deg, off, cursor, inv_sqrt);
    csr_kernel<<<(NE + 255) / 256, 256, 0, stream>>>(ei, inv_sqrt, cursor, csr_src, csr_w);

    // h1 = emb @ W1
    {
        dim3 grid((NV + BM - 1) / BM, NG / BN);
        gemm_kernel<<<grid, 256, 0, stream>>>(emb, W1, h1, NV, ND, NG);
    }
    // x1 = relu(norm-agg(h1) + b1)
    agg1_kernel<<<NV, 256, 0, stream>>>(h1, off, csr_src, csr_w, inv_sqrt, b1, x1);
    // h2 = x1 @ W2  (into h1 buffer)
    {
        dim3 grid((NV + BM - 1) / BM, NG / BN);
        gemm_kernel<<<grid, 256, 0, stream>>>(x1, W2, h1, NV, NG, NG);
    }
    // out = (norm-agg(h2) + b2)[word_ids]  -> fp32
    agg2_kernel<<<NBS, 256, 0, stream>>>(h1, off, csr_src, csr_w, inv_sqrt, b2, wid, out);
}

// Round 3
// 621.893 us; speedup vs baseline: 1.2248x; 1.2248x over previous
//
#include <hip/hip_runtime.h>
#include <hip/hip_bf16.h>

#define NV 50000
#define ND 300
#define NDP 320      // K of layer-1 padded to multiple of 32
#define NG 256
#define NE 1600000
#define NBS 4096     // B*S

typedef short short8 __attribute__((ext_vector_type(8)));
typedef float f32x4 __attribute__((ext_vector_type(4)));
typedef _Float16 half4 __attribute__((ext_vector_type(4)));

__device__ __forceinline__ ushort f2bf(float f) {
    unsigned u = __builtin_bit_cast(unsigned, f);
    unsigned r = (u + 0x7fffu + ((u >> 16) & 1u)) >> 16;
    return (ushort)r;
}
__device__ __forceinline__ float bf2f(ushort h) {
    unsigned u = ((unsigned)h) << 16;
    return __builtin_bit_cast(float, u);
}

// ---------------- histogram of dst (in-degree), int4 loads ----------------
__global__ __launch_bounds__(256) void hist_kernel(const int* __restrict__ dst,
                                                   int* __restrict__ deg) {
    int i = blockIdx.x * blockDim.x + threadIdx.x;
    if (i * 4 >= NE) return;
    int4 d = *(const int4*)(dst + i * 4);
    atomicAdd(&deg[d.x], 1);
    atomicAdd(&deg[d.y], 1);
    atomicAdd(&deg[d.z], 1);
    atomicAdd(&deg[d.w], 1);
}

// ---------------- exclusive scan of deg -> off/cursor, inv_sqrt ----------------
__global__ __launch_bounds__(1024) void scan_kernel(const int* __restrict__ deg,
                                                    int* __restrict__ off,
                                                    int* __restrict__ cursor,
                                                    float* __restrict__ inv_sqrt) {
    const int T = 1024;
    const int CH = (NV + T - 1) / T;  // 49
    int t = threadIdx.x;
    int begin = t * CH;
    int end = begin + CH; if (end > NV) end = NV;
    int sum = 0;
    for (int i = begin; i < end; ++i) sum += deg[i];
    __shared__ int s[T];
    s[t] = sum;
    __syncthreads();
    for (int d = 1; d < T; d <<= 1) {
        int v = (t >= d) ? s[t - d] : 0;
        __syncthreads();
        s[t] += v;
        __syncthreads();
    }
    int run = s[t] - sum;
    for (int i = begin; i < end; ++i) {
        int dv = deg[i];
        off[i] = run;
        cursor[i] = run;
        inv_sqrt[i] = rsqrtf((float)(dv + 1));  // deg = 1 (self loop) + in-degree
        run += dv;
    }
    if (t == 0) off[NV] = NE;
}

// ---------------- CSR build (counting-sort placement) ----------------
__global__ __launch_bounds__(256) void csr_kernel(const int* __restrict__ ei,
                                                  const float* __restrict__ inv_sqrt,
                                                  int* __restrict__ cursor,
                                                  int* __restrict__ csr_src,
                                                  float* __restrict__ csr_w) {
    int i = blockIdx.x * blockDim.x + threadIdx.x;
    if (i >= NE) return;
    int s = ei[i];
    int d = ei[NE + i];
    int pos = atomicAdd(&cursor[d], 1);
    csr_src[pos] = s;
    csr_w[pos] = inv_sqrt[s];
}

// ---------------- W (K x N) -> W^T hi/lo bf16 [N][ldk], zero-padded ----------------
__global__ __launch_bounds__(256) void splitw_kernel(const float* __restrict__ W,
                                                     int K, int N, int ldk,
                                                     ushort* __restrict__ Th,
                                                     ushort* __restrict__ Tl) {
    int idx = blockIdx.x * 256 + threadIdx.x;
    if (idx >= N * ldk) return;
    int n = idx / ldk, k = idx - n * ldk;
    float v = (k < K) ? W[(size_t)k * N + n] : 0.f;
    ushort h = f2bf(v);
    Th[idx] = h;
    Tl[idx] = f2bf(v - bf2f(h));
}

// ---------------- split-bf16 MFMA GEMM: C[M x NG](fp16) = A[M x K] * B[K x NG] ----
// B given pre-transposed+split: BTh/BTl = bf16 [NG][ldb] (k contiguous, zero-padded).
// A either fp32 [M][lda] (A_FP32) or pre-split bf16 pair Ah_g/Al_g [M][lda].
template <bool A_FP32>
__global__ __launch_bounds__(256) void gemm_mfma(const float* __restrict__ A,
                                                 const ushort* __restrict__ Ah_g,
                                                 const ushort* __restrict__ Al_g,
                                                 int lda,
                                                 const ushort* __restrict__ BTh,
                                                 const ushort* __restrict__ BTl,
                                                 int ldb,
                                                 int M, int K, int KP,
                                                 _Float16* __restrict__ C) {
    __shared__ short Ah[64][40];
    __shared__ short Al[64][40];
    __shared__ short Bh[64][40];
    __shared__ short Bl[64][40];
    int t = threadIdx.x;
    int bm = blockIdx.x * 64;
    int bn = blockIdx.y * 64;
    int lane = t & 63, wv = t >> 6;
    int sr = t >> 2;           // staging row 0..63
    int skq = (t & 3) * 8;     // staging k offset {0,8,16,24}
    f32x4 acc[4];
#pragma unroll
    for (int f = 0; f < 4; ++f) acc[f] = (f32x4)0.0f;

    for (int k0 = 0; k0 < KP; k0 += 32) {
        int gr = bm + sr, gk = k0 + skq;
        // ---- stage A tile (64 x 32) as hi/lo bf16 ----
        short8 vah, val;
        if (A_FP32) {
            float v[8];
            if (gr < M) {
                if (gk + 8 <= K) {
                    float4 p0 = *(const float4*)(A + (size_t)gr * lda + gk);
                    float4 p1 = *(const float4*)(A + (size_t)gr * lda + gk + 4);
                    v[0] = p0.x; v[1] = p0.y; v[2] = p0.z; v[3] = p0.w;
                    v[4] = p1.x; v[5] = p1.y; v[6] = p1.z; v[7] = p1.w;
                } else {
#pragma unroll
                    for (int e = 0; e < 8; ++e)
                        v[e] = (gk + e < K) ? A[(size_t)gr * lda + gk + e] : 0.f;
                }
            } else {
#pragma unroll
                for (int e = 0; e < 8; ++e) v[e] = 0.f;
            }
#pragma unroll
            for (int e = 0; e < 8; ++e) {
                ushort h = f2bf(v[e]);
                vah[e] = (short)h;
                val[e] = (short)f2bf(v[e] - bf2f(h));
            }
        } else {
            if (gr < M) {
                vah = *(const short8*)(Ah_g + (size_t)gr * lda + gk);
                val = *(const short8*)(Al_g + (size_t)gr * lda + gk);
            } else {
                vah = (short8)0;
                val = (short8)0;
            }
        }
        *(short8*)&Ah[sr][skq] = vah;
        *(short8*)&Al[sr][skq] = val;
        // ---- stage B tile (64 n x 32 k) straight copy (pre-transposed) ----
        {
            short8 bh = *(const short8*)(BTh + (size_t)(bn + sr) * ldb + gk);
            short8 bl = *(const short8*)(BTl + (size_t)(bn + sr) * ldb + gk);
            *(short8*)&Bh[sr][skq] = bh;
            *(short8*)&Bl[sr][skq] = bl;
        }
        __syncthreads();
        // ---- MFMA ----
        int m16 = lane & 15, kb = (lane >> 4) * 8;
        short8 a_h = *(const short8*)&Ah[wv * 16 + m16][kb];
        short8 a_l = *(const short8*)&Al[wv * 16 + m16][kb];
#pragma unroll
        for (int f = 0; f < 4; ++f) {
            short8 b_h = *(const short8*)&Bh[f * 16 + m16][kb];
            short8 b_l = *(const short8*)&Bl[f * 16 + m16][kb];
            acc[f] = __builtin_amdgcn_mfma_f32_16x16x32_bf16(a_h, b_h, acc[f], 0, 0, 0);
            acc[f] = __builtin_amdgcn_mfma_f32_16x16x32_bf16(a_h, b_l, acc[f], 0, 0, 0);
            acc[f] = __builtin_amdgcn_mfma_f32_16x16x32_bf16(a_l, b_h, acc[f], 0, 0, 0);
        }
        __syncthreads();
    }
    // ---- epilogue: C/D layout col=lane&15, row=(lane>>4)*4+reg ----
    int m16 = lane & 15, rq = lane >> 4;
#pragma unroll
    for (int f = 0; f < 4; ++f) {
#pragma unroll
        for (int r = 0; r < 4; ++r) {
            int row = bm + wv * 16 + rq * 4 + r;
            if (row < M) C[(size_t)row * NG + bn + f * 16 + m16] = (_Float16)acc[f][r];
        }
    }
}

// ---------------- layer-1 agg: wave per node, fp16 gather, bf16-split out ----------
__global__ __launch_bounds__(256) void agg1_kernel(const _Float16* __restrict__ h1h,
                                                   const int* __restrict__ off,
                                                   const int* __restrict__ csr_src,
                                                   const float* __restrict__ csr_w,
                                                   const float* __restrict__ inv_sqrt,
                                                   const float* __restrict__ b1,
                                                   ushort* __restrict__ x1h,
                                                   ushort* __restrict__ x1l) {
    int wv = threadIdx.x >> 6, lane = threadIdx.x & 63;
    int i = blockIdx.x * 4 + wv;
    if (i >= NV) return;
    int c4 = lane * 4;
    int s0 = off[i], s1 = off[i + 1];
    float a0 = 0.f, a1 = 0.f, a2 = 0.f, a3 = 0.f;
    for (int j = s0; j < s1; ++j) {
        int s = csr_src[j];
        float w = csr_w[j];
        half4 hv = *(const half4*)(h1h + (size_t)s * NG + c4);
        a0 += w * (float)hv[0];
        a1 += w * (float)hv[1];
        a2 += w * (float)hv[2];
        a3 += w * (float)hv[3];
    }
    float is = inv_sqrt[i], is2 = is * is;
    half4 sv = *(const half4*)(h1h + (size_t)i * NG + c4);
    float4 bb = *(const float4*)(b1 + c4);
    float v0 = fmaxf(is * a0 + (float)sv[0] * is2 + bb.x, 0.f);
    float v1 = fmaxf(is * a1 + (float)sv[1] * is2 + bb.y, 0.f);
    float v2 = fmaxf(is * a2 + (float)sv[2] * is2 + bb.z, 0.f);
    float v3 = fmaxf(is * a3 + (float)sv[3] * is2 + bb.w, 0.f);
    ushort4 hh, ll;
    hh.x = f2bf(v0); ll.x = f2bf(v0 - bf2f(hh.x));
    hh.y = f2bf(v1); ll.y = f2bf(v1 - bf2f(hh.y));
    hh.z = f2bf(v2); ll.z = f2bf(v2 - bf2f(hh.z));
    hh.w = f2bf(v3); ll.w = f2bf(v3 - bf2f(hh.w));
    *(ushort4*)(x1h + (size_t)i * NG + c4) = hh;
    *(ushort4*)(x1l + (size_t)i * NG + c4) = ll;
}

// ---------------- layer-2 agg: wave per word position, fp32 out ----------------
__global__ __launch_bounds__(256) void agg2_kernel(const _Float16* __restrict__ h2h,
                                                   const int* __restrict__ off,
                                                   const int* __restrict__ csr_src,
                                                   const float* __restrict__ csr_w,
                                                   const float* __restrict__ inv_sqrt,
                                                   const float* __restrict__ b2,
                                                   const int* __restrict__ word_ids,
                                                   float* __restrict__ out) {
    int wv = threadIdx.x >> 6, lane = threadIdx.x & 63;
    int p = blockIdx.x * 4 + wv;
    if (p >= NBS) return;
    int n = word_ids[p];
    int c4 = lane * 4;
    int s0 = off[n], s1 = off[n + 1];
    float a0 = 0.f, a1 = 0.f, a2 = 0.f, a3 = 0.f;
    for (int j = s0; j < s1; ++j) {
        int s = csr_src[j];
        float w = csr_w[j];
        half4 hv = *(const half4*)(h2h + (size_t)s * NG + c4);
        a0 += w * (float)hv[0];
        a1 += w * (float)hv[1];
        a2 += w * (float)hv[2];
        a3 += w * (float)hv[3];
    }
    float is = inv_sqrt[n], is2 = is * is;
    half4 sv = *(const half4*)(h2h + (size_t)n * NG + c4);
    float4 bb = *(const float4*)(b2 + c4);
    float4 o;
    o.x = is * a0 + (float)sv[0] * is2 + bb.x;
    o.y = is * a1 + (float)sv[1] * is2 + bb.y;
    o.z = is * a2 + (float)sv[2] * is2 + bb.z;
    o.w = is * a3 + (float)sv[3] * is2 + bb.w;
    *(float4*)(out + (size_t)p * NG + c4) = o;
}

extern "C" void kernel_launch(void* const* d_in, const int* in_sizes, int n_in,
                              void* d_out, int out_size, void* d_ws, size_t ws_size,
                              hipStream_t stream) {
    const float* emb = (const float*)d_in[0];       // V x D
    const float* W1  = (const float*)d_in[1];       // D x G
    const float* b1  = (const float*)d_in[2];       // G
    const float* W2  = (const float*)d_in[3];       // G x G
    const float* b2  = (const float*)d_in[4];       // G
    const int*   ei  = (const int*)d_in[5];         // 2 x E
    const int*   wid = (const int*)d_in[6];         // B x S
    float* out = (float*)d_out;

    char* w = (char*)d_ws;
    auto alloc = [&](size_t bytes) {
        void* p = (void*)w;
        w += (bytes + 255) & ~(size_t)255;
        return p;
    };
    int*    deg      = (int*)alloc((size_t)NV * 4);
    int*    off      = (int*)alloc((size_t)(NV + 1) * 4);
    int*    cursor   = (int*)alloc((size_t)NV * 4);
    float*  inv_sqrt = (float*)alloc((size_t)NV * 4);
    int*    csr_src  = (int*)alloc((size_t)NE * 4);
    float*  csr_w    = (float*)alloc((size_t)NE * 4);
    ushort* W1T_h    = (ushort*)alloc((size_t)NG * NDP * 2);
    ushort* W1T_l    = (ushort*)alloc((size_t)NG * NDP * 2);
    ushort* W2T_h    = (ushort*)alloc((size_t)NG * NG * 2);
    ushort* W2T_l    = (ushort*)alloc((size_t)NG * NG * 2);
    _Float16* h1h    = (_Float16*)alloc((size_t)NV * NG * 2);
    ushort* x1h      = (ushort*)alloc((size_t)NV * NG * 2);
    ushort* x1l      = (ushort*)alloc((size_t)NV * NG * 2);
    _Float16* h2h    = (_Float16*)alloc((size_t)NV * NG * 2);

    hipMemsetAsync(deg, 0, (size_t)NV * 4, stream);

    hist_kernel<<<(NE / 4 + 255) / 256, 256, 0, stream>>>(ei + NE, deg);
    scan_kernel<<<1, 1024, 0, stream>>>(deg, off, cursor, inv_sqrt);
    csr_kernel<<<(NE + 255) / 256, 256, 0, stream>>>(ei, inv_sqrt, cursor, csr_src, csr_w);

    splitw_kernel<<<(NG * NDP + 255) / 256, 256, 0, stream>>>(W1, ND, NG, NDP, W1T_h, W1T_l);
    splitw_kernel<<<(NG * NG + 255) / 256, 256, 0, stream>>>(W2, NG, NG, NG, W2T_h, W2T_l);

    // h1 = emb @ W1  (fp16 out)
    {
        dim3 grid((NV + 63) / 64, NG / 64);
        gemm_mfma<true><<<grid, 256, 0, stream>>>(emb, nullptr, nullptr, ND,
                                                  W1T_h, W1T_l, NDP, NV, ND, NDP, h1h);
    }
    // x1 = relu(norm-agg(h1) + b1)  (bf16 hi/lo out)
    agg1_kernel<<<(NV + 3) / 4, 256, 0, stream>>>(h1h, off, csr_src, csr_w, inv_sqrt, b1, x1h, x1l);
    // h2 = x1 @ W2  (fp16 out)
    {
        dim3 grid((NV + 63) / 64, NG / 64);
        gemm_mfma<false><<<grid, 256, 0, stream>>>(nullptr, x1h, x1l, NG,
                                                   W2T_h, W2T_l, NG, NV, NG, NG, h2h);
    }
    // out = (norm-agg(h2) + b2)[word_ids]  (fp32)
    agg2_kernel<<<(NBS + 3) / 4, 256, 0, stream>>>(h2h, off, csr_src, csr_w, inv_sqrt, b2, wid, out);
}

// Round 4
// 540.346 us; speedup vs baseline: 1.4097x; 1.1509x over previous
//
#include <hip/hip_runtime.h>
#include <hip/hip_bf16.h>

#define NV 50000
#define ND 300
#define NDP 320      // K of layer-1 padded to multiple of 32
#define NG 256
#define NE 1600000
#define NBS 4096     // B*S

typedef short short8 __attribute__((ext_vector_type(8)));
typedef float f32x4 __attribute__((ext_vector_type(4)));
typedef _Float16 half4 __attribute__((ext_vector_type(4)));

__device__ __forceinline__ ushort f2bf(float f) {
    unsigned u = __builtin_bit_cast(unsigned, f);
    unsigned r = (u + 0x7fffu + ((u >> 16) & 1u)) >> 16;
    return (ushort)r;
}
__device__ __forceinline__ float bf2f(ushort h) {
    unsigned u = ((unsigned)h) << 16;
    return __builtin_bit_cast(float, u);
}

// ---------------- histogram of dst (in-degree), int4 loads ----------------
__global__ __launch_bounds__(256) void hist_kernel(const int* __restrict__ dst,
                                                   int* __restrict__ deg) {
    int i = blockIdx.x * blockDim.x + threadIdx.x;
    if (i * 4 >= NE) return;
    int4 d = *(const int4*)(dst + i * 4);
    atomicAdd(&deg[d.x], 1);
    atomicAdd(&deg[d.y], 1);
    atomicAdd(&deg[d.z], 1);
    atomicAdd(&deg[d.w], 1);
}

// ---------------- exclusive scan of deg -> off/cursor, inv_sqrt ----------------
__global__ __launch_bounds__(1024) void scan_kernel(const int* __restrict__ deg,
                                                    int* __restrict__ off,
                                                    int* __restrict__ cursor,
                                                    float* __restrict__ inv_sqrt) {
    const int T = 1024;
    const int CH = (NV + T - 1) / T;  // 49
    int t = threadIdx.x;
    int begin = t * CH;
    int end = begin + CH; if (end > NV) end = NV;
    int sum = 0;
    for (int i = begin; i < end; ++i) sum += deg[i];
    __shared__ int s[T];
    s[t] = sum;
    __syncthreads();
    for (int d = 1; d < T; d <<= 1) {
        int v = (t >= d) ? s[t - d] : 0;
        __syncthreads();
        s[t] += v;
        __syncthreads();
    }
    int run = s[t] - sum;
    for (int i = begin; i < end; ++i) {
        int dv = deg[i];
        off[i] = run;
        cursor[i] = run;
        inv_sqrt[i] = rsqrtf((float)(dv + 1));  // deg = 1 (self loop) + in-degree
        run += dv;
    }
    if (t == 0) off[NV] = NE;
}

// ---------------- CSR build (counting-sort placement) ----------------
__global__ __launch_bounds__(256) void csr_kernel(const int* __restrict__ ei,
                                                  const float* __restrict__ inv_sqrt,
                                                  int* __restrict__ cursor,
                                                  int* __restrict__ csr_src,
                                                  float* __restrict__ csr_w) {
    int i = blockIdx.x * blockDim.x + threadIdx.x;
    if (i >= NE) return;
    int s = ei[i];
    int d = ei[NE + i];
    int pos = atomicAdd(&cursor[d], 1);
    csr_src[pos] = s;
    csr_w[pos] = inv_sqrt[s];
}

// ---------------- W (K x N) -> W^T hi/lo bf16 [N][ldk], zero-padded ----------------
__global__ __launch_bounds__(256) void splitw_kernel(const float* __restrict__ W,
                                                     int K, int N, int ldk,
                                                     ushort* __restrict__ Th,
                                                     ushort* __restrict__ Tl) {
    int idx = blockIdx.x * 256 + threadIdx.x;
    if (idx >= N * ldk) return;
    int n = idx / ldk, k = idx - n * ldk;
    float v = (k < K) ? W[(size_t)k * N + n] : 0.f;
    ushort h = f2bf(v);
    Th[idx] = h;
    Tl[idx] = f2bf(v - bf2f(h));
}

// ---- split-bf16 MFMA GEMM, 128x128 tile, 4 waves x (64x64 via 4x4 16x16 frags) ----
// C[M x NG](fp16) = A[M x K] * B[K x NG]
// B pre-transposed+split: BTh/BTl bf16 [NG][ldb] (k contiguous, zero-padded to KP).
// A: fp32 [M][lda] (A_FP32) or pre-split bf16 Ah_g/Al_g [M][lda].
template <bool A_FP32>
__global__ __launch_bounds__(256) void gemm_mfma(const float* __restrict__ A,
                                                 const ushort* __restrict__ Ah_g,
                                                 const ushort* __restrict__ Al_g,
                                                 int lda,
                                                 const ushort* __restrict__ BTh,
                                                 const ushort* __restrict__ BTl,
                                                 int ldb,
                                                 int M, int K, int KP,
                                                 _Float16* __restrict__ C) {
    __shared__ short Ah[128][40];
    __shared__ short Al[128][40];
    __shared__ short Bh[128][40];
    __shared__ short Bl[128][40];
    int t = threadIdx.x;
    int bm = blockIdx.x * 128;
    int bn = blockIdx.y * 128;
    int lane = t & 63, wv = t >> 6;
    int wm = (wv >> 1) * 64, wn = (wv & 1) * 64;
    int srow = t >> 1;          // staging row 0..127
    int skq = (t & 1) * 16;     // staging k offset {0,16}
    f32x4 acc[4][4];
#pragma unroll
    for (int mi = 0; mi < 4; ++mi)
#pragma unroll
        for (int ni = 0; ni < 4; ++ni) acc[mi][ni] = (f32x4)0.0f;

    for (int k0 = 0; k0 < KP; k0 += 32) {
        int gk = k0 + skq;
        // ---- stage A tile (128 rows x 32 k) as hi/lo bf16, 16 elems/thread ----
        {
            int gr = bm + srow;
            short8 vah[2], val[2];
            if (A_FP32) {
                float v[16];
                if (gr < M && gk < K) {
                    if (gk + 16 <= K) {
#pragma unroll
                        for (int q = 0; q < 4; ++q) {
                            float4 p = *(const float4*)(A + (size_t)gr * lda + gk + q * 4);
                            v[q * 4 + 0] = p.x; v[q * 4 + 1] = p.y;
                            v[q * 4 + 2] = p.z; v[q * 4 + 3] = p.w;
                        }
                    } else {
#pragma unroll
                        for (int e = 0; e < 16; ++e)
                            v[e] = (gk + e < K) ? A[(size_t)gr * lda + gk + e] : 0.f;
                    }
                } else {
#pragma unroll
                    for (int e = 0; e < 16; ++e) v[e] = 0.f;
                }
#pragma unroll
                for (int e = 0; e < 16; ++e) {
                    ushort h = f2bf(v[e]);
                    ((short*)vah)[e] = (short)h;
                    ((short*)val)[e] = (short)f2bf(v[e] - bf2f(h));
                }
            } else {
                if (gr < M) {
                    vah[0] = *(const short8*)(Ah_g + (size_t)gr * lda + gk);
                    vah[1] = *(const short8*)(Ah_g + (size_t)gr * lda + gk + 8);
                    val[0] = *(const short8*)(Al_g + (size_t)gr * lda + gk);
                    val[1] = *(const short8*)(Al_g + (size_t)gr * lda + gk + 8);
                } else {
                    vah[0] = (short8)0; vah[1] = (short8)0;
                    val[0] = (short8)0; val[1] = (short8)0;
                }
            }
            *(short8*)&Ah[srow][skq] = vah[0];
            *(short8*)&Ah[srow][skq + 8] = vah[1];
            *(short8*)&Al[srow][skq] = val[0];
            *(short8*)&Al[srow][skq + 8] = val[1];
        }
        // ---- stage B tile (128 n x 32 k), pre-transposed straight copy ----
        {
            int nr = bn + srow;  // < NG always (grid-y * 128 + 0..127)
            short8 bh0 = *(const short8*)(BTh + (size_t)nr * ldb + gk);
            short8 bh1 = *(const short8*)(BTh + (size_t)nr * ldb + gk + 8);
            short8 bl0 = *(const short8*)(BTl + (size_t)nr * ldb + gk);
            short8 bl1 = *(const short8*)(BTl + (size_t)nr * ldb + gk + 8);
            *(short8*)&Bh[srow][skq] = bh0;
            *(short8*)&Bh[srow][skq + 8] = bh1;
            *(short8*)&Bl[srow][skq] = bl0;
            *(short8*)&Bl[srow][skq + 8] = bl1;
        }
        __syncthreads();
        // ---- MFMA: 4x4 fragments, 3 split passes ----
        int m16 = lane & 15, kb = (lane >> 4) * 8;
        short8 a_h[4], a_l[4], b_h[4], b_l[4];
#pragma unroll
        for (int mi = 0; mi < 4; ++mi) {
            a_h[mi] = *(const short8*)&Ah[wm + mi * 16 + m16][kb];
            a_l[mi] = *(const short8*)&Al[wm + mi * 16 + m16][kb];
        }
#pragma unroll
        for (int ni = 0; ni < 4; ++ni) {
            b_h[ni] = *(const short8*)&Bh[wn + ni * 16 + m16][kb];
            b_l[ni] = *(const short8*)&Bl[wn + ni * 16 + m16][kb];
        }
#pragma unroll
        for (int mi = 0; mi < 4; ++mi)
#pragma unroll
            for (int ni = 0; ni < 4; ++ni) {
                acc[mi][ni] = __builtin_amdgcn_mfma_f32_16x16x32_bf16(a_h[mi], b_h[ni], acc[mi][ni], 0, 0, 0);
                acc[mi][ni] = __builtin_amdgcn_mfma_f32_16x16x32_bf16(a_h[mi], b_l[ni], acc[mi][ni], 0, 0, 0);
                acc[mi][ni] = __builtin_amdgcn_mfma_f32_16x16x32_bf16(a_l[mi], b_h[ni], acc[mi][ni], 0, 0, 0);
            }
        __syncthreads();
    }
    // ---- epilogue: C/D layout col=lane&15, row=(lane>>4)*4+reg ----
    int m16 = lane & 15, rq = lane >> 4;
#pragma unroll
    for (int mi = 0; mi < 4; ++mi)
#pragma unroll
        for (int ni = 0; ni < 4; ++ni)
#pragma unroll
            for (int r = 0; r < 4; ++r) {
                int row = bm + wm + mi * 16 + rq * 4 + r;
                if (row < M)
                    C[(size_t)row * NG + bn + wn + ni * 16 + m16] = (_Float16)acc[mi][ni][r];
            }
}

// ---------------- layer-1 agg: wave per node, unroll-4 gather, bf16-split out ----
__global__ __launch_bounds__(256) void agg1_kernel(const _Float16* __restrict__ h1h,
                                                   const int* __restrict__ off,
                                                   const int* __restrict__ csr_src,
                                                   const float* __restrict__ csr_w,
                                                   const float* __restrict__ inv_sqrt,
                                                   const float* __restrict__ b1,
                                                   ushort* __restrict__ x1h,
                                                   ushort* __restrict__ x1l) {
    int wv = threadIdx.x >> 6, lane = threadIdx.x & 63;
    int i = blockIdx.x * 4 + wv;
    if (i >= NV) return;
    int c4 = lane * 4;
    int s0 = off[i], s1 = off[i + 1];
    float a0 = 0.f, a1 = 0.f, a2 = 0.f, a3 = 0.f;
    int j = s0;
    for (; j + 4 <= s1; j += 4) {
        int sA = csr_src[j], sB = csr_src[j + 1], sC = csr_src[j + 2], sD = csr_src[j + 3];
        float wA = csr_w[j], wB = csr_w[j + 1], wC = csr_w[j + 2], wD = csr_w[j + 3];
        half4 vA = *(const half4*)(h1h + (size_t)sA * NG + c4);
        half4 vB = *(const half4*)(h1h + (size_t)sB * NG + c4);
        half4 vC = *(const half4*)(h1h + (size_t)sC * NG + c4);
        half4 vD = *(const half4*)(h1h + (size_t)sD * NG + c4);
        a0 += wA * (float)vA[0] + wB * (float)vB[0] + wC * (float)vC[0] + wD * (float)vD[0];
        a1 += wA * (float)vA[1] + wB * (float)vB[1] + wC * (float)vC[1] + wD * (float)vD[1];
        a2 += wA * (float)vA[2] + wB * (float)vB[2] + wC * (float)vC[2] + wD * (float)vD[2];
        a3 += wA * (float)vA[3] + wB * (float)vB[3] + wC * (float)vC[3] + wD * (float)vD[3];
    }
    for (; j < s1; ++j) {
        int s = csr_src[j];
        float w = csr_w[j];
        half4 hv = *(const half4*)(h1h + (size_t)s * NG + c4);
        a0 += w * (float)hv[0];
        a1 += w * (float)hv[1];
        a2 += w * (float)hv[2];
        a3 += w * (float)hv[3];
    }
    float is = inv_sqrt[i], is2 = is * is;
    half4 sv = *(const half4*)(h1h + (size_t)i * NG + c4);
    float4 bb = *(const float4*)(b1 + c4);
    float v0 = fmaxf(is * a0 + (float)sv[0] * is2 + bb.x, 0.f);
    float v1 = fmaxf(is * a1 + (float)sv[1] * is2 + bb.y, 0.f);
    float v2 = fmaxf(is * a2 + (float)sv[2] * is2 + bb.z, 0.f);
    float v3 = fmaxf(is * a3 + (float)sv[3] * is2 + bb.w, 0.f);
    ushort4 hh, ll;
    hh.x = f2bf(v0); ll.x = f2bf(v0 - bf2f(hh.x));
    hh.y = f2bf(v1); ll.y = f2bf(v1 - bf2f(hh.y));
    hh.z = f2bf(v2); ll.z = f2bf(v2 - bf2f(hh.z));
    hh.w = f2bf(v3); ll.w = f2bf(v3 - bf2f(hh.w));
    *(ushort4*)(x1h + (size_t)i * NG + c4) = hh;
    *(ushort4*)(x1l + (size_t)i * NG + c4) = ll;
}

// ---------------- layer-2 agg: wave per word position, unroll-4, fp32 out ----------
__global__ __launch_bounds__(256) void agg2_kernel(const _Float16* __restrict__ h2h,
                                                   const int* __restrict__ off,
                                                   const int* __restrict__ csr_src,
                                                   const float* __restrict__ csr_w,
                                                   const float* __restrict__ inv_sqrt,
                                                   const float* __restrict__ b2,
                                                   const int* __restrict__ word_ids,
                                                   float* __restrict__ out) {
    int wv = threadIdx.x >> 6, lane = threadIdx.x & 63;
    int p = blockIdx.x * 4 + wv;
    if (p >= NBS) return;
    int n = word_ids[p];
    int c4 = lane * 4;
    int s0 = off[n], s1 = off[n + 1];
    float a0 = 0.f, a1 = 0.f, a2 = 0.f, a3 = 0.f;
    int j = s0;
    for (; j + 4 <= s1; j += 4) {
        int sA = csr_src[j], sB = csr_src[j + 1], sC = csr_src[j + 2], sD = csr_src[j + 3];
        float wA = csr_w[j], wB = csr_w[j + 1], wC = csr_w[j + 2], wD = csr_w[j + 3];
        half4 vA = *(const half4*)(h2h + (size_t)sA * NG + c4);
        half4 vB = *(const half4*)(h2h + (size_t)sB * NG + c4);
        half4 vC = *(const half4*)(h2h + (size_t)sC * NG + c4);
        half4 vD = *(const half4*)(h2h + (size_t)sD * NG + c4);
        a0 += wA * (float)vA[0] + wB * (float)vB[0] + wC * (float)vC[0] + wD * (float)vD[0];
        a1 += wA * (float)vA[1] + wB * (float)vB[1] + wC * (float)vC[1] + wD * (float)vD[1];
        a2 += wA * (float)vA[2] + wB * (float)vB[2] + wC * (float)vC[2] + wD * (float)vD[2];
        a3 += wA * (float)vA[3] + wB * (float)vB[3] + wC * (float)vC[3] + wD * (float)vD[3];
    }
    for (; j < s1; ++j) {
        int s = csr_src[j];
        float w = csr_w[j];
        half4 hv = *(const half4*)(h2h + (size_t)s * NG + c4);
        a0 += w * (float)hv[0];
        a1 += w * (float)hv[1];
        a2 += w * (float)hv[2];
        a3 += w * (float)hv[3];
    }
    float is = inv_sqrt[n], is2 = is * is;
    half4 sv = *(const half4*)(h2h + (size_t)n * NG + c4);
    float4 bb = *(const float4*)(b2 + c4);
    float4 o;
    o.x = is * a0 + (float)sv[0] * is2 + bb.x;
    o.y = is * a1 + (float)sv[1] * is2 + bb.y;
    o.z = is * a2 + (float)sv[2] * is2 + bb.z;
    o.w = is * a3 + (float)sv[3] * is2 + bb.w;
    *(float4*)(out + (size_t)p * NG + c4) = o;
}

extern "C" void kernel_launch(void* const* d_in, const int* in_sizes, int n_in,
                              void* d_out, int out_size, void* d_ws, size_t ws_size,
                              hipStream_t stream) {
    const float* emb = (const float*)d_in[0];       // V x D
    const float* W1  = (const float*)d_in[1];       // D x G
    const float* b1  = (const float*)d_in[2];       // G
    const float* W2  = (const float*)d_in[3];       // G x G
    const float* b2  = (const float*)d_in[4];       // G
    const int*   ei  = (const int*)d_in[5];         // 2 x E
    const int*   wid = (const int*)d_in[6];         // B x S
    float* out = (float*)d_out;

    char* w = (char*)d_ws;
    auto alloc = [&](size_t bytes) {
        void* p = (void*)w;
        w += (bytes + 255) & ~(size_t)255;
        return p;
    };
    int*    deg      = (int*)alloc((size_t)NV * 4);
    int*    off      = (int*)alloc((size_t)(NV + 1) * 4);
    int*    cursor   = (int*)alloc((size_t)NV * 4);
    float*  inv_sqrt = (float*)alloc((size_t)NV * 4);
    int*    csr_src  = (int*)alloc((size_t)NE * 4);
    float*  csr_w    = (float*)alloc((size_t)NE * 4);
    ushort* W1T_h    = (ushort*)alloc((size_t)NG * NDP * 2);
    ushort* W1T_l    = (ushort*)alloc((size_t)NG * NDP * 2);
    ushort* W2T_h    = (ushort*)alloc((size_t)NG * NG * 2);
    ushort* W2T_l    = (ushort*)alloc((size_t)NG * NG * 2);
    _Float16* h1h    = (_Float16*)alloc((size_t)NV * NG * 2);
    ushort* x1h      = (ushort*)alloc((size_t)NV * NG * 2);
    ushort* x1l      = (ushort*)alloc((size_t)NV * NG * 2);
    _Float16* h2h    = (_Float16*)alloc((size_t)NV * NG * 2);

    hipMemsetAsync(deg, 0, (size_t)NV * 4, stream);

    hist_kernel<<<(NE / 4 + 255) / 256, 256, 0, stream>>>(ei + NE, deg);
    scan_kernel<<<1, 1024, 0, stream>>>(deg, off, cursor, inv_sqrt);
    csr_kernel<<<(NE + 255) / 256, 256, 0, stream>>>(ei, inv_sqrt, cursor, csr_src, csr_w);

    splitw_kernel<<<(NG * NDP + 255) / 256, 256, 0, stream>>>(W1, ND, NG, NDP, W1T_h, W1T_l);
    splitw_kernel<<<(NG * NG + 255) / 256, 256, 0, stream>>>(W2, NG, NG, NG, W2T_h, W2T_l);

    // h1 = emb @ W1  (fp16 out)
    {
        dim3 grid((NV + 127) / 128, NG / 128);
        gemm_mfma<true><<<grid, 256, 0, stream>>>(emb, nullptr, nullptr, ND,
                                                  W1T_h, W1T_l, NDP, NV, ND, NDP, h1h);
    }
    // x1 = relu(norm-agg(h1) + b1)  (bf16 hi/lo out)
    agg1_kernel<<<(NV + 3) / 4, 256, 0, stream>>>(h1h, off, csr_src, csr_w, inv_sqrt, b1, x1h, x1l);
    // h2 = x1 @ W2  (fp16 out)
    {
        dim3 grid((NV + 127) / 128, NG / 128);
        gemm_mfma<false><<<grid, 256, 0, stream>>>(nullptr, x1h, x1l, NG,
                                                   W2T_h, W2T_l, NG, NV, NG, NG, h2h);
    }
    // out = (norm-agg(h2) + b2)[word_ids]  (fp32)
    agg2_kernel<<<(NBS + 3) / 4, 256, 0, stream>>>(h2h, off, csr_src, csr_w, inv_sqrt, b2, wid, out);
}

// Round 5
// 466.015 us; speedup vs baseline: 1.6345x; 1.1595x over previous
//
#include <hip/hip_runtime.h>
#include <hip/hip_bf16.h>

#define NV 50000
#define ND 300
#define NDP 320      // K of layer-1 padded to multiple of 32
#define NG 256
#define NE 1600000
#define NBS 4096     // B*S
#define NBUCK 196    // ceil(50000/256) buckets of 256 nodes (dst>>8)
#define EPB 8192     // edges per block in bucket_scatter

typedef short short8 __attribute__((ext_vector_type(8)));
typedef float f32x4 __attribute__((ext_vector_type(4)));
typedef _Float16 half4 __attribute__((ext_vector_type(4)));

__device__ __forceinline__ ushort f2bf(float f) {
    unsigned u = __builtin_bit_cast(unsigned, f);
    unsigned r = (u + 0x7fffu + ((u >> 16) & 1u)) >> 16;
    return (ushort)r;
}
__device__ __forceinline__ float bf2f(ushort h) {
    unsigned u = ((unsigned)h) << 16;
    return __builtin_bit_cast(float, u);
}

// ------- node-degree histogram + bucket histogram (LDS-aggregated) -------
__global__ __launch_bounds__(256) void hist_kernel(const int* __restrict__ dst,
                                                   int* __restrict__ deg,
                                                   int* __restrict__ bucket_count) {
    __shared__ int bh[NBUCK];
    int t = threadIdx.x;
    for (int b = t; b < NBUCK; b += 256) bh[b] = 0;
    __syncthreads();
    int i = blockIdx.x * 256 + t;
    if (i * 4 < NE) {
        int4 d = *(const int4*)(dst + i * 4);
        atomicAdd(&deg[d.x], 1);
        atomicAdd(&deg[d.y], 1);
        atomicAdd(&deg[d.z], 1);
        atomicAdd(&deg[d.w], 1);
        atomicAdd(&bh[d.x >> 8], 1);
        atomicAdd(&bh[d.y >> 8], 1);
        atomicAdd(&bh[d.z >> 8], 1);
        atomicAdd(&bh[d.w >> 8], 1);
    }
    __syncthreads();
    for (int b = t; b < NBUCK; b += 256)
        if (bh[b]) atomicAdd(&bucket_count[b], bh[b]);
}

// ------- scans: node-degree exclusive scan -> off, inv_sqrt; bucket scan -------
__global__ __launch_bounds__(1024) void scan_kernel(const int* __restrict__ deg,
                                                    int* __restrict__ off,
                                                    float* __restrict__ inv_sqrt,
                                                    const int* __restrict__ bucket_count,
                                                    int* __restrict__ bucket_base,
                                                    int* __restrict__ bucket_cursor) {
    const int T = 1024;
    const int CH = (NV + T - 1) / T;  // 49
    int t = threadIdx.x;
    if (t == 0) {  // tiny serial bucket scan in parallel with node scan
        int run = 0;
        for (int b = 0; b < NBUCK; ++b) {
            bucket_base[b] = run;
            bucket_cursor[b] = run;
            run += bucket_count[b];
        }
        bucket_base[NBUCK] = run;  // = NE
    }
    int begin = t * CH;
    int end = begin + CH; if (end > NV) end = NV;
    int sum = 0;
    for (int i = begin; i < end; ++i) sum += deg[i];
    __shared__ int s[T];
    s[t] = sum;
    __syncthreads();
    for (int d = 1; d < T; d <<= 1) {
        int v = (t >= d) ? s[t - d] : 0;
        __syncthreads();
        s[t] += v;
        __syncthreads();
    }
    int run = s[t] - sum;
    for (int i = begin; i < end; ++i) {
        int dv = deg[i];
        off[i] = run;
        inv_sqrt[i] = rsqrtf((float)(dv + 1));  // deg = 1 (self loop) + in-degree
        run += dv;
    }
    if (t == 0) off[NV] = NE;
}

// ------- pass A: scatter edges into coarse dst-buckets (contiguous runs) -------
__global__ __launch_bounds__(256) void bucket_scatter(const int* __restrict__ ei,
                                                      int* __restrict__ bucket_cursor,
                                                      int2* __restrict__ rec) {
    __shared__ int cnt[NBUCK];
    __shared__ int basel[NBUCK];
    int t = threadIdx.x;
    int e0 = blockIdx.x * EPB;
    for (int b = t; b < NBUCK; b += 256) cnt[b] = 0;
    __syncthreads();
    // pass 1: block-local bucket histogram
    for (int q = 0; q < EPB / 1024; ++q) {
        int i4 = e0 + q * 1024 + t * 4;
        if (i4 < NE) {
            int4 d = *(const int4*)(ei + NE + i4);
            atomicAdd(&cnt[d.x >> 8], 1);
            atomicAdd(&cnt[d.y >> 8], 1);
            atomicAdd(&cnt[d.z >> 8], 1);
            atomicAdd(&cnt[d.w >> 8], 1);
        }
    }
    __syncthreads();
    for (int b = t; b < NBUCK; b += 256) {
        int c = cnt[b];
        basel[b] = c ? atomicAdd(&bucket_cursor[b], c) : 0;
    }
    __syncthreads();
    for (int b = t; b < NBUCK; b += 256) cnt[b] = 0;
    __syncthreads();
    // pass 2: place records {src,dst} at block-contiguous bucket positions
    for (int q = 0; q < EPB / 1024; ++q) {
        int i4 = e0 + q * 1024 + t * 4;
        if (i4 < NE) {
            int4 s = *(const int4*)(ei + i4);
            int4 d = *(const int4*)(ei + NE + i4);
            int b0 = d.x >> 8, b1 = d.y >> 8, b2 = d.z >> 8, b3 = d.w >> 8;
            int r0 = atomicAdd(&cnt[b0], 1);
            rec[basel[b0] + r0] = make_int2(s.x, d.x);
            int r1 = atomicAdd(&cnt[b1], 1);
            rec[basel[b1] + r1] = make_int2(s.y, d.y);
            int r2 = atomicAdd(&cnt[b2], 1);
            rec[basel[b2] + r2] = make_int2(s.z, d.z);
            int r3 = atomicAdd(&cnt[b3], 1);
            rec[basel[b3] + r3] = make_int2(s.w, d.w);
        }
    }
}

// ------- pass B: one block per bucket, LDS cursors, L2-local CSR placement -------
__global__ __launch_bounds__(256) void csr_place(const int2* __restrict__ rec,
                                                 const int* __restrict__ bucket_base,
                                                 const int* __restrict__ off,
                                                 const float* __restrict__ inv_sqrt,
                                                 int* __restrict__ csr_src,
                                                 float* __restrict__ csr_w) {
    __shared__ int cur[256];
    int b = blockIdx.x, t = threadIdx.x;
    int n = (b << 8) + t;
    if (n < NV) cur[t] = off[n];
    __syncthreads();
    int r0 = bucket_base[b], r1 = bucket_base[b + 1];
    for (int i = r0 + t; i < r1; i += 256) {
        int2 e = rec[i];
        int p = atomicAdd(&cur[e.y & 255], 1);
        csr_src[p] = e.x;
        csr_w[p] = inv_sqrt[e.x];
    }
}

// ---------------- W (K x N) -> W^T hi/lo bf16 [N][ldk], zero-padded ----------------
__global__ __launch_bounds__(256) void splitw_kernel(const float* __restrict__ W,
                                                     int K, int N, int ldk,
                                                     ushort* __restrict__ Th,
                                                     ushort* __restrict__ Tl) {
    int idx = blockIdx.x * 256 + threadIdx.x;
    if (idx >= N * ldk) return;
    int n = idx / ldk, k = idx - n * ldk;
    float v = (k < K) ? W[(size_t)k * N + n] : 0.f;
    ushort h = f2bf(v);
    Th[idx] = h;
    Tl[idx] = f2bf(v - bf2f(h));
}

// ---- split-bf16 MFMA GEMM, 128x128 tile, 4 waves x (64x64 via 4x4 16x16 frags) ----
template <bool A_FP32>
__global__ __launch_bounds__(256) void gemm_mfma(const float* __restrict__ A,
                                                 const ushort* __restrict__ Ah_g,
                                                 const ushort* __restrict__ Al_g,
                                                 int lda,
                                                 const ushort* __restrict__ BTh,
                                                 const ushort* __restrict__ BTl,
                                                 int ldb,
                                                 int M, int K, int KP,
                                                 _Float16* __restrict__ C) {
    __shared__ short Ah[128][40];
    __shared__ short Al[128][40];
    __shared__ short Bh[128][40];
    __shared__ short Bl[128][40];
    int t = threadIdx.x;
    int bm = blockIdx.x * 128;
    int bn = blockIdx.y * 128;
    int lane = t & 63, wv = t >> 6;
    int wm = (wv >> 1) * 64, wn = (wv & 1) * 64;
    int srow = t >> 1;          // staging row 0..127
    int skq = (t & 1) * 16;     // staging k offset {0,16}
    f32x4 acc[4][4];
#pragma unroll
    for (int mi = 0; mi < 4; ++mi)
#pragma unroll
        for (int ni = 0; ni < 4; ++ni) acc[mi][ni] = (f32x4)0.0f;

    for (int k0 = 0; k0 < KP; k0 += 32) {
        int gk = k0 + skq;
        {
            int gr = bm + srow;
            short8 vah[2], val[2];
            if (A_FP32) {
                float v[16];
                if (gr < M && gk < K) {
                    if (gk + 16 <= K) {
#pragma unroll
                        for (int q = 0; q < 4; ++q) {
                            float4 p = *(const float4*)(A + (size_t)gr * lda + gk + q * 4);
                            v[q * 4 + 0] = p.x; v[q * 4 + 1] = p.y;
                            v[q * 4 + 2] = p.z; v[q * 4 + 3] = p.w;
                        }
                    } else {
#pragma unroll
                        for (int e = 0; e < 16; ++e)
                            v[e] = (gk + e < K) ? A[(size_t)gr * lda + gk + e] : 0.f;
                    }
                } else {
#pragma unroll
                    for (int e = 0; e < 16; ++e) v[e] = 0.f;
                }
#pragma unroll
                for (int e = 0; e < 16; ++e) {
                    ushort h = f2bf(v[e]);
                    ((short*)vah)[e] = (short)h;
                    ((short*)val)[e] = (short)f2bf(v[e] - bf2f(h));
                }
            } else {
                if (gr < M) {
                    vah[0] = *(const short8*)(Ah_g + (size_t)gr * lda + gk);
                    vah[1] = *(const short8*)(Ah_g + (size_t)gr * lda + gk + 8);
                    val[0] = *(const short8*)(Al_g + (size_t)gr * lda + gk);
                    val[1] = *(const short8*)(Al_g + (size_t)gr * lda + gk + 8);
                } else {
                    vah[0] = (short8)0; vah[1] = (short8)0;
                    val[0] = (short8)0; val[1] = (short8)0;
                }
            }
            *(short8*)&Ah[srow][skq] = vah[0];
            *(short8*)&Ah[srow][skq + 8] = vah[1];
            *(short8*)&Al[srow][skq] = val[0];
            *(short8*)&Al[srow][skq + 8] = val[1];
        }
        {
            int nr = bn + srow;
            short8 bh0 = *(const short8*)(BTh + (size_t)nr * ldb + gk);
            short8 bh1 = *(const short8*)(BTh + (size_t)nr * ldb + gk + 8);
            short8 bl0 = *(const short8*)(BTl + (size_t)nr * ldb + gk);
            short8 bl1 = *(const short8*)(BTl + (size_t)nr * ldb + gk + 8);
            *(short8*)&Bh[srow][skq] = bh0;
            *(short8*)&Bh[srow][skq + 8] = bh1;
            *(short8*)&Bl[srow][skq] = bl0;
            *(short8*)&Bl[srow][skq + 8] = bl1;
        }
        __syncthreads();
        int m16 = lane & 15, kb = (lane >> 4) * 8;
        short8 a_h[4], a_l[4], b_h[4], b_l[4];
#pragma unroll
        for (int mi = 0; mi < 4; ++mi) {
            a_h[mi] = *(const short8*)&Ah[wm + mi * 16 + m16][kb];
            a_l[mi] = *(const short8*)&Al[wm + mi * 16 + m16][kb];
        }
#pragma unroll
        for (int ni = 0; ni < 4; ++ni) {
            b_h[ni] = *(const short8*)&Bh[wn + ni * 16 + m16][kb];
            b_l[ni] = *(const short8*)&Bl[wn + ni * 16 + m16][kb];
        }
#pragma unroll
        for (int mi = 0; mi < 4; ++mi)
#pragma unroll
            for (int ni = 0; ni < 4; ++ni) {
                acc[mi][ni] = __builtin_amdgcn_mfma_f32_16x16x32_bf16(a_h[mi], b_h[ni], acc[mi][ni], 0, 0, 0);
                acc[mi][ni] = __builtin_amdgcn_mfma_f32_16x16x32_bf16(a_h[mi], b_l[ni], acc[mi][ni], 0, 0, 0);
                acc[mi][ni] = __builtin_amdgcn_mfma_f32_16x16x32_bf16(a_l[mi], b_h[ni], acc[mi][ni], 0, 0, 0);
            }
        __syncthreads();
    }
    int m16 = lane & 15, rq = lane >> 4;
#pragma unroll
    for (int mi = 0; mi < 4; ++mi)
#pragma unroll
        for (int ni = 0; ni < 4; ++ni)
#pragma unroll
            for (int r = 0; r < 4; ++r) {
                int row = bm + wm + mi * 16 + rq * 4 + r;
                if (row < M)
                    C[(size_t)row * NG + bn + wn + ni * 16 + m16] = (_Float16)acc[mi][ni][r];
            }
}

// ---------------- layer-1 agg: wave per node, unroll-4 gather, bf16-split out ----
__global__ __launch_bounds__(256) void agg1_kernel(const _Float16* __restrict__ h1h,
                                                   const int* __restrict__ off,
                                                   const int* __restrict__ csr_src,
                                                   const float* __restrict__ csr_w,
                                                   const float* __restrict__ inv_sqrt,
                                                   const float* __restrict__ b1,
                                                   ushort* __restrict__ x1h,
                                                   ushort* __restrict__ x1l) {
    int wv = threadIdx.x >> 6, lane = threadIdx.x & 63;
    int i = blockIdx.x * 4 + wv;
    if (i >= NV) return;
    int c4 = lane * 4;
    int s0 = off[i], s1 = off[i + 1];
    float a0 = 0.f, a1 = 0.f, a2 = 0.f, a3 = 0.f;
    int j = s0;
    for (; j + 4 <= s1; j += 4) {
        int sA = csr_src[j], sB = csr_src[j + 1], sC = csr_src[j + 2], sD = csr_src[j + 3];
        float wA = csr_w[j], wB = csr_w[j + 1], wC = csr_w[j + 2], wD = csr_w[j + 3];
        half4 vA = *(const half4*)(h1h + (size_t)sA * NG + c4);
        half4 vB = *(const half4*)(h1h + (size_t)sB * NG + c4);
        half4 vC = *(const half4*)(h1h + (size_t)sC * NG + c4);
        half4 vD = *(const half4*)(h1h + (size_t)sD * NG + c4);
        a0 += wA * (float)vA[0] + wB * (float)vB[0] + wC * (float)vC[0] + wD * (float)vD[0];
        a1 += wA * (float)vA[1] + wB * (float)vB[1] + wC * (float)vC[1] + wD * (float)vD[1];
        a2 += wA * (float)vA[2] + wB * (float)vB[2] + wC * (float)vC[2] + wD * (float)vD[2];
        a3 += wA * (float)vA[3] + wB * (float)vB[3] + wC * (float)vC[3] + wD * (float)vD[3];
    }
    for (; j < s1; ++j) {
        int s = csr_src[j];
        float w = csr_w[j];
        half4 hv = *(const half4*)(h1h + (size_t)s * NG + c4);
        a0 += w * (float)hv[0];
        a1 += w * (float)hv[1];
        a2 += w * (float)hv[2];
        a3 += w * (float)hv[3];
    }
    float is = inv_sqrt[i], is2 = is * is;
    half4 sv = *(const half4*)(h1h + (size_t)i * NG + c4);
    float4 bb = *(const float4*)(b1 + c4);
    float v0 = fmaxf(is * a0 + (float)sv[0] * is2 + bb.x, 0.f);
    float v1 = fmaxf(is * a1 + (float)sv[1] * is2 + bb.y, 0.f);
    float v2 = fmaxf(is * a2 + (float)sv[2] * is2 + bb.z, 0.f);
    float v3 = fmaxf(is * a3 + (float)sv[3] * is2 + bb.w, 0.f);
    ushort4 hh, ll;
    hh.x = f2bf(v0); ll.x = f2bf(v0 - bf2f(hh.x));
    hh.y = f2bf(v1); ll.y = f2bf(v1 - bf2f(hh.y));
    hh.z = f2bf(v2); ll.z = f2bf(v2 - bf2f(hh.z));
    hh.w = f2bf(v3); ll.w = f2bf(v3 - bf2f(hh.w));
    *(ushort4*)(x1h + (size_t)i * NG + c4) = hh;
    *(ushort4*)(x1l + (size_t)i * NG + c4) = ll;
}

// ---------------- layer-2 agg: wave per word position, unroll-4, fp32 out ----------
__global__ __launch_bounds__(256) void agg2_kernel(const _Float16* __restrict__ h2h,
                                                   const int* __restrict__ off,
                                                   const int* __restrict__ csr_src,
                                                   const float* __restrict__ csr_w,
                                                   const float* __restrict__ inv_sqrt,
                                                   const float* __restrict__ b2,
                                                   const int* __restrict__ word_ids,
                                                   float* __restrict__ out) {
    int wv = threadIdx.x >> 6, lane = threadIdx.x & 63;
    int p = blockIdx.x * 4 + wv;
    if (p >= NBS) return;
    int n = word_ids[p];
    int c4 = lane * 4;
    int s0 = off[n], s1 = off[n + 1];
    float a0 = 0.f, a1 = 0.f, a2 = 0.f, a3 = 0.f;
    int j = s0;
    for (; j + 4 <= s1; j += 4) {
        int sA = csr_src[j], sB = csr_src[j + 1], sC = csr_src[j + 2], sD = csr_src[j + 3];
        float wA = csr_w[j], wB = csr_w[j + 1], wC = csr_w[j + 2], wD = csr_w[j + 3];
        half4 vA = *(const half4*)(h2h + (size_t)sA * NG + c4);
        half4 vB = *(const half4*)(h2h + (size_t)sB * NG + c4);
        half4 vC = *(const half4*)(h2h + (size_t)sC * NG + c4);
        half4 vD = *(const half4*)(h2h + (size_t)sD * NG + c4);
        a0 += wA * (float)vA[0] + wB * (float)vB[0] + wC * (float)vC[0] + wD * (float)vD[0];
        a1 += wA * (float)vA[1] + wB * (float)vB[1] + wC * (float)vC[1] + wD * (float)vD[1];
        a2 += wA * (float)vA[2] + wB * (float)vB[2] + wC * (float)vC[2] + wD * (float)vD[2];
        a3 += wA * (float)vA[3] + wB * (float)vB[3] + wC * (float)vC[3] + wD * (float)vD[3];
    }
    for (; j < s1; ++j) {
        int s = csr_src[j];
        float w = csr_w[j];
        half4 hv = *(const half4*)(h2h + (size_t)s * NG + c4);
        a0 += w * (float)hv[0];
        a1 += w * (float)hv[1];
        a2 += w * (float)hv[2];
        a3 += w * (float)hv[3];
    }
    float is = inv_sqrt[n], is2 = is * is;
    half4 sv = *(const half4*)(h2h + (size_t)n * NG + c4);
    float4 bb = *(const float4*)(b2 + c4);
    float4 o;
    o.x = is * a0 + (float)sv[0] * is2 + bb.x;
    o.y = is * a1 + (float)sv[1] * is2 + bb.y;
    o.z = is * a2 + (float)sv[2] * is2 + bb.z;
    o.w = is * a3 + (float)sv[3] * is2 + bb.w;
    *(float4*)(out + (size_t)p * NG + c4) = o;
}

extern "C" void kernel_launch(void* const* d_in, const int* in_sizes, int n_in,
                              void* d_out, int out_size, void* d_ws, size_t ws_size,
                              hipStream_t stream) {
    const float* emb = (const float*)d_in[0];       // V x D
    const float* W1  = (const float*)d_in[1];       // D x G
    const float* b1  = (const float*)d_in[2];       // G
    const float* W2  = (const float*)d_in[3];       // G x G
    const float* b2  = (const float*)d_in[4];       // G
    const int*   ei  = (const int*)d_in[5];         // 2 x E
    const int*   wid = (const int*)d_in[6];         // B x S
    float* out = (float*)d_out;

    char* w = (char*)d_ws;
    auto alloc = [&](size_t bytes) {
        void* p = (void*)w;
        w += (bytes + 255) & ~(size_t)255;
        return p;
    };
    int*    deg      = (int*)alloc((size_t)NV * 4);
    int*    off      = (int*)alloc((size_t)(NV + 1) * 4);
    float*  inv_sqrt = (float*)alloc((size_t)NV * 4);
    int*    bucket_count  = (int*)alloc((size_t)NBUCK * 4);
    int*    bucket_base   = (int*)alloc((size_t)(NBUCK + 1) * 4);
    int*    bucket_cursor = (int*)alloc((size_t)NBUCK * 4);
    int*    csr_src  = (int*)alloc((size_t)NE * 4);
    float*  csr_w    = (float*)alloc((size_t)NE * 4);
    ushort* W1T_h    = (ushort*)alloc((size_t)NG * NDP * 2);
    ushort* W1T_l    = (ushort*)alloc((size_t)NG * NDP * 2);
    ushort* W2T_h    = (ushort*)alloc((size_t)NG * NG * 2);
    ushort* W2T_l    = (ushort*)alloc((size_t)NG * NG * 2);
    _Float16* h1h    = (_Float16*)alloc((size_t)NV * NG * 2);
    ushort* x1h      = (ushort*)alloc((size_t)NV * NG * 2);
    ushort* x1l      = (ushort*)alloc((size_t)NV * NG * 2);
    _Float16* h2h    = (_Float16*)alloc((size_t)NV * NG * 2);
    // bucket_rec (NE*8 = 12.8 MB) aliases h2h (25.6 MB): csr_place finishes
    // reading it before gemm2 writes h2h (same-stream ordering).
    int2* bucket_rec = (int2*)h2h;

    hipMemsetAsync(deg, 0, (size_t)NV * 4, stream);
    hipMemsetAsync(bucket_count, 0, (size_t)NBUCK * 4, stream);

    hist_kernel<<<(NE / 4 + 255) / 256, 256, 0, stream>>>(ei + NE, deg, bucket_count);
    scan_kernel<<<1, 1024, 0, stream>>>(deg, off, inv_sqrt,
                                        bucket_count, bucket_base, bucket_cursor);
    bucket_scatter<<<(NE + EPB - 1) / EPB, 256, 0, stream>>>(ei, bucket_cursor, bucket_rec);
    csr_place<<<NBUCK, 256, 0, stream>>>(bucket_rec, bucket_base, off, inv_sqrt,
                                         csr_src, csr_w);

    splitw_kernel<<<(NG * NDP + 255) / 256, 256, 0, stream>>>(W1, ND, NG, NDP, W1T_h, W1T_l);
    splitw_kernel<<<(NG * NG + 255) / 256, 256, 0, stream>>>(W2, NG, NG, NG, W2T_h, W2T_l);

    // h1 = emb @ W1  (fp16 out)
    {
        dim3 grid((NV + 127) / 128, NG / 128);
        gemm_mfma<true><<<grid, 256, 0, stream>>>(emb, nullptr, nullptr, ND,
                                                  W1T_h, W1T_l, NDP, NV, ND, NDP, h1h);
    }
    // x1 = relu(norm-agg(h1) + b1)  (bf16 hi/lo out)
    agg1_kernel<<<(NV + 3) / 4, 256, 0, stream>>>(h1h, off, csr_src, csr_w, inv_sqrt, b1, x1h, x1l);
    // h2 = x1 @ W2  (fp16 out)
    {
        dim3 grid((NV + 127) / 128, NG / 128);
        gemm_mfma<false><<<grid, 256, 0, stream>>>(nullptr, x1h, x1l, NG,
                                                   W2T_h, W2T_l, NG, NV, NG, NG, h2h);
    }
    // out = (norm-agg(h2) + b2)[word_ids]  (fp32)
    agg2_kernel<<<(NBS + 3) / 4, 256, 0, stream>>>(h2h, off, csr_src, csr_w, inv_sqrt, b2, wid, out);
}

// Round 6
// 449.750 us; speedup vs baseline: 1.6937x; 1.0362x over previous
//
#include <hip/hip_runtime.h>
#include <hip/hip_bf16.h>

#define NV 50000
#define ND 300
#define NDP 320      // K of layer-1 padded to multiple of 32
#define NG 256
#define NE 1600000
#define NBS 4096     // B*S
#define NBUCK 196    // ceil(50000/256) buckets of 256 nodes (dst>>8)
#define EPB 8192     // edges per block in bucket_scatter

typedef short short8 __attribute__((ext_vector_type(8)));
typedef float f32x4 __attribute__((ext_vector_type(4)));
typedef _Float16 half4 __attribute__((ext_vector_type(4)));

__device__ __forceinline__ ushort f2bf(float f) {
    unsigned u = __builtin_bit_cast(unsigned, f);
    unsigned r = (u + 0x7fffu + ((u >> 16) & 1u)) >> 16;
    return (ushort)r;
}
__device__ __forceinline__ float bf2f(ushort h) {
    unsigned u = ((unsigned)h) << 16;
    return __builtin_bit_cast(float, u);
}

// ------- node-degree histogram + bucket histogram (LDS-aggregated) -------
__global__ __launch_bounds__(256) void hist_kernel(const int* __restrict__ dst,
                                                   int* __restrict__ deg,
                                                   int* __restrict__ bucket_count) {
    __shared__ int bh[NBUCK];
    int t = threadIdx.x;
    for (int b = t; b < NBUCK; b += 256) bh[b] = 0;
    __syncthreads();
    int i = blockIdx.x * 256 + t;
    if (i * 4 < NE) {
        int4 d = *(const int4*)(dst + i * 4);
        atomicAdd(&deg[d.x], 1);
        atomicAdd(&deg[d.y], 1);
        atomicAdd(&deg[d.z], 1);
        atomicAdd(&deg[d.w], 1);
        atomicAdd(&bh[d.x >> 8], 1);
        atomicAdd(&bh[d.y >> 8], 1);
        atomicAdd(&bh[d.z >> 8], 1);
        atomicAdd(&bh[d.w >> 8], 1);
    }
    __syncthreads();
    for (int b = t; b < NBUCK; b += 256)
        if (bh[b]) atomicAdd(&bucket_count[b], bh[b]);
}

// ------- scans: node-degree exclusive scan -> off, inv_sqrt; bucket scan -------
__global__ __launch_bounds__(1024) void scan_kernel(const int* __restrict__ deg,
                                                    int* __restrict__ off,
                                                    float* __restrict__ inv_sqrt,
                                                    const int* __restrict__ bucket_count,
                                                    int* __restrict__ bucket_base,
                                                    int* __restrict__ bucket_cursor) {
    const int T = 1024;
    const int CH = (NV + T - 1) / T;  // 49
    int t = threadIdx.x;
    if (t == 0) {
        int run = 0;
        for (int b = 0; b < NBUCK; ++b) {
            bucket_base[b] = run;
            bucket_cursor[b] = run;
            run += bucket_count[b];
        }
        bucket_base[NBUCK] = run;  // = NE
    }
    int begin = t * CH;
    int end = begin + CH; if (end > NV) end = NV;
    int sum = 0;
    for (int i = begin; i < end; ++i) sum += deg[i];
    __shared__ int s[T];
    s[t] = sum;
    __syncthreads();
    for (int d = 1; d < T; d <<= 1) {
        int v = (t >= d) ? s[t - d] : 0;
        __syncthreads();
        s[t] += v;
        __syncthreads();
    }
    int run = s[t] - sum;
    for (int i = begin; i < end; ++i) {
        int dv = deg[i];
        off[i] = run;
        inv_sqrt[i] = rsqrtf((float)(dv + 1));  // deg = 1 (self loop) + in-degree
        run += dv;
    }
    if (t == 0) off[NV] = NE;
}

// ------- pass A: scatter edges into coarse dst-buckets (contiguous runs) -------
__global__ __launch_bounds__(256) void bucket_scatter(const int* __restrict__ ei,
                                                      int* __restrict__ bucket_cursor,
                                                      int2* __restrict__ rec) {
    __shared__ int cnt[NBUCK];
    __shared__ int basel[NBUCK];
    int t = threadIdx.x;
    int e0 = blockIdx.x * EPB;
    for (int b = t; b < NBUCK; b += 256) cnt[b] = 0;
    __syncthreads();
    for (int q = 0; q < EPB / 1024; ++q) {
        int i4 = e0 + q * 1024 + t * 4;
        if (i4 < NE) {
            int4 d = *(const int4*)(ei + NE + i4);
            atomicAdd(&cnt[d.x >> 8], 1);
            atomicAdd(&cnt[d.y >> 8], 1);
            atomicAdd(&cnt[d.z >> 8], 1);
            atomicAdd(&cnt[d.w >> 8], 1);
        }
    }
    __syncthreads();
    for (int b = t; b < NBUCK; b += 256) {
        int c = cnt[b];
        basel[b] = c ? atomicAdd(&bucket_cursor[b], c) : 0;
    }
    __syncthreads();
    for (int b = t; b < NBUCK; b += 256) cnt[b] = 0;
    __syncthreads();
    for (int q = 0; q < EPB / 1024; ++q) {
        int i4 = e0 + q * 1024 + t * 4;
        if (i4 < NE) {
            int4 s = *(const int4*)(ei + i4);
            int4 d = *(const int4*)(ei + NE + i4);
            int b0 = d.x >> 8, b1 = d.y >> 8, b2 = d.z >> 8, b3 = d.w >> 8;
            int r0 = atomicAdd(&cnt[b0], 1);
            rec[basel[b0] + r0] = make_int2(s.x, d.x);
            int r1 = atomicAdd(&cnt[b1], 1);
            rec[basel[b1] + r1] = make_int2(s.y, d.y);
            int r2 = atomicAdd(&cnt[b2], 1);
            rec[basel[b2] + r2] = make_int2(s.z, d.z);
            int r3 = atomicAdd(&cnt[b3], 1);
            rec[basel[b3] + r3] = make_int2(s.w, d.w);
        }
    }
}

// ------- pass B: one block per bucket, LDS cursors, L2-local CSR placement -------
__global__ __launch_bounds__(256) void csr_place(const int2* __restrict__ rec,
                                                 const int* __restrict__ bucket_base,
                                                 const int* __restrict__ off,
                                                 const float* __restrict__ inv_sqrt,
                                                 int* __restrict__ csr_src,
                                                 float* __restrict__ csr_w) {
    __shared__ int cur[256];
    int b = blockIdx.x, t = threadIdx.x;
    int n = (b << 8) + t;
    if (n < NV) cur[t] = off[n];
    __syncthreads();
    int r0 = bucket_base[b], r1 = bucket_base[b + 1];
    for (int i = r0 + t; i < r1; i += 256) {
        int2 e = rec[i];
        int p = atomicAdd(&cur[e.y & 255], 1);
        csr_src[p] = e.x;
        csr_w[p] = inv_sqrt[e.x];
    }
}

// ---------------- W (K x N) -> W^T hi/lo bf16 [N][ldk], zero-padded ----------------
__global__ __launch_bounds__(256) void splitw_kernel(const float* __restrict__ W,
                                                     int K, int N, int ldk,
                                                     ushort* __restrict__ Th,
                                                     ushort* __restrict__ Tl) {
    int idx = blockIdx.x * 256 + threadIdx.x;
    if (idx >= N * ldk) return;
    int n = idx / ldk, k = idx - n * ldk;
    float v = (k < K) ? W[(size_t)k * N + n] : 0.f;
    ushort h = f2bf(v);
    Th[idx] = h;
    Tl[idx] = f2bf(v - bf2f(h));
}

// ---- split-bf16 MFMA GEMM, 128x128 tile. A is fp32 [M][lda] (split in-kernel).
// B pre-transposed+split: BTh/BTl bf16 [NG][ldb]. OUT32: fp32 C + bias; else fp16 C.
template <bool OUT32>
__global__ __launch_bounds__(256) void gemm_mfma(const float* __restrict__ A,
                                                 int lda,
                                                 const ushort* __restrict__ BTh,
                                                 const ushort* __restrict__ BTl,
                                                 int ldb,
                                                 int M, int K, int KP,
                                                 _Float16* __restrict__ C16,
                                                 float* __restrict__ C32,
                                                 const float* __restrict__ bias) {
    __shared__ short Ah[128][40];
    __shared__ short Al[128][40];
    __shared__ short Bh[128][40];
    __shared__ short Bl[128][40];
    int t = threadIdx.x;
    int bm = blockIdx.x * 128;
    int bn = blockIdx.y * 128;
    int lane = t & 63, wv = t >> 6;
    int wm = (wv >> 1) * 64, wn = (wv & 1) * 64;
    int srow = t >> 1;          // staging row 0..127
    int skq = (t & 1) * 16;     // staging k offset {0,16}
    f32x4 acc[4][4];
#pragma unroll
    for (int mi = 0; mi < 4; ++mi)
#pragma unroll
        for (int ni = 0; ni < 4; ++ni) acc[mi][ni] = (f32x4)0.0f;

    for (int k0 = 0; k0 < KP; k0 += 32) {
        int gk = k0 + skq;
        {
            int gr = bm + srow;
            short8 vah[2], val[2];
            float v[16];
            if (gr < M && gk < K) {
                if (gk + 16 <= K) {
#pragma unroll
                    for (int q = 0; q < 4; ++q) {
                        float4 p = *(const float4*)(A + (size_t)gr * lda + gk + q * 4);
                        v[q * 4 + 0] = p.x; v[q * 4 + 1] = p.y;
                        v[q * 4 + 2] = p.z; v[q * 4 + 3] = p.w;
                    }
                } else {
#pragma unroll
                    for (int e = 0; e < 16; ++e)
                        v[e] = (gk + e < K) ? A[(size_t)gr * lda + gk + e] : 0.f;
                }
            } else {
#pragma unroll
                for (int e = 0; e < 16; ++e) v[e] = 0.f;
            }
#pragma unroll
            for (int e = 0; e < 16; ++e) {
                ushort h = f2bf(v[e]);
                ((short*)vah)[e] = (short)h;
                ((short*)val)[e] = (short)f2bf(v[e] - bf2f(h));
            }
            *(short8*)&Ah[srow][skq] = vah[0];
            *(short8*)&Ah[srow][skq + 8] = vah[1];
            *(short8*)&Al[srow][skq] = val[0];
            *(short8*)&Al[srow][skq + 8] = val[1];
        }
        {
            int nr = bn + srow;
            short8 bh0 = *(const short8*)(BTh + (size_t)nr * ldb + gk);
            short8 bh1 = *(const short8*)(BTh + (size_t)nr * ldb + gk + 8);
            short8 bl0 = *(const short8*)(BTl + (size_t)nr * ldb + gk);
            short8 bl1 = *(const short8*)(BTl + (size_t)nr * ldb + gk + 8);
            *(short8*)&Bh[srow][skq] = bh0;
            *(short8*)&Bh[srow][skq + 8] = bh1;
            *(short8*)&Bl[srow][skq] = bl0;
            *(short8*)&Bl[srow][skq + 8] = bl1;
        }
        __syncthreads();
        int m16 = lane & 15, kb = (lane >> 4) * 8;
        short8 a_h[4], a_l[4], b_h[4], b_l[4];
#pragma unroll
        for (int mi = 0; mi < 4; ++mi) {
            a_h[mi] = *(const short8*)&Ah[wm + mi * 16 + m16][kb];
            a_l[mi] = *(const short8*)&Al[wm + mi * 16 + m16][kb];
        }
#pragma unroll
        for (int ni = 0; ni < 4; ++ni) {
            b_h[ni] = *(const short8*)&Bh[wn + ni * 16 + m16][kb];
            b_l[ni] = *(const short8*)&Bl[wn + ni * 16 + m16][kb];
        }
#pragma unroll
        for (int mi = 0; mi < 4; ++mi)
#pragma unroll
            for (int ni = 0; ni < 4; ++ni) {
                acc[mi][ni] = __builtin_amdgcn_mfma_f32_16x16x32_bf16(a_h[mi], b_h[ni], acc[mi][ni], 0, 0, 0);
                acc[mi][ni] = __builtin_amdgcn_mfma_f32_16x16x32_bf16(a_h[mi], b_l[ni], acc[mi][ni], 0, 0, 0);
                acc[mi][ni] = __builtin_amdgcn_mfma_f32_16x16x32_bf16(a_l[mi], b_h[ni], acc[mi][ni], 0, 0, 0);
            }
        __syncthreads();
    }
    int m16 = lane & 15, rq = lane >> 4;
#pragma unroll
    for (int mi = 0; mi < 4; ++mi)
#pragma unroll
        for (int ni = 0; ni < 4; ++ni)
#pragma unroll
            for (int r = 0; r < 4; ++r) {
                int row = bm + wm + mi * 16 + rq * 4 + r;
                int col = bn + wn + ni * 16 + m16;
                if (row < M) {
                    if (OUT32)
                        C32[(size_t)row * NG + col] = acc[mi][ni][r] + bias[col];
                    else
                        C16[(size_t)row * NG + col] = (_Float16)acc[mi][ni][r];
                }
            }
}

// ---------------- layer-1 agg: wave per node, unroll-8 gather, fp16 out ----------
__global__ __launch_bounds__(256) void agg1_kernel(const _Float16* __restrict__ h1h,
                                                   const int* __restrict__ off,
                                                   const int* __restrict__ csr_src,
                                                   const float* __restrict__ csr_w,
                                                   const float* __restrict__ inv_sqrt,
                                                   const float* __restrict__ b1,
                                                   _Float16* __restrict__ x1) {
    int wv = threadIdx.x >> 6, lane = threadIdx.x & 63;
    int i = blockIdx.x * 4 + wv;
    if (i >= NV) return;
    int c4 = lane * 4;
    int s0 = off[i], s1 = off[i + 1];
    float a0 = 0.f, a1 = 0.f, a2 = 0.f, a3 = 0.f;
    int j = s0;
    for (; j + 8 <= s1; j += 8) {
        int sx[8];
        float wx[8];
        half4 vx[8];
#pragma unroll
        for (int u = 0; u < 8; ++u) { sx[u] = csr_src[j + u]; wx[u] = csr_w[j + u]; }
#pragma unroll
        for (int u = 0; u < 8; ++u) vx[u] = *(const half4*)(h1h + (size_t)sx[u] * NG + c4);
#pragma unroll
        for (int u = 0; u < 8; ++u) {
            a0 += wx[u] * (float)vx[u][0];
            a1 += wx[u] * (float)vx[u][1];
            a2 += wx[u] * (float)vx[u][2];
            a3 += wx[u] * (float)vx[u][3];
        }
    }
    for (; j < s1; ++j) {
        int s = csr_src[j];
        float w = csr_w[j];
        half4 hv = *(const half4*)(h1h + (size_t)s * NG + c4);
        a0 += w * (float)hv[0];
        a1 += w * (float)hv[1];
        a2 += w * (float)hv[2];
        a3 += w * (float)hv[3];
    }
    float is = inv_sqrt[i], is2 = is * is;
    half4 sv = *(const half4*)(h1h + (size_t)i * NG + c4);
    float4 bb = *(const float4*)(b1 + c4);
    half4 o;
    o[0] = (_Float16)fmaxf(is * a0 + (float)sv[0] * is2 + bb.x, 0.f);
    o[1] = (_Float16)fmaxf(is * a1 + (float)sv[1] * is2 + bb.y, 0.f);
    o[2] = (_Float16)fmaxf(is * a2 + (float)sv[2] * is2 + bb.z, 0.f);
    o[3] = (_Float16)fmaxf(is * a3 + (float)sv[3] * is2 + bb.w, 0.f);
    *(half4*)(x1 + (size_t)i * NG + c4) = o;
}

// ---- layer-2 agg on x1 at word positions only (W2 deferred): y = is*sum + is^2*x1_n
__global__ __launch_bounds__(256) void agg2_kernel(const _Float16* __restrict__ x1,
                                                   const int* __restrict__ off,
                                                   const int* __restrict__ csr_src,
                                                   const float* __restrict__ csr_w,
                                                   const float* __restrict__ inv_sqrt,
                                                   const int* __restrict__ word_ids,
                                                   float* __restrict__ y) {
    int wv = threadIdx.x >> 6, lane = threadIdx.x & 63;
    int p = blockIdx.x * 4 + wv;
    if (p >= NBS) return;
    int n = word_ids[p];
    int c4 = lane * 4;
    int s0 = off[n], s1 = off[n + 1];
    float a0 = 0.f, a1 = 0.f, a2 = 0.f, a3 = 0.f;
    int j = s0;
    for (; j + 8 <= s1; j += 8) {
        int sx[8];
        float wx[8];
        half4 vx[8];
#pragma unroll
        for (int u = 0; u < 8; ++u) { sx[u] = csr_src[j + u]; wx[u] = csr_w[j + u]; }
#pragma unroll
        for (int u = 0; u < 8; ++u) vx[u] = *(const half4*)(x1 + (size_t)sx[u] * NG + c4);
#pragma unroll
        for (int u = 0; u < 8; ++u) {
            a0 += wx[u] * (float)vx[u][0];
            a1 += wx[u] * (float)vx[u][1];
            a2 += wx[u] * (float)vx[u][2];
            a3 += wx[u] * (float)vx[u][3];
        }
    }
    for (; j < s1; ++j) {
        int s = csr_src[j];
        float w = csr_w[j];
        half4 hv = *(const half4*)(x1 + (size_t)s * NG + c4);
        a0 += w * (float)hv[0];
        a1 += w * (float)hv[1];
        a2 += w * (float)hv[2];
        a3 += w * (float)hv[3];
    }
    float is = inv_sqrt[n], is2 = is * is;
    half4 sv = *(const half4*)(x1 + (size_t)n * NG + c4);
    float4 o;
    o.x = is * a0 + (float)sv[0] * is2;
    o.y = is * a1 + (float)sv[1] * is2;
    o.z = is * a2 + (float)sv[2] * is2;
    o.w = is * a3 + (float)sv[3] * is2;
    *(float4*)(y + (size_t)p * NG + c4) = o;
}

extern "C" void kernel_launch(void* const* d_in, const int* in_sizes, int n_in,
                              void* d_out, int out_size, void* d_ws, size_t ws_size,
                              hipStream_t stream) {
    const float* emb = (const float*)d_in[0];       // V x D
    const float* W1  = (const float*)d_in[1];       // D x G
    const float* b1  = (const float*)d_in[2];       // G
    const float* W2  = (const float*)d_in[3];       // G x G
    const float* b2  = (const float*)d_in[4];       // G
    const int*   ei  = (const int*)d_in[5];         // 2 x E
    const int*   wid = (const int*)d_in[6];         // B x S
    float* out = (float*)d_out;

    char* w = (char*)d_ws;
    auto alloc = [&](size_t bytes) {
        void* p = (void*)w;
        w += (bytes + 255) & ~(size_t)255;
        return p;
    };
    int*    deg      = (int*)alloc((size_t)NV * 4);
    int*    off      = (int*)alloc((size_t)(NV + 1) * 4);
    float*  inv_sqrt = (float*)alloc((size_t)NV * 4);
    int*    bucket_count  = (int*)alloc((size_t)NBUCK * 4);
    int*    bucket_base   = (int*)alloc((size_t)(NBUCK + 1) * 4);
    int*    bucket_cursor = (int*)alloc((size_t)NBUCK * 4);
    int*    csr_src  = (int*)alloc((size_t)NE * 4);
    float*  csr_w    = (float*)alloc((size_t)NE * 4);
    int2*   bucket_rec = (int2*)alloc((size_t)NE * 8);
    ushort* W1T_h    = (ushort*)alloc((size_t)NG * NDP * 2);
    ushort* W1T_l    = (ushort*)alloc((size_t)NG * NDP * 2);
    ushort* W2T_h    = (ushort*)alloc((size_t)NG * NG * 2);
    ushort* W2T_l    = (ushort*)alloc((size_t)NG * NG * 2);
    _Float16* h1h    = (_Float16*)alloc((size_t)NV * NG * 2);
    _Float16* x1     = (_Float16*)alloc((size_t)NV * NG * 2);
    float*  y        = (float*)alloc((size_t)NBS * NG * 4);

    hipMemsetAsync(deg, 0, (size_t)NV * 4, stream);
    hipMemsetAsync(bucket_count, 0, (size_t)NBUCK * 4, stream);

    hist_kernel<<<(NE / 4 + 255) / 256, 256, 0, stream>>>(ei + NE, deg, bucket_count);
    scan_kernel<<<1, 1024, 0, stream>>>(deg, off, inv_sqrt,
                                        bucket_count, bucket_base, bucket_cursor);
    bucket_scatter<<<(NE + EPB - 1) / EPB, 256, 0, stream>>>(ei, bucket_cursor, bucket_rec);
    csr_place<<<NBUCK, 256, 0, stream>>>(bucket_rec, bucket_base, off, inv_sqrt,
                                         csr_src, csr_w);

    splitw_kernel<<<(NG * NDP + 255) / 256, 256, 0, stream>>>(W1, ND, NG, NDP, W1T_h, W1T_l);
    splitw_kernel<<<(NG * NG + 255) / 256, 256, 0, stream>>>(W2, NG, NG, NG, W2T_h, W2T_l);

    // h1 = emb @ W1  (fp16 out)
    {
        dim3 grid((NV + 127) / 128, NG / 128);
        gemm_mfma<false><<<grid, 256, 0, stream>>>(emb, ND, W1T_h, W1T_l, NDP,
                                                   NV, ND, NDP, h1h, nullptr, nullptr);
    }
    // x1 = relu(norm-agg(h1) + b1)  (fp16 out)
    agg1_kernel<<<(NV + 3) / 4, 256, 0, stream>>>(h1h, off, csr_src, csr_w, inv_sqrt, b1, x1);
    // y = norm-agg(x1) at word positions (fp32)
    agg2_kernel<<<(NBS + 3) / 4, 256, 0, stream>>>(x1, off, csr_src, csr_w, inv_sqrt, wid, y);
    // out = y @ W2 + b2  (fp32)
    {
        dim3 grid((NBS + 127) / 128, NG / 128);
        gemm_mfma<true><<<grid, 256, 0, stream>>>(y, NG, W2T_h, W2T_l, NG,
                                                  NBS, NG, NG, nullptr, out, b2);
    }
}

// Round 7
// 346.129 us; speedup vs baseline: 2.2007x; 1.2994x over previous
//
#include <hip/hip_runtime.h>
#include <hip/hip_bf16.h>

#define NV 50000
#define ND 300
#define NDP 320      // K of layer-1 padded to multiple of 32
#define NG 256
#define NE 1600000
#define NBS 4096     // B*S
#define NBUCK 196    // ceil(50000/256) buckets of 256 nodes (dst>>8)
#define EPB 8192     // edges per block in bucket_scatter

typedef short short8 __attribute__((ext_vector_type(8)));
typedef float f32x4 __attribute__((ext_vector_type(4)));
typedef _Float16 half4 __attribute__((ext_vector_type(4)));

__device__ __forceinline__ ushort f2bf(float f) {
    unsigned u = __builtin_bit_cast(unsigned, f);
    unsigned r = (u + 0x7fffu + ((u >> 16) & 1u)) >> 16;
    return (ushort)r;
}
__device__ __forceinline__ float bf2f(ushort h) {
    unsigned u = ((unsigned)h) << 16;
    return __builtin_bit_cast(float, u);
}

// ------- node-degree histogram + bucket histogram (LDS-aggregated) -------
__global__ __launch_bounds__(256) void hist_kernel(const int* __restrict__ dst,
                                                   int* __restrict__ deg,
                                                   int* __restrict__ bucket_count) {
    __shared__ int bh[NBUCK];
    int t = threadIdx.x;
    for (int b = t; b < NBUCK; b += 256) bh[b] = 0;
    __syncthreads();
    int i = blockIdx.x * 256 + t;
    if (i * 4 < NE) {
        int4 d = *(const int4*)(dst + i * 4);
        atomicAdd(&deg[d.x], 1);
        atomicAdd(&deg[d.y], 1);
        atomicAdd(&deg[d.z], 1);
        atomicAdd(&deg[d.w], 1);
        atomicAdd(&bh[d.x >> 8], 1);
        atomicAdd(&bh[d.y >> 8], 1);
        atomicAdd(&bh[d.z >> 8], 1);
        atomicAdd(&bh[d.w >> 8], 1);
    }
    __syncthreads();
    for (int b = t; b < NBUCK; b += 256)
        if (bh[b]) atomicAdd(&bucket_count[b], bh[b]);
}

// ------- bucket scan: one block, Hillis-Steele over 196 counts -------
__global__ __launch_bounds__(256) void bucket_scan(const int* __restrict__ bucket_count,
                                                   int* __restrict__ bucket_base,
                                                   int* __restrict__ bucket_cursor) {
    __shared__ int s[256];
    int t = threadIdx.x;
    int v = (t < NBUCK) ? bucket_count[t] : 0;
    s[t] = v;
    __syncthreads();
    for (int d = 1; d < 256; d <<= 1) {
        int x = (t >= d) ? s[t - d] : 0;
        __syncthreads();
        s[t] += x;
        __syncthreads();
    }
    int excl = s[t] - v;
    if (t < NBUCK) {
        bucket_base[t] = excl;
        bucket_cursor[t] = excl;
    }
    if (t == 255) bucket_base[NBUCK] = s[255];  // = NE
}

// ------- node scan: one block per bucket, LDS scan of 256 degrees -------
__global__ __launch_bounds__(256) void node_scan(const int* __restrict__ deg,
                                                 const int* __restrict__ bucket_base,
                                                 int* __restrict__ off,
                                                 float* __restrict__ inv_sqrt) {
    __shared__ int s[256];
    int b = blockIdx.x, t = threadIdx.x;
    int n = (b << 8) + t;
    int v = (n < NV) ? deg[n] : 0;
    s[t] = v;
    __syncthreads();
    for (int d = 1; d < 256; d <<= 1) {
        int x = (t >= d) ? s[t - d] : 0;
        __syncthreads();
        s[t] += x;
        __syncthreads();
    }
    int excl = s[t] - v + bucket_base[b];
    if (n < NV) {
        off[n] = excl;
        inv_sqrt[n] = rsqrtf((float)(v + 1));  // deg = 1 (self loop) + in-degree
    }
    if (b == NBUCK - 1 && t == 0) off[NV] = NE;
}

// ------- pass A: scatter edges into coarse dst-buckets (contiguous runs) -------
__global__ __launch_bounds__(256) void bucket_scatter(const int* __restrict__ ei,
                                                      int* __restrict__ bucket_cursor,
                                                      int2* __restrict__ rec) {
    __shared__ int cnt[NBUCK];
    __shared__ int basel[NBUCK];
    int t = threadIdx.x;
    int e0 = blockIdx.x * EPB;
    for (int b = t; b < NBUCK; b += 256) cnt[b] = 0;
    __syncthreads();
    for (int q = 0; q < EPB / 1024; ++q) {
        int i4 = e0 + q * 1024 + t * 4;
        if (i4 < NE) {
            int4 d = *(const int4*)(ei + NE + i4);
            atomicAdd(&cnt[d.x >> 8], 1);
            atomicAdd(&cnt[d.y >> 8], 1);
            atomicAdd(&cnt[d.z >> 8], 1);
            atomicAdd(&cnt[d.w >> 8], 1);
        }
    }
    __syncthreads();
    for (int b = t; b < NBUCK; b += 256) {
        int c = cnt[b];
        basel[b] = c ? atomicAdd(&bucket_cursor[b], c) : 0;
    }
    __syncthreads();
    for (int b = t; b < NBUCK; b += 256) cnt[b] = 0;
    __syncthreads();
    for (int q = 0; q < EPB / 1024; ++q) {
        int i4 = e0 + q * 1024 + t * 4;
        if (i4 < NE) {
            int4 s = *(const int4*)(ei + i4);
            int4 d = *(const int4*)(ei + NE + i4);
            int b0 = d.x >> 8, b1 = d.y >> 8, b2 = d.z >> 8, b3 = d.w >> 8;
            int r0 = atomicAdd(&cnt[b0], 1);
            rec[basel[b0] + r0] = make_int2(s.x, d.x);
            int r1 = atomicAdd(&cnt[b1], 1);
            rec[basel[b1] + r1] = make_int2(s.y, d.y);
            int r2 = atomicAdd(&cnt[b2], 1);
            rec[basel[b2] + r2] = make_int2(s.z, d.z);
            int r3 = atomicAdd(&cnt[b3], 1);
            rec[basel[b3] + r3] = make_int2(s.w, d.w);
        }
    }
}

// ------- pass B: one block per bucket, LDS cursors, L2-local CSR placement -------
__global__ __launch_bounds__(256) void csr_place(const int2* __restrict__ rec,
                                                 const int* __restrict__ bucket_base,
                                                 const int* __restrict__ off,
                                                 const float* __restrict__ inv_sqrt,
                                                 int* __restrict__ csr_src,
                                                 float* __restrict__ csr_w) {
    __shared__ int cur[256];
    int b = blockIdx.x, t = threadIdx.x;
    int n = (b << 8) + t;
    if (n < NV) cur[t] = off[n];
    __syncthreads();
    int r0 = bucket_base[b], r1 = bucket_base[b + 1];
    for (int i = r0 + t; i < r1; i += 256) {
        int2 e = rec[i];
        int p = atomicAdd(&cur[e.y & 255], 1);
        csr_src[p] = e.x;
        csr_w[p] = inv_sqrt[e.x];
    }
}

// ---------------- W (K x N) -> W^T hi/lo bf16 [N][ldk], zero-padded ----------------
__global__ __launch_bounds__(256) void splitw_kernel(const float* __restrict__ W,
                                                     int K, int N, int ldk,
                                                     ushort* __restrict__ Th,
                                                     ushort* __restrict__ Tl) {
    int idx = blockIdx.x * 256 + threadIdx.x;
    if (idx >= N * ldk) return;
    int n = idx / ldk, k = idx - n * ldk;
    float v = (k < K) ? W[(size_t)k * N + n] : 0.f;
    ushort h = f2bf(v);
    Th[idx] = h;
    Tl[idx] = f2bf(v - bf2f(h));
}

// ---- split-bf16 MFMA GEMM, 128x128 tile. A is fp32 [M][lda] (split in-kernel).
// B pre-transposed+split: BTh/BTl bf16 [NG][ldb]. OUT32: fp32 C + bias; else fp16 C.
template <bool OUT32>
__global__ __launch_bounds__(256) void gemm_mfma(const float* __restrict__ A,
                                                 int lda,
                                                 const ushort* __restrict__ BTh,
                                                 const ushort* __restrict__ BTl,
                                                 int ldb,
                                                 int M, int K, int KP,
                                                 _Float16* __restrict__ C16,
                                                 float* __restrict__ C32,
                                                 const float* __restrict__ bias) {
    __shared__ short Ah[128][40];
    __shared__ short Al[128][40];
    __shared__ short Bh[128][40];
    __shared__ short Bl[128][40];
    int t = threadIdx.x;
    int bm = blockIdx.x * 128;
    int bn = blockIdx.y * 128;
    int lane = t & 63, wv = t >> 6;
    int wm = (wv >> 1) * 64, wn = (wv & 1) * 64;
    int srow = t >> 1;          // staging row 0..127
    int skq = (t & 1) * 16;     // staging k offset {0,16}
    f32x4 acc[4][4];
#pragma unroll
    for (int mi = 0; mi < 4; ++mi)
#pragma unroll
        for (int ni = 0; ni < 4; ++ni) acc[mi][ni] = (f32x4)0.0f;

    for (int k0 = 0; k0 < KP; k0 += 32) {
        int gk = k0 + skq;
        {
            int gr = bm + srow;
            short8 vah[2], val[2];
            float v[16];
            if (gr < M && gk < K) {
                if (gk + 16 <= K) {
#pragma unroll
                    for (int q = 0; q < 4; ++q) {
                        float4 p = *(const float4*)(A + (size_t)gr * lda + gk + q * 4);
                        v[q * 4 + 0] = p.x; v[q * 4 + 1] = p.y;
                        v[q * 4 + 2] = p.z; v[q * 4 + 3] = p.w;
                    }
                } else {
#pragma unroll
                    for (int e = 0; e < 16; ++e)
                        v[e] = (gk + e < K) ? A[(size_t)gr * lda + gk + e] : 0.f;
                }
            } else {
#pragma unroll
                for (int e = 0; e < 16; ++e) v[e] = 0.f;
            }
#pragma unroll
            for (int e = 0; e < 16; ++e) {
                ushort h = f2bf(v[e]);
                ((short*)vah)[e] = (short)h;
                ((short*)val)[e] = (short)f2bf(v[e] - bf2f(h));
            }
            *(short8*)&Ah[srow][skq] = vah[0];
            *(short8*)&Ah[srow][skq + 8] = vah[1];
            *(short8*)&Al[srow][skq] = val[0];
            *(short8*)&Al[srow][skq + 8] = val[1];
        }
        {
            int nr = bn + srow;
            short8 bh0 = *(const short8*)(BTh + (size_t)nr * ldb + gk);
            short8 bh1 = *(const short8*)(BTh + (size_t)nr * ldb + gk + 8);
            short8 bl0 = *(const short8*)(BTl + (size_t)nr * ldb + gk);
            short8 bl1 = *(const short8*)(BTl + (size_t)nr * ldb + gk + 8);
            *(short8*)&Bh[srow][skq] = bh0;
            *(short8*)&Bh[srow][skq + 8] = bh1;
            *(short8*)&Bl[srow][skq] = bl0;
            *(short8*)&Bl[srow][skq + 8] = bl1;
        }
        __syncthreads();
        int m16 = lane & 15, kb = (lane >> 4) * 8;
        short8 a_h[4], a_l[4], b_h[4], b_l[4];
#pragma unroll
        for (int mi = 0; mi < 4; ++mi) {
            a_h[mi] = *(const short8*)&Ah[wm + mi * 16 + m16][kb];
            a_l[mi] = *(const short8*)&Al[wm + mi * 16 + m16][kb];
        }
#pragma unroll
        for (int ni = 0; ni < 4; ++ni) {
            b_h[ni] = *(const short8*)&Bh[wn + ni * 16 + m16][kb];
            b_l[ni] = *(const short8*)&Bl[wn + ni * 16 + m16][kb];
        }
#pragma unroll
        for (int mi = 0; mi < 4; ++mi)
#pragma unroll
            for (int ni = 0; ni < 4; ++ni) {
                acc[mi][ni] = __builtin_amdgcn_mfma_f32_16x16x32_bf16(a_h[mi], b_h[ni], acc[mi][ni], 0, 0, 0);
                acc[mi][ni] = __builtin_amdgcn_mfma_f32_16x16x32_bf16(a_h[mi], b_l[ni], acc[mi][ni], 0, 0, 0);
                acc[mi][ni] = __builtin_amdgcn_mfma_f32_16x16x32_bf16(a_l[mi], b_h[ni], acc[mi][ni], 0, 0, 0);
            }
        __syncthreads();
    }
    int m16 = lane & 15, rq = lane >> 4;
#pragma unroll
    for (int mi = 0; mi < 4; ++mi)
#pragma unroll
        for (int ni = 0; ni < 4; ++ni)
#pragma unroll
            for (int r = 0; r < 4; ++r) {
                int row = bm + wm + mi * 16 + rq * 4 + r;
                int col = bn + wn + ni * 16 + m16;
                if (row < M) {
                    if (OUT32)
                        C32[(size_t)row * NG + col] = acc[mi][ni][r] + bias[col];
                    else
                        C16[(size_t)row * NG + col] = (_Float16)acc[mi][ni][r];
                }
            }
}

// ---------------- layer-1 agg: wave per node, unroll-8 gather, fp16 out ----------
__global__ __launch_bounds__(256) void agg1_kernel(const _Float16* __restrict__ h1h,
                                                   const int* __restrict__ off,
                                                   const int* __restrict__ csr_src,
                                                   const float* __restrict__ csr_w,
                                                   const float* __restrict__ inv_sqrt,
                                                   const float* __restrict__ b1,
                                                   _Float16* __restrict__ x1) {
    int wv = threadIdx.x >> 6, lane = threadIdx.x & 63;
    int i = blockIdx.x * 4 + wv;
    if (i >= NV) return;
    int c4 = lane * 4;
    int s0 = off[i], s1 = off[i + 1];
    float a0 = 0.f, a1 = 0.f, a2 = 0.f, a3 = 0.f;
    int j = s0;
    for (; j + 8 <= s1; j += 8) {
        int sx[8];
        float wx[8];
        half4 vx[8];
#pragma unroll
        for (int u = 0; u < 8; ++u) { sx[u] = csr_src[j + u]; wx[u] = csr_w[j + u]; }
#pragma unroll
        for (int u = 0; u < 8; ++u) vx[u] = *(const half4*)(h1h + (size_t)sx[u] * NG + c4);
#pragma unroll
        for (int u = 0; u < 8; ++u) {
            a0 += wx[u] * (float)vx[u][0];
            a1 += wx[u] * (float)vx[u][1];
            a2 += wx[u] * (float)vx[u][2];
            a3 += wx[u] * (float)vx[u][3];
        }
    }
    for (; j < s1; ++j) {
        int s = csr_src[j];
        float w = csr_w[j];
        half4 hv = *(const half4*)(h1h + (size_t)s * NG + c4);
        a0 += w * (float)hv[0];
        a1 += w * (float)hv[1];
        a2 += w * (float)hv[2];
        a3 += w * (float)hv[3];
    }
    float is = inv_sqrt[i], is2 = is * is;
    half4 sv = *(const half4*)(h1h + (size_t)i * NG + c4);
    float4 bb = *(const float4*)(b1 + c4);
    half4 o;
    o[0] = (_Float16)fmaxf(is * a0 + (float)sv[0] * is2 + bb.x, 0.f);
    o[1] = (_Float16)fmaxf(is * a1 + (float)sv[1] * is2 + bb.y, 0.f);
    o[2] = (_Float16)fmaxf(is * a2 + (float)sv[2] * is2 + bb.z, 0.f);
    o[3] = (_Float16)fmaxf(is * a3 + (float)sv[3] * is2 + bb.w, 0.f);
    *(half4*)(x1 + (size_t)i * NG + c4) = o;
}

// ---- layer-2 agg on x1 at word positions only (W2 deferred): y = is*sum + is^2*x1_n
__global__ __launch_bounds__(256) void agg2_kernel(const _Float16* __restrict__ x1,
                                                   const int* __restrict__ off,
                                                   const int* __restrict__ csr_src,
                                                   const float* __restrict__ csr_w,
                                                   const float* __restrict__ inv_sqrt,
                                                   const int* __restrict__ word_ids,
                                                   float* __restrict__ y) {
    int wv = threadIdx.x >> 6, lane = threadIdx.x & 63;
    int p = blockIdx.x * 4 + wv;
    if (p >= NBS) return;
    int n = word_ids[p];
    int c4 = lane * 4;
    int s0 = off[n], s1 = off[n + 1];
    float a0 = 0.f, a1 = 0.f, a2 = 0.f, a3 = 0.f;
    int j = s0;
    for (; j + 8 <= s1; j += 8) {
        int sx[8];
        float wx[8];
        half4 vx[8];
#pragma unroll
        for (int u = 0; u < 8; ++u) { sx[u] = csr_src[j + u]; wx[u] = csr_w[j + u]; }
#pragma unroll
        for (int u = 0; u < 8; ++u) vx[u] = *(const half4*)(x1 + (size_t)sx[u] * NG + c4);
#pragma unroll
        for (int u = 0; u < 8; ++u) {
            a0 += wx[u] * (float)vx[u][0];
            a1 += wx[u] * (float)vx[u][1];
            a2 += wx[u] * (float)vx[u][2];
            a3 += wx[u] * (float)vx[u][3];
        }
    }
    for (; j < s1; ++j) {
        int s = csr_src[j];
        float w = csr_w[j];
        half4 hv = *(const half4*)(x1 + (size_t)s * NG + c4);
        a0 += w * (float)hv[0];
        a1 += w * (float)hv[1];
        a2 += w * (float)hv[2];
        a3 += w * (float)hv[3];
    }
    float is = inv_sqrt[n], is2 = is * is;
    half4 sv = *(const half4*)(x1 + (size_t)n * NG + c4);
    float4 o;
    o.x = is * a0 + (float)sv[0] * is2;
    o.y = is * a1 + (float)sv[1] * is2;
    o.z = is * a2 + (float)sv[2] * is2;
    o.w = is * a3 + (float)sv[3] * is2;
    *(float4*)(y + (size_t)p * NG + c4) = o;
}

extern "C" void kernel_launch(void* const* d_in, const int* in_sizes, int n_in,
                              void* d_out, int out_size, void* d_ws, size_t ws_size,
                              hipStream_t stream) {
    const float* emb = (const float*)d_in[0];       // V x D
    const float* W1  = (const float*)d_in[1];       // D x G
    const float* b1  = (const float*)d_in[2];       // G
    const float* W2  = (const float*)d_in[3];       // G x G
    const float* b2  = (const float*)d_in[4];       // G
    const int*   ei  = (const int*)d_in[5];         // 2 x E
    const int*   wid = (const int*)d_in[6];         // B x S
    float* out = (float*)d_out;

    char* w = (char*)d_ws;
    auto alloc = [&](size_t bytes) {
        void* p = (void*)w;
        w += (bytes + 255) & ~(size_t)255;
        return p;
    };
    int*    deg      = (int*)alloc((size_t)NV * 4);
    int*    off      = (int*)alloc((size_t)(NV + 1) * 4);
    float*  inv_sqrt = (float*)alloc((size_t)NV * 4);
    int*    bucket_count  = (int*)alloc((size_t)NBUCK * 4);
    int*    bucket_base   = (int*)alloc((size_t)(NBUCK + 1) * 4);
    int*    bucket_cursor = (int*)alloc((size_t)NBUCK * 4);
    int*    csr_src  = (int*)alloc((size_t)NE * 4);
    float*  csr_w    = (float*)alloc((size_t)NE * 4);
    int2*   bucket_rec = (int2*)alloc((size_t)NE * 8);
    ushort* W1T_h    = (ushort*)alloc((size_t)NG * NDP * 2);
    ushort* W1T_l    = (ushort*)alloc((size_t)NG * NDP * 2);
    ushort* W2T_h    = (ushort*)alloc((size_t)NG * NG * 2);
    ushort* W2T_l    = (ushort*)alloc((size_t)NG * NG * 2);
    _Float16* h1h    = (_Float16*)alloc((size_t)NV * NG * 2);
    _Float16* x1     = (_Float16*)alloc((size_t)NV * NG * 2);
    float*  y        = (float*)alloc((size_t)NBS * NG * 4);

    hipMemsetAsync(deg, 0, (size_t)NV * 4, stream);
    hipMemsetAsync(bucket_count, 0, (size_t)NBUCK * 4, stream);

    hist_kernel<<<(NE / 4 + 255) / 256, 256, 0, stream>>>(ei + NE, deg, bucket_count);
    bucket_scan<<<1, 256, 0, stream>>>(bucket_count, bucket_base, bucket_cursor);
    node_scan<<<NBUCK, 256, 0, stream>>>(deg, bucket_base, off, inv_sqrt);
    bucket_scatter<<<(NE + EPB - 1) / EPB, 256, 0, stream>>>(ei, bucket_cursor, bucket_rec);
    csr_place<<<NBUCK, 256, 0, stream>>>(bucket_rec, bucket_base, off, inv_sqrt,
                                         csr_src, csr_w);

    splitw_kernel<<<(NG * NDP + 255) / 256, 256, 0, stream>>>(W1, ND, NG, NDP, W1T_h, W1T_l);
    splitw_kernel<<<(NG * NG + 255) / 256, 256, 0, stream>>>(W2, NG, NG, NG, W2T_h, W2T_l);

    // h1 = emb @ W1  (fp16 out)
    {
        dim3 grid((NV + 127) / 128, NG / 128);
        gemm_mfma<false><<<grid, 256, 0, stream>>>(emb, ND, W1T_h, W1T_l, NDP,
                                                   NV, ND, NDP, h1h, nullptr, nullptr);
    }
    // x1 = relu(norm-agg(h1) + b1)  (fp16 out)
    agg1_kernel<<<(NV + 3) / 4, 256, 0, stream>>>(h1h, off, csr_src, csr_w, inv_sqrt, b1, x1);
    // y = norm-agg(x1) at word positions (fp32)
    agg2_kernel<<<(NBS + 3) / 4, 256, 0, stream>>>(x1, off, csr_src, csr_w, inv_sqrt, wid, y);
    // out = y @ W2 + b2  (fp32)
    {
        dim3 grid((NBS + 127) / 128, NG / 128);
        gemm_mfma<true><<<grid, 256, 0, stream>>>(y, NG, W2T_h, W2T_l, NG,
                                                  NBS, NG, NG, nullptr, out, b2);
    }
}

// Round 8
// 297.120 us; speedup vs baseline: 2.5637x; 1.1649x over previous
//
#include <hip/hip_runtime.h>
#include <hip/hip_bf16.h>

#define NV 50000
#define ND 300
#define NDP 320      // K of layer-1 padded to multiple of 32
#define NG 256
#define NE 1600000
#define NBS 4096     // B*S
#define NBUCK 196    // ceil(50000/256) buckets of 256 nodes (dst>>8)
#define EPB 8192     // edges per block in bucket_scatter

typedef short short8 __attribute__((ext_vector_type(8)));
typedef float f32x4 __attribute__((ext_vector_type(4)));
typedef float f32x2 __attribute__((ext_vector_type(2)));
typedef _Float16 half4 __attribute__((ext_vector_type(4)));

__device__ __forceinline__ ushort f2bf(float f) {
    unsigned u = __builtin_bit_cast(unsigned, f);
    unsigned r = (u + 0x7fffu + ((u >> 16) & 1u)) >> 16;
    return (ushort)r;
}
__device__ __forceinline__ float bf2f(ushort h) {
    unsigned u = ((unsigned)h) << 16;
    return __builtin_bit_cast(float, u);
}

// ------- node-degree histogram + bucket histogram (LDS-aggregated) -------
__global__ __launch_bounds__(256) void hist_kernel(const int* __restrict__ dst,
                                                   int* __restrict__ deg,
                                                   int* __restrict__ bucket_count) {
    __shared__ int bh[NBUCK];
    int t = threadIdx.x;
    for (int b = t; b < NBUCK; b += 256) bh[b] = 0;
    __syncthreads();
    int i = blockIdx.x * 256 + t;
    if (i * 4 < NE) {
        int4 d = *(const int4*)(dst + i * 4);
        atomicAdd(&deg[d.x], 1);
        atomicAdd(&deg[d.y], 1);
        atomicAdd(&deg[d.z], 1);
        atomicAdd(&deg[d.w], 1);
        atomicAdd(&bh[d.x >> 8], 1);
        atomicAdd(&bh[d.y >> 8], 1);
        atomicAdd(&bh[d.z >> 8], 1);
        atomicAdd(&bh[d.w >> 8], 1);
    }
    __syncthreads();
    for (int b = t; b < NBUCK; b += 256)
        if (bh[b]) atomicAdd(&bucket_count[b], bh[b]);
}

// ------- bucket scan: one block, Hillis-Steele over 196 counts -------
__global__ __launch_bounds__(256) void bucket_scan(const int* __restrict__ bucket_count,
                                                   int* __restrict__ bucket_base,
                                                   int* __restrict__ bucket_cursor) {
    __shared__ int s[256];
    int t = threadIdx.x;
    int v = (t < NBUCK) ? bucket_count[t] : 0;
    s[t] = v;
    __syncthreads();
    for (int d = 1; d < 256; d <<= 1) {
        int x = (t >= d) ? s[t - d] : 0;
        __syncthreads();
        s[t] += x;
        __syncthreads();
    }
    int excl = s[t] - v;
    if (t < NBUCK) {
        bucket_base[t] = excl;
        bucket_cursor[t] = excl;
    }
    if (t == 255) bucket_base[NBUCK] = s[255];  // = NE
}

// ------- node scan: one block per bucket, LDS scan of 256 degrees -------
__global__ __launch_bounds__(256) void node_scan(const int* __restrict__ deg,
                                                 const int* __restrict__ bucket_base,
                                                 int* __restrict__ off,
                                                 float* __restrict__ inv_sqrt) {
    __shared__ int s[256];
    int b = blockIdx.x, t = threadIdx.x;
    int n = (b << 8) + t;
    int v = (n < NV) ? deg[n] : 0;
    s[t] = v;
    __syncthreads();
    for (int d = 1; d < 256; d <<= 1) {
        int x = (t >= d) ? s[t - d] : 0;
        __syncthreads();
        s[t] += x;
        __syncthreads();
    }
    int excl = s[t] - v + bucket_base[b];
    if (n < NV) {
        off[n] = excl;
        inv_sqrt[n] = rsqrtf((float)(v + 1));  // deg = 1 (self loop) + in-degree
    }
    if (b == NBUCK - 1 && t == 0) off[NV] = NE;
}

// ------- pass A: scatter edges into coarse dst-buckets (contiguous runs) -------
__global__ __launch_bounds__(256) void bucket_scatter(const int* __restrict__ ei,
                                                      int* __restrict__ bucket_cursor,
                                                      int2* __restrict__ rec) {
    __shared__ int cnt[NBUCK];
    __shared__ int basel[NBUCK];
    int t = threadIdx.x;
    int e0 = blockIdx.x * EPB;
    for (int b = t; b < NBUCK; b += 256) cnt[b] = 0;
    __syncthreads();
    for (int q = 0; q < EPB / 1024; ++q) {
        int i4 = e0 + q * 1024 + t * 4;
        if (i4 < NE) {
            int4 d = *(const int4*)(ei + NE + i4);
            atomicAdd(&cnt[d.x >> 8], 1);
            atomicAdd(&cnt[d.y >> 8], 1);
            atomicAdd(&cnt[d.z >> 8], 1);
            atomicAdd(&cnt[d.w >> 8], 1);
        }
    }
    __syncthreads();
    for (int b = t; b < NBUCK; b += 256) {
        int c = cnt[b];
        basel[b] = c ? atomicAdd(&bucket_cursor[b], c) : 0;
    }
    __syncthreads();
    for (int b = t; b < NBUCK; b += 256) cnt[b] = 0;
    __syncthreads();
    for (int q = 0; q < EPB / 1024; ++q) {
        int i4 = e0 + q * 1024 + t * 4;
        if (i4 < NE) {
            int4 s = *(const int4*)(ei + i4);
            int4 d = *(const int4*)(ei + NE + i4);
            int b0 = d.x >> 8, b1 = d.y >> 8, b2 = d.z >> 8, b3 = d.w >> 8;
            int r0 = atomicAdd(&cnt[b0], 1);
            rec[basel[b0] + r0] = make_int2(s.x, d.x);
            int r1 = atomicAdd(&cnt[b1], 1);
            rec[basel[b1] + r1] = make_int2(s.y, d.y);
            int r2 = atomicAdd(&cnt[b2], 1);
            rec[basel[b2] + r2] = make_int2(s.z, d.z);
            int r3 = atomicAdd(&cnt[b3], 1);
            rec[basel[b3] + r3] = make_int2(s.w, d.w);
        }
    }
}

// ------- pass B: one block per bucket, LDS cursors, L2-local CSR placement -------
__global__ __launch_bounds__(256) void csr_place(const int2* __restrict__ rec,
                                                 const int* __restrict__ bucket_base,
                                                 const int* __restrict__ off,
                                                 const float* __restrict__ inv_sqrt,
                                                 int* __restrict__ csr_src,
                                                 float* __restrict__ csr_w) {
    __shared__ int cur[256];
    int b = blockIdx.x, t = threadIdx.x;
    int n = (b << 8) + t;
    if (n < NV) cur[t] = off[n];
    __syncthreads();
    int r0 = bucket_base[b], r1 = bucket_base[b + 1];
    for (int i = r0 + t; i < r1; i += 256) {
        int2 e = rec[i];
        int p = atomicAdd(&cur[e.y & 255], 1);
        csr_src[p] = e.x;
        csr_w[p] = inv_sqrt[e.x];
    }
}

// ---------------- W (K x N) -> W^T hi/lo bf16 [N][ldk], zero-padded ----------------
__global__ __launch_bounds__(256) void splitw_kernel(const float* __restrict__ W,
                                                     int K, int N, int ldk,
                                                     ushort* __restrict__ Th,
                                                     ushort* __restrict__ Tl) {
    int idx = blockIdx.x * 256 + threadIdx.x;
    if (idx >= N * ldk) return;
    int n = idx / ldk, k = idx - n * ldk;
    float v = (k < K) ? W[(size_t)k * N + n] : 0.f;
    ushort h = f2bf(v);
    Th[idx] = h;
    Tl[idx] = f2bf(v - bf2f(h));
}

// ---- split-bf16 MFMA GEMM, 128x128 tile. A is fp32 [M][lda] (split in-kernel).
// B pre-transposed+split: BTh/BTl bf16 [NG][ldb].
// OMODE: 0 = fp16 C16, 1 = fp32 C32 + bias, 2 = fp8(e4m3) C8 via HW cvt.
template <int OMODE>
__global__ __launch_bounds__(256) void gemm_mfma(const float* __restrict__ A,
                                                 int lda,
                                                 const ushort* __restrict__ BTh,
                                                 const ushort* __restrict__ BTl,
                                                 int ldb,
                                                 int M, int K, int KP,
                                                 _Float16* __restrict__ C16,
                                                 float* __restrict__ C32,
                                                 unsigned char* __restrict__ C8,
                                                 const float* __restrict__ bias) {
    __shared__ short Ah[128][40];
    __shared__ short Al[128][40];
    __shared__ short Bh[128][40];
    __shared__ short Bl[128][40];
    int t = threadIdx.x;
    int bm = blockIdx.x * 128;
    int bn = blockIdx.y * 128;
    int lane = t & 63, wv = t >> 6;
    int wm = (wv >> 1) * 64, wn = (wv & 1) * 64;
    int srow = t >> 1;          // staging row 0..127
    int skq = (t & 1) * 16;     // staging k offset {0,16}
    f32x4 acc[4][4];
#pragma unroll
    for (int mi = 0; mi < 4; ++mi)
#pragma unroll
        for (int ni = 0; ni < 4; ++ni) acc[mi][ni] = (f32x4)0.0f;

    for (int k0 = 0; k0 < KP; k0 += 32) {
        int gk = k0 + skq;
        {
            int gr = bm + srow;
            short8 vah[2], val[2];
            float v[16];
            if (gr < M && gk < K) {
                if (gk + 16 <= K) {
#pragma unroll
                    for (int q = 0; q < 4; ++q) {
                        float4 p = *(const float4*)(A + (size_t)gr * lda + gk + q * 4);
                        v[q * 4 + 0] = p.x; v[q * 4 + 1] = p.y;
                        v[q * 4 + 2] = p.z; v[q * 4 + 3] = p.w;
                    }
                } else {
#pragma unroll
                    for (int e = 0; e < 16; ++e)
                        v[e] = (gk + e < K) ? A[(size_t)gr * lda + gk + e] : 0.f;
                }
            } else {
#pragma unroll
                for (int e = 0; e < 16; ++e) v[e] = 0.f;
            }
#pragma unroll
            for (int e = 0; e < 16; ++e) {
                ushort h = f2bf(v[e]);
                ((short*)vah)[e] = (short)h;
                ((short*)val)[e] = (short)f2bf(v[e] - bf2f(h));
            }
            *(short8*)&Ah[srow][skq] = vah[0];
            *(short8*)&Ah[srow][skq + 8] = vah[1];
            *(short8*)&Al[srow][skq] = val[0];
            *(short8*)&Al[srow][skq + 8] = val[1];
        }
        {
            int nr = bn + srow;
            short8 bh0 = *(const short8*)(BTh + (size_t)nr * ldb + gk);
            short8 bh1 = *(const short8*)(BTh + (size_t)nr * ldb + gk + 8);
            short8 bl0 = *(const short8*)(BTl + (size_t)nr * ldb + gk);
            short8 bl1 = *(const short8*)(BTl + (size_t)nr * ldb + gk + 8);
            *(short8*)&Bh[srow][skq] = bh0;
            *(short8*)&Bh[srow][skq + 8] = bh1;
            *(short8*)&Bl[srow][skq] = bl0;
            *(short8*)&Bl[srow][skq + 8] = bl1;
        }
        __syncthreads();
        int m16 = lane & 15, kb = (lane >> 4) * 8;
        short8 a_h[4], a_l[4], b_h[4], b_l[4];
#pragma unroll
        for (int mi = 0; mi < 4; ++mi) {
            a_h[mi] = *(const short8*)&Ah[wm + mi * 16 + m16][kb];
            a_l[mi] = *(const short8*)&Al[wm + mi * 16 + m16][kb];
        }
#pragma unroll
        for (int ni = 0; ni < 4; ++ni) {
            b_h[ni] = *(const short8*)&Bh[wn + ni * 16 + m16][kb];
            b_l[ni] = *(const short8*)&Bl[wn + ni * 16 + m16][kb];
        }
#pragma unroll
        for (int mi = 0; mi < 4; ++mi)
#pragma unroll
            for (int ni = 0; ni < 4; ++ni) {
                acc[mi][ni] = __builtin_amdgcn_mfma_f32_16x16x32_bf16(a_h[mi], b_h[ni], acc[mi][ni], 0, 0, 0);
                acc[mi][ni] = __builtin_amdgcn_mfma_f32_16x16x32_bf16(a_h[mi], b_l[ni], acc[mi][ni], 0, 0, 0);
                acc[mi][ni] = __builtin_amdgcn_mfma_f32_16x16x32_bf16(a_l[mi], b_h[ni], acc[mi][ni], 0, 0, 0);
            }
        __syncthreads();
    }
    int m16 = lane & 15, rq = lane >> 4;
#pragma unroll
    for (int mi = 0; mi < 4; ++mi)
#pragma unroll
        for (int ni = 0; ni < 4; ++ni) {
            int row0 = bm + wm + mi * 16 + rq * 4;
            int col = bn + wn + ni * 16 + m16;
            if (OMODE == 2) {
                int p01 = __builtin_amdgcn_cvt_pk_fp8_f32(acc[mi][ni][0], acc[mi][ni][1], 0, false);
                int p23 = __builtin_amdgcn_cvt_pk_fp8_f32(acc[mi][ni][2], acc[mi][ni][3], 0, false);
                if (row0 + 0 < M) C8[(size_t)(row0 + 0) * NG + col] = (unsigned char)(p01 & 0xff);
                if (row0 + 1 < M) C8[(size_t)(row0 + 1) * NG + col] = (unsigned char)((p01 >> 8) & 0xff);
                if (row0 + 2 < M) C8[(size_t)(row0 + 2) * NG + col] = (unsigned char)(p23 & 0xff);
                if (row0 + 3 < M) C8[(size_t)(row0 + 3) * NG + col] = (unsigned char)((p23 >> 8) & 0xff);
            } else {
#pragma unroll
                for (int r = 0; r < 4; ++r) {
                    int row = row0 + r;
                    if (row < M) {
                        if (OMODE == 1)
                            C32[(size_t)row * NG + col] = acc[mi][ni][r] + bias[col];
                        else
                            C16[(size_t)row * NG + col] = (_Float16)acc[mi][ni][r];
                    }
                }
            }
        }
}

// ---- layer-1 agg: wave per node, unroll-8 fp8 gather (HW cvt), fp16 out ----
__global__ __launch_bounds__(256) void agg1_kernel(const unsigned char* __restrict__ h1f8,
                                                   const int* __restrict__ off,
                                                   const int* __restrict__ csr_src,
                                                   const float* __restrict__ csr_w,
                                                   const float* __restrict__ inv_sqrt,
                                                   const float* __restrict__ b1,
                                                   _Float16* __restrict__ x1) {
    int wv = threadIdx.x >> 6, lane = threadIdx.x & 63;
    int i = blockIdx.x * 4 + wv;
    if (i >= NV) return;
    int c4 = lane * 4;
    int s0 = off[i], s1 = off[i + 1];
    float a0 = 0.f, a1 = 0.f, a2 = 0.f, a3 = 0.f;
    int j = s0;
    for (; j + 8 <= s1; j += 8) {
        int sx[8];
        float wx[8];
        unsigned pk[8];
#pragma unroll
        for (int u = 0; u < 8; ++u) { sx[u] = csr_src[j + u]; wx[u] = csr_w[j + u]; }
#pragma unroll
        for (int u = 0; u < 8; ++u)
            pk[u] = *(const unsigned*)(h1f8 + (size_t)sx[u] * NG + c4);
#pragma unroll
        for (int u = 0; u < 8; ++u) {
            f32x2 v01 = __builtin_amdgcn_cvt_pk_f32_fp8(pk[u], false);
            f32x2 v23 = __builtin_amdgcn_cvt_pk_f32_fp8(pk[u], true);
            a0 += wx[u] * v01[0];
            a1 += wx[u] * v01[1];
            a2 += wx[u] * v23[0];
            a3 += wx[u] * v23[1];
        }
    }
    for (; j < s1; ++j) {
        int s = csr_src[j];
        float w = csr_w[j];
        unsigned pk = *(const unsigned*)(h1f8 + (size_t)s * NG + c4);
        f32x2 v01 = __builtin_amdgcn_cvt_pk_f32_fp8(pk, false);
        f32x2 v23 = __builtin_amdgcn_cvt_pk_f32_fp8(pk, true);
        a0 += w * v01[0];
        a1 += w * v01[1];
        a2 += w * v23[0];
        a3 += w * v23[1];
    }
    float is = inv_sqrt[i], is2 = is * is;
    unsigned pks = *(const unsigned*)(h1f8 + (size_t)i * NG + c4);
    f32x2 s01 = __builtin_amdgcn_cvt_pk_f32_fp8(pks, false);
    f32x2 s23 = __builtin_amdgcn_cvt_pk_f32_fp8(pks, true);
    float4 bb = *(const float4*)(b1 + c4);
    half4 o;
    o[0] = (_Float16)fmaxf(is * a0 + s01[0] * is2 + bb.x, 0.f);
    o[1] = (_Float16)fmaxf(is * a1 + s01[1] * is2 + bb.y, 0.f);
    o[2] = (_Float16)fmaxf(is * a2 + s23[0] * is2 + bb.z, 0.f);
    o[3] = (_Float16)fmaxf(is * a3 + s23[1] * is2 + bb.w, 0.f);
    *(half4*)(x1 + (size_t)i * NG + c4) = o;
}

// ---- layer-2 agg on x1 at word positions only (W2 deferred): y = is*sum + is^2*x1_n
__global__ __launch_bounds__(256) void agg2_kernel(const _Float16* __restrict__ x1,
                                                   const int* __restrict__ off,
                                                   const int* __restrict__ csr_src,
                                                   const float* __restrict__ csr_w,
                                                   const float* __restrict__ inv_sqrt,
                                                   const int* __restrict__ word_ids,
                                                   float* __restrict__ y) {
    int wv = threadIdx.x >> 6, lane = threadIdx.x & 63;
    int p = blockIdx.x * 4 + wv;
    if (p >= NBS) return;
    int n = word_ids[p];
    int c4 = lane * 4;
    int s0 = off[n], s1 = off[n + 1];
    float a0 = 0.f, a1 = 0.f, a2 = 0.f, a3 = 0.f;
    int j = s0;
    for (; j + 8 <= s1; j += 8) {
        int sx[8];
        float wx[8];
        half4 vx[8];
#pragma unroll
        for (int u = 0; u < 8; ++u) { sx[u] = csr_src[j + u]; wx[u] = csr_w[j + u]; }
#pragma unroll
        for (int u = 0; u < 8; ++u) vx[u] = *(const half4*)(x1 + (size_t)sx[u] * NG + c4);
#pragma unroll
        for (int u = 0; u < 8; ++u) {
            a0 += wx[u] * (float)vx[u][0];
            a1 += wx[u] * (float)vx[u][1];
            a2 += wx[u] * (float)vx[u][2];
            a3 += wx[u] * (float)vx[u][3];
        }
    }
    for (; j < s1; ++j) {
        int s = csr_src[j];
        float w = csr_w[j];
        half4 hv = *(const half4*)(x1 + (size_t)s * NG + c4);
        a0 += w * (float)hv[0];
        a1 += w * (float)hv[1];
        a2 += w * (float)hv[2];
        a3 += w * (float)hv[3];
    }
    float is = inv_sqrt[n], is2 = is * is;
    half4 sv = *(const half4*)(x1 + (size_t)n * NG + c4);
    float4 o;
    o.x = is * a0 + (float)sv[0] * is2;
    o.y = is * a1 + (float)sv[1] * is2;
    o.z = is * a2 + (float)sv[2] * is2;
    o.w = is * a3 + (float)sv[3] * is2;
    *(float4*)(y + (size_t)p * NG + c4) = o;
}

extern "C" void kernel_launch(void* const* d_in, const int* in_sizes, int n_in,
                              void* d_out, int out_size, void* d_ws, size_t ws_size,
                              hipStream_t stream) {
    const float* emb = (const float*)d_in[0];       // V x D
    const float* W1  = (const float*)d_in[1];       // D x G
    const float* b1  = (const float*)d_in[2];       // G
    const float* W2  = (const float*)d_in[3];       // G x G
    const float* b2  = (const float*)d_in[4];       // G
    const int*   ei  = (const int*)d_in[5];         // 2 x E
    const int*   wid = (const int*)d_in[6];         // B x S
    float* out = (float*)d_out;

    char* w = (char*)d_ws;
    auto alloc = [&](size_t bytes) {
        void* p = (void*)w;
        w += (bytes + 255) & ~(size_t)255;
        return p;
    };
    int*    deg      = (int*)alloc((size_t)NV * 4);
    int*    off      = (int*)alloc((size_t)(NV + 1) * 4);
    float*  inv_sqrt = (float*)alloc((size_t)NV * 4);
    int*    bucket_count  = (int*)alloc((size_t)NBUCK * 4);
    int*    bucket_base   = (int*)alloc((size_t)(NBUCK + 1) * 4);
    int*    bucket_cursor = (int*)alloc((size_t)NBUCK * 4);
    int*    csr_src  = (int*)alloc((size_t)NE * 4);
    float*  csr_w    = (float*)alloc((size_t)NE * 4);
    int2*   bucket_rec = (int2*)alloc((size_t)NE * 8);
    ushort* W1T_h    = (ushort*)alloc((size_t)NG * NDP * 2);
    ushort* W1T_l    = (ushort*)alloc((size_t)NG * NDP * 2);
    ushort* W2T_h    = (ushort*)alloc((size_t)NG * NG * 2);
    ushort* W2T_l    = (ushort*)alloc((size_t)NG * NG * 2);
    unsigned char* h1f8 = (unsigned char*)alloc((size_t)NV * NG);
    _Float16* x1     = (_Float16*)alloc((size_t)NV * NG * 2);
    float*  y        = (float*)alloc((size_t)NBS * NG * 4);

    hipMemsetAsync(deg, 0, (size_t)NV * 4, stream);
    hipMemsetAsync(bucket_count, 0, (size_t)NBUCK * 4, stream);

    hist_kernel<<<(NE / 4 + 255) / 256, 256, 0, stream>>>(ei + NE, deg, bucket_count);
    bucket_scan<<<1, 256, 0, stream>>>(bucket_count, bucket_base, bucket_cursor);
    node_scan<<<NBUCK, 256, 0, stream>>>(deg, bucket_base, off, inv_sqrt);
    bucket_scatter<<<(NE + EPB - 1) / EPB, 256, 0, stream>>>(ei, bucket_cursor, bucket_rec);
    csr_place<<<NBUCK, 256, 0, stream>>>(bucket_rec, bucket_base, off, inv_sqrt,
                                         csr_src, csr_w);

    splitw_kernel<<<(NG * NDP + 255) / 256, 256, 0, stream>>>(W1, ND, NG, NDP, W1T_h, W1T_l);
    splitw_kernel<<<(NG * NG + 255) / 256, 256, 0, stream>>>(W2, NG, NG, NG, W2T_h, W2T_l);

    // h1 = emb @ W1  (fp8 e4m3 out via HW cvt)
    {
        dim3 grid((NV + 127) / 128, NG / 128);
        gemm_mfma<2><<<grid, 256, 0, stream>>>(emb, ND, W1T_h, W1T_l, NDP,
                                               NV, ND, NDP, nullptr, nullptr, h1f8, nullptr);
    }
    // x1 = relu(norm-agg(h1) + b1)  (fp16 out)
    agg1_kernel<<<(NV + 3) / 4, 256, 0, stream>>>(h1f8, off, csr_src, csr_w, inv_sqrt, b1, x1);
    // y = norm-agg(x1) at word positions (fp32)
    agg2_kernel<<<(NBS + 3) / 4, 256, 0, stream>>>(x1, off, csr_src, csr_w, inv_sqrt, wid, y);
    // out = y @ W2 + b2  (fp32)
    {
        dim3 grid((NBS + 127) / 128, NG / 128);
        gemm_mfma<1><<<grid, 256, 0, stream>>>(y, NG, W2T_h, W2T_l, NG,
                                               NBS, NG, NG, nullptr, out, nullptr, b2);
    }
}

// Round 9
// 221.246 us; speedup vs baseline: 3.4429x; 1.3429x over previous
//
#include <hip/hip_runtime.h>
#include <hip/hip_bf16.h>

#define NV 50000
#define ND 300
#define NDP 320      // K of layer-1 padded to multiple of 32
#define NG 256
#define NE 1600000
#define NBS 4096     // B*S
#define NBUCK 196    // ceil(50000/256) buckets of 256 nodes (dst>>8)
#define EPB 8192     // edges per block in bucket_scatter
#define CPAD 16      // bucket counter pad: 16 ints = 64 B line per counter

typedef short short8 __attribute__((ext_vector_type(8)));
typedef float f32x4 __attribute__((ext_vector_type(4)));
typedef float f32x2 __attribute__((ext_vector_type(2)));
typedef _Float16 half4 __attribute__((ext_vector_type(4)));

__device__ __forceinline__ ushort f2bf(float f) {
    unsigned u = __builtin_bit_cast(unsigned, f);
    unsigned r = (u + 0x7fffu + ((u >> 16) & 1u)) >> 16;
    return (ushort)r;
}
__device__ __forceinline__ float bf2f(ushort h) {
    unsigned u = ((unsigned)h) << 16;
    return __builtin_bit_cast(float, u);
}

// ------- bucket-only histogram (LDS-aggregated, padded global counters) -------
__global__ __launch_bounds__(256) void hist_bucket(const int* __restrict__ dst,
                                                   int* __restrict__ bucket_count) {
    __shared__ int bh[NBUCK];
    int t = threadIdx.x;
    for (int b = t; b < NBUCK; b += 256) bh[b] = 0;
    __syncthreads();
    for (int i = blockIdx.x * 256 + t; i * 4 < NE; i += gridDim.x * 256) {
        int4 d = *(const int4*)(dst + i * 4);
        atomicAdd(&bh[d.x >> 8], 1);
        atomicAdd(&bh[d.y >> 8], 1);
        atomicAdd(&bh[d.z >> 8], 1);
        atomicAdd(&bh[d.w >> 8], 1);
    }
    __syncthreads();
    for (int b = t; b < NBUCK; b += 256)
        if (bh[b]) atomicAdd(&bucket_count[b * CPAD], bh[b]);
}

// ------- bucket scan: one block, Hillis-Steele over 196 padded counts -------
__global__ __launch_bounds__(256) void bucket_scan(const int* __restrict__ bucket_count,
                                                   int* __restrict__ bucket_base,
                                                   int* __restrict__ bucket_cursor) {
    __shared__ int s[256];
    int t = threadIdx.x;
    int v = (t < NBUCK) ? bucket_count[t * CPAD] : 0;
    s[t] = v;
    __syncthreads();
    for (int d = 1; d < 256; d <<= 1) {
        int x = (t >= d) ? s[t - d] : 0;
        __syncthreads();
        s[t] += x;
        __syncthreads();
    }
    int excl = s[t] - v;
    if (t < NBUCK) {
        bucket_base[t] = excl;
        bucket_cursor[t * CPAD] = excl;
    }
    if (t == 255) bucket_base[NBUCK] = s[255];  // = NE
}

// ------- pass A: scatter edges into coarse dst-buckets (contiguous runs) -------
__global__ __launch_bounds__(256) void bucket_scatter(const int* __restrict__ ei,
                                                      int* __restrict__ bucket_cursor,
                                                      int2* __restrict__ rec) {
    __shared__ int cnt[NBUCK];
    __shared__ int basel[NBUCK];
    int t = threadIdx.x;
    int e0 = blockIdx.x * EPB;
    for (int b = t; b < NBUCK; b += 256) cnt[b] = 0;
    __syncthreads();
    for (int q = 0; q < EPB / 1024; ++q) {
        int i4 = e0 + q * 1024 + t * 4;
        if (i4 < NE) {
            int4 d = *(const int4*)(ei + NE + i4);
            atomicAdd(&cnt[d.x >> 8], 1);
            atomicAdd(&cnt[d.y >> 8], 1);
            atomicAdd(&cnt[d.z >> 8], 1);
            atomicAdd(&cnt[d.w >> 8], 1);
        }
    }
    __syncthreads();
    for (int b = t; b < NBUCK; b += 256) {
        int c = cnt[b];
        basel[b] = c ? atomicAdd(&bucket_cursor[b * CPAD], c) : 0;
    }
    __syncthreads();
    for (int b = t; b < NBUCK; b += 256) cnt[b] = 0;
    __syncthreads();
    for (int q = 0; q < EPB / 1024; ++q) {
        int i4 = e0 + q * 1024 + t * 4;
        if (i4 < NE) {
            int4 s = *(const int4*)(ei + i4);
            int4 d = *(const int4*)(ei + NE + i4);
            int b0 = d.x >> 8, b1 = d.y >> 8, b2 = d.z >> 8, b3 = d.w >> 8;
            int r0 = atomicAdd(&cnt[b0], 1);
            rec[basel[b0] + r0] = make_int2(s.x, d.x);
            int r1 = atomicAdd(&cnt[b1], 1);
            rec[basel[b1] + r1] = make_int2(s.y, d.y);
            int r2 = atomicAdd(&cnt[b2], 1);
            rec[basel[b2] + r2] = make_int2(s.z, d.z);
            int r3 = atomicAdd(&cnt[b3], 1);
            rec[basel[b3] + r3] = make_int2(s.w, d.w);
        }
    }
}

// ------- pass B: per bucket — LDS degree count + scan + place (fused) -------
__global__ __launch_bounds__(256) void csr_build(const int2* __restrict__ rec,
                                                 const int* __restrict__ bucket_base,
                                                 int* __restrict__ off,
                                                 float* __restrict__ inv_sqrt,
                                                 int* __restrict__ csr_src) {
    __shared__ int degl[256];
    __shared__ int s[256];
    int b = blockIdx.x, t = threadIdx.x;
    degl[t] = 0;
    __syncthreads();
    int r0 = bucket_base[b], r1 = bucket_base[b + 1];
    for (int i = r0 + t; i < r1; i += 256)
        atomicAdd(&degl[rec[i].y & 255], 1);
    __syncthreads();
    int v = degl[t];
    s[t] = v;
    __syncthreads();
    for (int d = 1; d < 256; d <<= 1) {
        int x = (t >= d) ? s[t - d] : 0;
        __syncthreads();
        s[t] += x;
        __syncthreads();
    }
    int excl = s[t] - v + r0;
    int n = (b << 8) + t;
    if (n < NV) {
        off[n] = excl;
        inv_sqrt[n] = rsqrtf((float)(v + 1));  // deg = 1 (self loop) + in-degree
    }
    if (b == NBUCK - 1 && t == 0) off[NV] = NE;
    __syncthreads();
    degl[t] = excl;  // reuse as cursor
    __syncthreads();
    for (int i = r0 + t; i < r1; i += 256) {
        int2 e = rec[i];
        int p = atomicAdd(&degl[e.y & 255], 1);
        csr_src[p] = e.x;
    }
}

// ---------------- W (K x N) -> W^T hi/lo bf16 [N][ldk], zero-padded ----------------
__global__ __launch_bounds__(256) void splitw_kernel(const float* __restrict__ W,
                                                     int K, int N, int ldk,
                                                     ushort* __restrict__ Th,
                                                     ushort* __restrict__ Tl) {
    int idx = blockIdx.x * 256 + threadIdx.x;
    if (idx >= N * ldk) return;
    int n = idx / ldk, k = idx - n * ldk;
    float v = (k < K) ? W[(size_t)k * N + n] : 0.f;
    ushort h = f2bf(v);
    Th[idx] = h;
    Tl[idx] = f2bf(v - bf2f(h));
}

// ---- split-bf16 MFMA GEMM, 128x128 tile. A is fp32 [M][lda] (split in-kernel).
// B pre-transposed+split: BTh/BTl bf16 [NG][ldb].
// OMODE: 1 = fp32 C32 + bias, 2 = fp8(e4m3) C8 via HW cvt.
template <int OMODE>
__global__ __launch_bounds__(256) void gemm_mfma(const float* __restrict__ A,
                                                 int lda,
                                                 const ushort* __restrict__ BTh,
                                                 const ushort* __restrict__ BTl,
                                                 int ldb,
                                                 int M, int K, int KP,
                                                 float* __restrict__ C32,
                                                 unsigned char* __restrict__ C8,
                                                 const float* __restrict__ bias) {
    __shared__ short Ah[128][40];
    __shared__ short Al[128][40];
    __shared__ short Bh[128][40];
    __shared__ short Bl[128][40];
    int t = threadIdx.x;
    int bm = blockIdx.x * 128;
    int bn = blockIdx.y * 128;
    int lane = t & 63, wv = t >> 6;
    int wm = (wv >> 1) * 64, wn = (wv & 1) * 64;
    int srow = t >> 1;          // staging row 0..127
    int skq = (t & 1) * 16;     // staging k offset {0,16}
    f32x4 acc[4][4];
#pragma unroll
    for (int mi = 0; mi < 4; ++mi)
#pragma unroll
        for (int ni = 0; ni < 4; ++ni) acc[mi][ni] = (f32x4)0.0f;

    for (int k0 = 0; k0 < KP; k0 += 32) {
        int gk = k0 + skq;
        {
            int gr = bm + srow;
            short8 vah[2], val[2];
            float v[16];
            if (gr < M && gk < K) {
                if (gk + 16 <= K) {
#pragma unroll
                    for (int q = 0; q < 4; ++q) {
                        float4 p = *(const float4*)(A + (size_t)gr * lda + gk + q * 4);
                        v[q * 4 + 0] = p.x; v[q * 4 + 1] = p.y;
                        v[q * 4 + 2] = p.z; v[q * 4 + 3] = p.w;
                    }
                } else {
#pragma unroll
                    for (int e = 0; e < 16; ++e)
                        v[e] = (gk + e < K) ? A[(size_t)gr * lda + gk + e] : 0.f;
                }
            } else {
#pragma unroll
                for (int e = 0; e < 16; ++e) v[e] = 0.f;
            }
#pragma unroll
            for (int e = 0; e < 16; ++e) {
                ushort h = f2bf(v[e]);
                ((short*)vah)[e] = (short)h;
                ((short*)val)[e] = (short)f2bf(v[e] - bf2f(h));
            }
            *(short8*)&Ah[srow][skq] = vah[0];
            *(short8*)&Ah[srow][skq + 8] = vah[1];
            *(short8*)&Al[srow][skq] = val[0];
            *(short8*)&Al[srow][skq + 8] = val[1];
        }
        {
            int nr = bn + srow;
            short8 bh0 = *(const short8*)(BTh + (size_t)nr * ldb + gk);
            short8 bh1 = *(const short8*)(BTh + (size_t)nr * ldb + gk + 8);
            short8 bl0 = *(const short8*)(BTl + (size_t)nr * ldb + gk);
            short8 bl1 = *(const short8*)(BTl + (size_t)nr * ldb + gk + 8);
            *(short8*)&Bh[srow][skq] = bh0;
            *(short8*)&Bh[srow][skq + 8] = bh1;
            *(short8*)&Bl[srow][skq] = bl0;
            *(short8*)&Bl[srow][skq + 8] = bl1;
        }
        __syncthreads();
        int m16 = lane & 15, kb = (lane >> 4) * 8;
        short8 a_h[4], a_l[4], b_h[4], b_l[4];
#pragma unroll
        for (int mi = 0; mi < 4; ++mi) {
            a_h[mi] = *(const short8*)&Ah[wm + mi * 16 + m16][kb];
            a_l[mi] = *(const short8*)&Al[wm + mi * 16 + m16][kb];
        }
#pragma unroll
        for (int ni = 0; ni < 4; ++ni) {
            b_h[ni] = *(const short8*)&Bh[wn + ni * 16 + m16][kb];
            b_l[ni] = *(const short8*)&Bl[wn + ni * 16 + m16][kb];
        }
#pragma unroll
        for (int mi = 0; mi < 4; ++mi)
#pragma unroll
            for (int ni = 0; ni < 4; ++ni) {
                acc[mi][ni] = __builtin_amdgcn_mfma_f32_16x16x32_bf16(a_h[mi], b_h[ni], acc[mi][ni], 0, 0, 0);
                acc[mi][ni] = __builtin_amdgcn_mfma_f32_16x16x32_bf16(a_h[mi], b_l[ni], acc[mi][ni], 0, 0, 0);
                acc[mi][ni] = __builtin_amdgcn_mfma_f32_16x16x32_bf16(a_l[mi], b_h[ni], acc[mi][ni], 0, 0, 0);
            }
        __syncthreads();
    }
    int m16 = lane & 15, rq = lane >> 4;
#pragma unroll
    for (int mi = 0; mi < 4; ++mi)
#pragma unroll
        for (int ni = 0; ni < 4; ++ni) {
            int row0 = bm + wm + mi * 16 + rq * 4;
            int col = bn + wn + ni * 16 + m16;
            if (OMODE == 2) {
                int p01 = __builtin_amdgcn_cvt_pk_fp8_f32(acc[mi][ni][0], acc[mi][ni][1], 0, false);
                int p23 = __builtin_amdgcn_cvt_pk_fp8_f32(acc[mi][ni][2], acc[mi][ni][3], 0, false);
                if (row0 + 0 < M) C8[(size_t)(row0 + 0) * NG + col] = (unsigned char)(p01 & 0xff);
                if (row0 + 1 < M) C8[(size_t)(row0 + 1) * NG + col] = (unsigned char)((p01 >> 8) & 0xff);
                if (row0 + 2 < M) C8[(size_t)(row0 + 2) * NG + col] = (unsigned char)(p23 & 0xff);
                if (row0 + 3 < M) C8[(size_t)(row0 + 3) * NG + col] = (unsigned char)((p23 >> 8) & 0xff);
            } else {
#pragma unroll
                for (int r = 0; r < 4; ++r) {
                    int row = row0 + r;
                    if (row < M)
                        C32[(size_t)row * NG + col] = acc[mi][ni][r] + bias[col];
                }
            }
        }
}

// ---- layer-1 agg: wave per node, unroll-8 fp8 gather (HW cvt), inline inv_sqrt[src] ----
__global__ __launch_bounds__(256) void agg1_kernel(const unsigned char* __restrict__ h1f8,
                                                   const int* __restrict__ off,
                                                   const int* __restrict__ csr_src,
                                                   const float* __restrict__ inv_sqrt,
                                                   const float* __restrict__ b1,
                                                   _Float16* __restrict__ x1) {
    int wv = threadIdx.x >> 6, lane = threadIdx.x & 63;
    int i = blockIdx.x * 4 + wv;
    if (i >= NV) return;
    int c4 = lane * 4;
    int s0 = off[i], s1 = off[i + 1];
    float a0 = 0.f, a1 = 0.f, a2 = 0.f, a3 = 0.f;
    int j = s0;
    for (; j + 8 <= s1; j += 8) {
        int sx[8];
        float wx[8];
        unsigned pk[8];
#pragma unroll
        for (int u = 0; u < 8; ++u) sx[u] = csr_src[j + u];
#pragma unroll
        for (int u = 0; u < 8; ++u) {
            wx[u] = inv_sqrt[sx[u]];
            pk[u] = *(const unsigned*)(h1f8 + (size_t)sx[u] * NG + c4);
        }
#pragma unroll
        for (int u = 0; u < 8; ++u) {
            f32x2 v01 = __builtin_amdgcn_cvt_pk_f32_fp8(pk[u], false);
            f32x2 v23 = __builtin_amdgcn_cvt_pk_f32_fp8(pk[u], true);
            a0 += wx[u] * v01[0];
            a1 += wx[u] * v01[1];
            a2 += wx[u] * v23[0];
            a3 += wx[u] * v23[1];
        }
    }
    for (; j < s1; ++j) {
        int s = csr_src[j];
        float w = inv_sqrt[s];
        unsigned pk = *(const unsigned*)(h1f8 + (size_t)s * NG + c4);
        f32x2 v01 = __builtin_amdgcn_cvt_pk_f32_fp8(pk, false);
        f32x2 v23 = __builtin_amdgcn_cvt_pk_f32_fp8(pk, true);
        a0 += w * v01[0];
        a1 += w * v01[1];
        a2 += w * v23[0];
        a3 += w * v23[1];
    }
    float is = inv_sqrt[i], is2 = is * is;
    unsigned pks = *(const unsigned*)(h1f8 + (size_t)i * NG + c4);
    f32x2 s01 = __builtin_amdgcn_cvt_pk_f32_fp8(pks, false);
    f32x2 s23 = __builtin_amdgcn_cvt_pk_f32_fp8(pks, true);
    float4 bb = *(const float4*)(b1 + c4);
    half4 o;
    o[0] = (_Float16)fmaxf(is * a0 + s01[0] * is2 + bb.x, 0.f);
    o[1] = (_Float16)fmaxf(is * a1 + s01[1] * is2 + bb.y, 0.f);
    o[2] = (_Float16)fmaxf(is * a2 + s23[0] * is2 + bb.z, 0.f);
    o[3] = (_Float16)fmaxf(is * a3 + s23[1] * is2 + bb.w, 0.f);
    *(half4*)(x1 + (size_t)i * NG + c4) = o;
}

// ---- layer-2 agg on x1 at word positions only (W2 deferred): y = is*sum + is^2*x1_n
__global__ __launch_bounds__(256) void agg2_kernel(const _Float16* __restrict__ x1,
                                                   const int* __restrict__ off,
                                                   const int* __restrict__ csr_src,
                                                   const float* __restrict__ inv_sqrt,
                                                   const int* __restrict__ word_ids,
                                                   float* __restrict__ y) {
    int wv = threadIdx.x >> 6, lane = threadIdx.x & 63;
    int p = blockIdx.x * 4 + wv;
    if (p >= NBS) return;
    int n = word_ids[p];
    int c4 = lane * 4;
    int s0 = off[n], s1 = off[n + 1];
    float a0 = 0.f, a1 = 0.f, a2 = 0.f, a3 = 0.f;
    int j = s0;
    for (; j + 8 <= s1; j += 8) {
        int sx[8];
        float wx[8];
        half4 vx[8];
#pragma unroll
        for (int u = 0; u < 8; ++u) sx[u] = csr_src[j + u];
#pragma unroll
        for (int u = 0; u < 8; ++u) {
            wx[u] = inv_sqrt[sx[u]];
            vx[u] = *(const half4*)(x1 + (size_t)sx[u] * NG + c4);
        }
#pragma unroll
        for (int u = 0; u < 8; ++u) {
            a0 += wx[u] * (float)vx[u][0];
            a1 += wx[u] * (float)vx[u][1];
            a2 += wx[u] * (float)vx[u][2];
            a3 += wx[u] * (float)vx[u][3];
        }
    }
    for (; j < s1; ++j) {
        int s = csr_src[j];
        float w = inv_sqrt[s];
        half4 hv = *(const half4*)(x1 + (size_t)s * NG + c4);
        a0 += w * (float)hv[0];
        a1 += w * (float)hv[1];
        a2 += w * (float)hv[2];
        a3 += w * (float)hv[3];
    }
    float is = inv_sqrt[n], is2 = is * is;
    half4 sv = *(const half4*)(x1 + (size_t)n * NG + c4);
    float4 o;
    o.x = is * a0 + (float)sv[0] * is2;
    o.y = is * a1 + (float)sv[1] * is2;
    o.z = is * a2 + (float)sv[2] * is2;
    o.w = is * a3 + (float)sv[3] * is2;
    *(float4*)(y + (size_t)p * NG + c4) = o;
}

extern "C" void kernel_launch(void* const* d_in, const int* in_sizes, int n_in,
                              void* d_out, int out_size, void* d_ws, size_t ws_size,
                              hipStream_t stream) {
    const float* emb = (const float*)d_in[0];       // V x D
    const float* W1  = (const float*)d_in[1];       // D x G
    const float* b1  = (const float*)d_in[2];       // G
    const float* W2  = (const float*)d_in[3];       // G x G
    const float* b2  = (const float*)d_in[4];       // G
    const int*   ei  = (const int*)d_in[5];         // 2 x E
    const int*   wid = (const int*)d_in[6];         // B x S
    float* out = (float*)d_out;

    char* w = (char*)d_ws;
    auto alloc = [&](size_t bytes) {
        void* p = (void*)w;
        w += (bytes + 255) & ~(size_t)255;
        return p;
    };
    int*    off      = (int*)alloc((size_t)(NV + 1) * 4);
    float*  inv_sqrt = (float*)alloc((size_t)NV * 4);
    int*    bucket_count  = (int*)alloc((size_t)NBUCK * CPAD * 4);
    int*    bucket_base   = (int*)alloc((size_t)(NBUCK + 1) * 4);
    int*    bucket_cursor = (int*)alloc((size_t)NBUCK * CPAD * 4);
    int*    csr_src  = (int*)alloc((size_t)NE * 4);
    int2*   bucket_rec = (int2*)alloc((size_t)NE * 8);
    ushort* W1T_h    = (ushort*)alloc((size_t)NG * NDP * 2);
    ushort* W1T_l    = (ushort*)alloc((size_t)NG * NDP * 2);
    ushort* W2T_h    = (ushort*)alloc((size_t)NG * NG * 2);
    ushort* W2T_l    = (ushort*)alloc((size_t)NG * NG * 2);
    unsigned char* h1f8 = (unsigned char*)alloc((size_t)NV * NG);
    _Float16* x1     = (_Float16*)alloc((size_t)NV * NG * 2);
    float*  y        = (float*)alloc((size_t)NBS * NG * 4);

    hipMemsetAsync(bucket_count, 0, (size_t)NBUCK * CPAD * 4, stream);

    hist_bucket<<<1024, 256, 0, stream>>>(ei + NE, bucket_count);
    bucket_scan<<<1, 256, 0, stream>>>(bucket_count, bucket_base, bucket_cursor);
    bucket_scatter<<<(NE + EPB - 1) / EPB, 256, 0, stream>>>(ei, bucket_cursor, bucket_rec);
    csr_build<<<NBUCK, 256, 0, stream>>>(bucket_rec, bucket_base, off, inv_sqrt, csr_src);

    splitw_kernel<<<(NG * NDP + 255) / 256, 256, 0, stream>>>(W1, ND, NG, NDP, W1T_h, W1T_l);
    splitw_kernel<<<(NG * NG + 255) / 256, 256, 0, stream>>>(W2, NG, NG, NG, W2T_h, W2T_l);

    // h1 = emb @ W1  (fp8 e4m3 out via HW cvt)
    {
        dim3 grid((NV + 127) / 128, NG / 128);
        gemm_mfma<2><<<grid, 256, 0, stream>>>(emb, ND, W1T_h, W1T_l, NDP,
                                               NV, ND, NDP, nullptr, h1f8, nullptr);
    }
    // x1 = relu(norm-agg(h1) + b1)  (fp16 out)
    agg1_kernel<<<(NV + 3) / 4, 256, 0, stream>>>(h1f8, off, csr_src, inv_sqrt, b1, x1);
    // y = norm-agg(x1) at word positions (fp32)
    agg2_kernel<<<(NBS + 3) / 4, 256, 0, stream>>>(x1, off, csr_src, inv_sqrt, wid, y);
    // out = y @ W2 + b2  (fp32)
    {
        dim3 grid((NBS + 127) / 128, NG / 128);
        gemm_mfma<1><<<grid, 256, 0, stream>>>(y, NG, W2T_h, W2T_l, NG,
                                               NBS, NG, NG, out, nullptr, b2);
    }
}

// Round 10
// 213.938 us; speedup vs baseline: 3.5605x; 1.0342x over previous
//
#include <hip/hip_runtime.h>
#include <hip/hip_bf16.h>

#define NV 50000
#define ND 300
#define NDP 320      // K of layer-1 padded to multiple of 32
#define NG 256
#define NE 1600000
#define NBS 4096     // B*S
#define NBUCK 196    // ceil(50000/256) buckets of 256 nodes (dst>>8)
#define EPB 8192     // edges per block in bucket_scatter
#define CPAD 16      // bucket counter pad: 16 ints = 64 B line per counter

typedef short short8 __attribute__((ext_vector_type(8)));
typedef float f32x4 __attribute__((ext_vector_type(4)));
typedef float f32x2 __attribute__((ext_vector_type(2)));
typedef _Float16 half4 __attribute__((ext_vector_type(4)));

__device__ __forceinline__ ushort f2bf(float f) {
    unsigned u = __builtin_bit_cast(unsigned, f);
    unsigned r = (u + 0x7fffu + ((u >> 16) & 1u)) >> 16;
    return (ushort)r;
}
__device__ __forceinline__ float bf2f(ushort h) {
    unsigned u = ((unsigned)h) << 16;
    return __builtin_bit_cast(float, u);
}

// ------- bucket-only histogram (LDS-aggregated, padded global counters) -------
__global__ __launch_bounds__(256) void hist_bucket(const int* __restrict__ dst,
                                                   int* __restrict__ bucket_count) {
    __shared__ int bh[NBUCK];
    int t = threadIdx.x;
    for (int b = t; b < NBUCK; b += 256) bh[b] = 0;
    __syncthreads();
    for (int i = blockIdx.x * 256 + t; i * 4 < NE; i += gridDim.x * 256) {
        int4 d = *(const int4*)(dst + i * 4);
        atomicAdd(&bh[d.x >> 8], 1);
        atomicAdd(&bh[d.y >> 8], 1);
        atomicAdd(&bh[d.z >> 8], 1);
        atomicAdd(&bh[d.w >> 8], 1);
    }
    __syncthreads();
    for (int b = t; b < NBUCK; b += 256)
        if (bh[b]) atomicAdd(&bucket_count[b * CPAD], bh[b]);
}

// ------- bucket scan: one block, Hillis-Steele over 196 padded counts -------
__global__ __launch_bounds__(256) void bucket_scan(const int* __restrict__ bucket_count,
                                                   int* __restrict__ bucket_base,
                                                   int* __restrict__ bucket_cursor) {
    __shared__ int s[256];
    int t = threadIdx.x;
    int v = (t < NBUCK) ? bucket_count[t * CPAD] : 0;
    s[t] = v;
    __syncthreads();
    for (int d = 1; d < 256; d <<= 1) {
        int x = (t >= d) ? s[t - d] : 0;
        __syncthreads();
        s[t] += x;
        __syncthreads();
    }
    int excl = s[t] - v;
    if (t < NBUCK) {
        bucket_base[t] = excl;
        bucket_cursor[t * CPAD] = excl;
    }
    if (t == 255) bucket_base[NBUCK] = s[255];  // = NE
}

// ------- pass A: scatter edges into coarse dst-buckets, 4 B packed records -------
// rec = src (bits 0..15, V<65536) | (dst & 255) << 16
__global__ __launch_bounds__(256) void bucket_scatter(const int* __restrict__ ei,
                                                      int* __restrict__ bucket_cursor,
                                                      unsigned* __restrict__ rec) {
    __shared__ int cnt[NBUCK];
    __shared__ int basel[NBUCK];
    int t = threadIdx.x;
    int e0 = blockIdx.x * EPB;
    for (int b = t; b < NBUCK; b += 256) cnt[b] = 0;
    __syncthreads();
    for (int q = 0; q < EPB / 1024; ++q) {
        int i4 = e0 + q * 1024 + t * 4;
        if (i4 < NE) {
            int4 d = *(const int4*)(ei + NE + i4);
            atomicAdd(&cnt[d.x >> 8], 1);
            atomicAdd(&cnt[d.y >> 8], 1);
            atomicAdd(&cnt[d.z >> 8], 1);
            atomicAdd(&cnt[d.w >> 8], 1);
        }
    }
    __syncthreads();
    for (int b = t; b < NBUCK; b += 256) {
        int c = cnt[b];
        basel[b] = c ? atomicAdd(&bucket_cursor[b * CPAD], c) : 0;
    }
    __syncthreads();
    for (int b = t; b < NBUCK; b += 256) cnt[b] = 0;
    __syncthreads();
    for (int q = 0; q < EPB / 1024; ++q) {
        int i4 = e0 + q * 1024 + t * 4;
        if (i4 < NE) {
            int4 s = *(const int4*)(ei + i4);
            int4 d = *(const int4*)(ei + NE + i4);
            int b0 = d.x >> 8, b1 = d.y >> 8, b2 = d.z >> 8, b3 = d.w >> 8;
            int r0 = atomicAdd(&cnt[b0], 1);
            rec[basel[b0] + r0] = (unsigned)s.x | ((unsigned)(d.x & 255) << 16);
            int r1 = atomicAdd(&cnt[b1], 1);
            rec[basel[b1] + r1] = (unsigned)s.y | ((unsigned)(d.y & 255) << 16);
            int r2 = atomicAdd(&cnt[b2], 1);
            rec[basel[b2] + r2] = (unsigned)s.z | ((unsigned)(d.z & 255) << 16);
            int r3 = atomicAdd(&cnt[b3], 1);
            rec[basel[b3] + r3] = (unsigned)s.w | ((unsigned)(d.w & 255) << 16);
        }
    }
}

// ------- pass B: per bucket — LDS degree count + scan + place (fused) -------
__global__ __launch_bounds__(256) void csr_build(const unsigned* __restrict__ rec,
                                                 const int* __restrict__ bucket_base,
                                                 int* __restrict__ off,
                                                 float* __restrict__ inv_sqrt,
                                                 ushort* __restrict__ csr_src) {
    __shared__ int degl[256];
    __shared__ int s[256];
    int b = blockIdx.x, t = threadIdx.x;
    degl[t] = 0;
    __syncthreads();
    int r0 = bucket_base[b], r1 = bucket_base[b + 1];
    for (int i = r0 + t; i < r1; i += 256)
        atomicAdd(&degl[(rec[i] >> 16) & 255], 1);
    __syncthreads();
    int v = degl[t];
    s[t] = v;
    __syncthreads();
    for (int d = 1; d < 256; d <<= 1) {
        int x = (t >= d) ? s[t - d] : 0;
        __syncthreads();
        s[t] += x;
        __syncthreads();
    }
    int excl = s[t] - v + r0;
    int n = (b << 8) + t;
    if (n < NV) {
        off[n] = excl;
        inv_sqrt[n] = rsqrtf((float)(v + 1));  // deg = 1 (self loop) + in-degree
    }
    if (b == NBUCK - 1 && t == 0) off[NV] = NE;
    __syncthreads();
    degl[t] = excl;  // reuse as cursor
    __syncthreads();
    for (int i = r0 + t; i < r1; i += 256) {
        unsigned e = rec[i];
        int p = atomicAdd(&degl[(e >> 16) & 255], 1);
        csr_src[p] = (ushort)(e & 0xffff);
    }
}

// ---------------- W (K x N) -> W^T hi/lo bf16 [N][ldk], zero-padded ----------------
__global__ __launch_bounds__(256) void splitw_kernel(const float* __restrict__ W,
                                                     int K, int N, int ldk,
                                                     ushort* __restrict__ Th,
                                                     ushort* __restrict__ Tl) {
    int idx = blockIdx.x * 256 + threadIdx.x;
    if (idx >= N * ldk) return;
    int n = idx / ldk, k = idx - n * ldk;
    float v = (k < K) ? W[(size_t)k * N + n] : 0.f;
    ushort h = f2bf(v);
    Th[idx] = h;
    Tl[idx] = f2bf(v - bf2f(h));
}

// ---- MFMA GEMM, 128x128 tile, 2 split passes: A(bf16) x (B_h + B_l).
// A fp32 [M][lda] rounded to bf16 in staging. B pre-transposed+split bf16 [NG][ldb].
// OMODE: 1 = fp32 C32 + bias, 2 = fp8(e4m3) C8 via HW cvt.
template <int OMODE>
__global__ __launch_bounds__(256) void gemm_mfma(const float* __restrict__ A,
                                                 int lda,
                                                 const ushort* __restrict__ BTh,
                                                 const ushort* __restrict__ BTl,
                                                 int ldb,
                                                 int M, int K, int KP,
                                                 float* __restrict__ C32,
                                                 unsigned char* __restrict__ C8,
                                                 const float* __restrict__ bias) {
    __shared__ short Ah[128][40];
    __shared__ short Bh[128][40];
    __shared__ short Bl[128][40];
    int t = threadIdx.x;
    int bm = blockIdx.x * 128;
    int bn = blockIdx.y * 128;
    int lane = t & 63, wv = t >> 6;
    int wm = (wv >> 1) * 64, wn = (wv & 1) * 64;
    int srow = t >> 1;          // staging row 0..127
    int skq = (t & 1) * 16;     // staging k offset {0,16}
    f32x4 acc[4][4];
#pragma unroll
    for (int mi = 0; mi < 4; ++mi)
#pragma unroll
        for (int ni = 0; ni < 4; ++ni) acc[mi][ni] = (f32x4)0.0f;

    for (int k0 = 0; k0 < KP; k0 += 32) {
        int gk = k0 + skq;
        {
            int gr = bm + srow;
            short va[16];
            float v[16];
            if (gr < M && gk < K) {
                if (gk + 16 <= K) {
#pragma unroll
                    for (int q = 0; q < 4; ++q) {
                        float4 p = *(const float4*)(A + (size_t)gr * lda + gk + q * 4);
                        v[q * 4 + 0] = p.x; v[q * 4 + 1] = p.y;
                        v[q * 4 + 2] = p.z; v[q * 4 + 3] = p.w;
                    }
                } else {
#pragma unroll
                    for (int e = 0; e < 16; ++e)
                        v[e] = (gk + e < K) ? A[(size_t)gr * lda + gk + e] : 0.f;
                }
            } else {
#pragma unroll
                for (int e = 0; e < 16; ++e) v[e] = 0.f;
            }
#pragma unroll
            for (int e = 0; e < 16; ++e) va[e] = (short)f2bf(v[e]);
            *(short8*)&Ah[srow][skq] = *(short8*)&va[0];
            *(short8*)&Ah[srow][skq + 8] = *(short8*)&va[8];
        }
        {
            int nr = bn + srow;
            short8 bh0 = *(const short8*)(BTh + (size_t)nr * ldb + gk);
            short8 bh1 = *(const short8*)(BTh + (size_t)nr * ldb + gk + 8);
            short8 bl0 = *(const short8*)(BTl + (size_t)nr * ldb + gk);
            short8 bl1 = *(const short8*)(BTl + (size_t)nr * ldb + gk + 8);
            *(short8*)&Bh[srow][skq] = bh0;
            *(short8*)&Bh[srow][skq + 8] = bh1;
            *(short8*)&Bl[srow][skq] = bl0;
            *(short8*)&Bl[srow][skq + 8] = bl1;
        }
        __syncthreads();
        int m16 = lane & 15, kb = (lane >> 4) * 8;
        short8 a_h[4], b_h[4], b_l[4];
#pragma unroll
        for (int mi = 0; mi < 4; ++mi)
            a_h[mi] = *(const short8*)&Ah[wm + mi * 16 + m16][kb];
#pragma unroll
        for (int ni = 0; ni < 4; ++ni) {
            b_h[ni] = *(const short8*)&Bh[wn + ni * 16 + m16][kb];
            b_l[ni] = *(const short8*)&Bl[wn + ni * 16 + m16][kb];
        }
#pragma unroll
        for (int mi = 0; mi < 4; ++mi)
#pragma unroll
            for (int ni = 0; ni < 4; ++ni) {
                acc[mi][ni] = __builtin_amdgcn_mfma_f32_16x16x32_bf16(a_h[mi], b_h[ni], acc[mi][ni], 0, 0, 0);
                acc[mi][ni] = __builtin_amdgcn_mfma_f32_16x16x32_bf16(a_h[mi], b_l[ni], acc[mi][ni], 0, 0, 0);
            }
        __syncthreads();
    }
    int m16 = lane & 15, rq = lane >> 4;
#pragma unroll
    for (int mi = 0; mi < 4; ++mi)
#pragma unroll
        for (int ni = 0; ni < 4; ++ni) {
            int row0 = bm + wm + mi * 16 + rq * 4;
            int col = bn + wn + ni * 16 + m16;
            if (OMODE == 2) {
                int p01 = __builtin_amdgcn_cvt_pk_fp8_f32(acc[mi][ni][0], acc[mi][ni][1], 0, false);
                int p23 = __builtin_amdgcn_cvt_pk_fp8_f32(acc[mi][ni][2], acc[mi][ni][3], 0, false);
                if (row0 + 0 < M) C8[(size_t)(row0 + 0) * NG + col] = (unsigned char)(p01 & 0xff);
                if (row0 + 1 < M) C8[(size_t)(row0 + 1) * NG + col] = (unsigned char)((p01 >> 8) & 0xff);
                if (row0 + 2 < M) C8[(size_t)(row0 + 2) * NG + col] = (unsigned char)(p23 & 0xff);
                if (row0 + 3 < M) C8[(size_t)(row0 + 3) * NG + col] = (unsigned char)((p23 >> 8) & 0xff);
            } else {
#pragma unroll
                for (int r = 0; r < 4; ++r) {
                    int row = row0 + r;
                    if (row < M)
                        C32[(size_t)row * NG + col] = acc[mi][ni][r] + bias[col];
                }
            }
        }
}

// ---- layer-1 agg: wave per node, unroll-8 fp8 gather (HW cvt), inline inv_sqrt[src] ----
__global__ __launch_bounds__(256) void agg1_kernel(const unsigned char* __restrict__ h1f8,
                                                   const int* __restrict__ off,
                                                   const ushort* __restrict__ csr_src,
                                                   const float* __restrict__ inv_sqrt,
                                                   const float* __restrict__ b1,
                                                   _Float16* __restrict__ x1) {
    int wv = threadIdx.x >> 6, lane = threadIdx.x & 63;
    int i = blockIdx.x * 4 + wv;
    if (i >= NV) return;
    int c4 = lane * 4;
    int s0 = off[i], s1 = off[i + 1];
    float a0 = 0.f, a1 = 0.f, a2 = 0.f, a3 = 0.f;
    int j = s0;
    for (; j + 8 <= s1; j += 8) {
        int sx[8];
        float wx[8];
        unsigned pk[8];
#pragma unroll
        for (int u = 0; u < 8; ++u) sx[u] = csr_src[j + u];
#pragma unroll
        for (int u = 0; u < 8; ++u) {
            wx[u] = inv_sqrt[sx[u]];
            pk[u] = *(const unsigned*)(h1f8 + (size_t)sx[u] * NG + c4);
        }
#pragma unroll
        for (int u = 0; u < 8; ++u) {
            f32x2 v01 = __builtin_amdgcn_cvt_pk_f32_fp8(pk[u], false);
            f32x2 v23 = __builtin_amdgcn_cvt_pk_f32_fp8(pk[u], true);
            a0 += wx[u] * v01[0];
            a1 += wx[u] * v01[1];
            a2 += wx[u] * v23[0];
            a3 += wx[u] * v23[1];
        }
    }
    for (; j < s1; ++j) {
        int s = csr_src[j];
        float w = inv_sqrt[s];
        unsigned pk = *(const unsigned*)(h1f8 + (size_t)s * NG + c4);
        f32x2 v01 = __builtin_amdgcn_cvt_pk_f32_fp8(pk, false);
        f32x2 v23 = __builtin_amdgcn_cvt_pk_f32_fp8(pk, true);
        a0 += w * v01[0];
        a1 += w * v01[1];
        a2 += w * v23[0];
        a3 += w * v23[1];
    }
    float is = inv_sqrt[i], is2 = is * is;
    unsigned pks = *(const unsigned*)(h1f8 + (size_t)i * NG + c4);
    f32x2 s01 = __builtin_amdgcn_cvt_pk_f32_fp8(pks, false);
    f32x2 s23 = __builtin_amdgcn_cvt_pk_f32_fp8(pks, true);
    float4 bb = *(const float4*)(b1 + c4);
    half4 o;
    o[0] = (_Float16)fmaxf(is * a0 + s01[0] * is2 + bb.x, 0.f);
    o[1] = (_Float16)fmaxf(is * a1 + s01[1] * is2 + bb.y, 0.f);
    o[2] = (_Float16)fmaxf(is * a2 + s23[0] * is2 + bb.z, 0.f);
    o[3] = (_Float16)fmaxf(is * a3 + s23[1] * is2 + bb.w, 0.f);
    *(half4*)(x1 + (size_t)i * NG + c4) = o;
}

// ---- layer-2 agg on x1 at word positions only (W2 deferred): y = is*sum + is^2*x1_n
__global__ __launch_bounds__(256) void agg2_kernel(const _Float16* __restrict__ x1,
                                                   const int* __restrict__ off,
                                                   const ushort* __restrict__ csr_src,
                                                   const float* __restrict__ inv_sqrt,
                                                   const int* __restrict__ word_ids,
                                                   float* __restrict__ y) {
    int wv = threadIdx.x >> 6, lane = threadIdx.x & 63;
    int p = blockIdx.x * 4 + wv;
    if (p >= NBS) return;
    int n = word_ids[p];
    int c4 = lane * 4;
    int s0 = off[n], s1 = off[n + 1];
    float a0 = 0.f, a1 = 0.f, a2 = 0.f, a3 = 0.f;
    int j = s0;
    for (; j + 8 <= s1; j += 8) {
        int sx[8];
        float wx[8];
        half4 vx[8];
#pragma unroll
        for (int u = 0; u < 8; ++u) sx[u] = csr_src[j + u];
#pragma unroll
        for (int u = 0; u < 8; ++u) {
            wx[u] = inv_sqrt[sx[u]];
            vx[u] = *(const half4*)(x1 + (size_t)sx[u] * NG + c4);
        }
#pragma unroll
        for (int u = 0; u < 8; ++u) {
            a0 += wx[u] * (float)vx[u][0];
            a1 += wx[u] * (float)vx[u][1];
            a2 += wx[u] * (float)vx[u][2];
            a3 += wx[u] * (float)vx[u][3];
        }
    }
    for (; j < s1; ++j) {
        int s = csr_src[j];
        float w = inv_sqrt[s];
        half4 hv = *(const half4*)(x1 + (size_t)s * NG + c4);
        a0 += w * (float)hv[0];
        a1 += w * (float)hv[1];
        a2 += w * (float)hv[2];
        a3 += w * (float)hv[3];
    }
    float is = inv_sqrt[n], is2 = is * is;
    half4 sv = *(const half4*)(x1 + (size_t)n * NG + c4);
    float4 o;
    o.x = is * a0 + (float)sv[0] * is2;
    o.y = is * a1 + (float)sv[1] * is2;
    o.z = is * a2 + (float)sv[2] * is2;
    o.w = is * a3 + (float)sv[3] * is2;
    *(float4*)(y + (size_t)p * NG + c4) = o;
}

extern "C" void kernel_launch(void* const* d_in, const int* in_sizes, int n_in,
                              void* d_out, int out_size, void* d_ws, size_t ws_size,
                              hipStream_t stream) {
    const float* emb = (const float*)d_in[0];       // V x D
    const float* W1  = (const float*)d_in[1];       // D x G
    const float* b1  = (const float*)d_in[2];       // G
    const float* W2  = (const float*)d_in[3];       // G x G
    const float* b2  = (const float*)d_in[4];       // G
    const int*   ei  = (const int*)d_in[5];         // 2 x E
    const int*   wid = (const int*)d_in[6];         // B x S
    float* out = (float*)d_out;

    char* w = (char*)d_ws;
    auto alloc = [&](size_t bytes) {
        void* p = (void*)w;
        w += (bytes + 255) & ~(size_t)255;
        return p;
    };
    int*    off      = (int*)alloc((size_t)(NV + 1) * 4);
    float*  inv_sqrt = (float*)alloc((size_t)NV * 4);
    int*    bucket_count  = (int*)alloc((size_t)NBUCK * CPAD * 4);
    int*    bucket_base   = (int*)alloc((size_t)(NBUCK + 1) * 4);
    int*    bucket_cursor = (int*)alloc((size_t)NBUCK * CPAD * 4);
    ushort* csr_src  = (ushort*)alloc((size_t)NE * 2);
    unsigned* bucket_rec = (unsigned*)alloc((size_t)NE * 4);
    ushort* W1T_h    = (ushort*)alloc((size_t)NG * NDP * 2);
    ushort* W1T_l    = (ushort*)alloc((size_t)NG * NDP * 2);
    ushort* W2T_h    = (ushort*)alloc((size_t)NG * NG * 2);
    ushort* W2T_l    = (ushort*)alloc((size_t)NG * NG * 2);
    unsigned char* h1f8 = (unsigned char*)alloc((size_t)NV * NG);
    _Float16* x1     = (_Float16*)alloc((size_t)NV * NG * 2);
    float*  y        = (float*)alloc((size_t)NBS * NG * 4);

    hipMemsetAsync(bucket_count, 0, (size_t)NBUCK * CPAD * 4, stream);

    hist_bucket<<<1024, 256, 0, stream>>>(ei + NE, bucket_count);
    bucket_scan<<<1, 256, 0, stream>>>(bucket_count, bucket_base, bucket_cursor);
    bucket_scatter<<<(NE + EPB - 1) / EPB, 256, 0, stream>>>(ei, bucket_cursor, bucket_rec);
    csr_build<<<NBUCK, 256, 0, stream>>>(bucket_rec, bucket_base, off, inv_sqrt, csr_src);

    splitw_kernel<<<(NG * NDP + 255) / 256, 256, 0, stream>>>(W1, ND, NG, NDP, W1T_h, W1T_l);
    splitw_kernel<<<(NG * NG + 255) / 256, 256, 0, stream>>>(W2, NG, NG, NG, W2T_h, W2T_l);

    // h1 = emb @ W1  (fp8 e4m3 out via HW cvt)
    {
        dim3 grid((NV + 127) / 128, NG / 128);
        gemm_mfma<2><<<grid, 256, 0, stream>>>(emb, ND, W1T_h, W1T_l, NDP,
                                               NV, ND, NDP, nullptr, h1f8, nullptr);
    }
    // x1 = relu(norm-agg(h1) + b1)  (fp16 out)
    agg1_kernel<<<(NV + 3) / 4, 256, 0, stream>>>(h1f8, off, csr_src, inv_sqrt, b1, x1);
    // y = norm-agg(x1) at word positions (fp32)
    agg2_kernel<<<(NBS + 3) / 4, 256, 0, stream>>>(x1, off, csr_src, inv_sqrt, wid, y);
    // out = y @ W2 + b2  (fp32)
    {
        dim3 grid((NBS + 127) / 128, NG / 128);
        gemm_mfma<1><<<grid, 256, 0, stream>>>(y, NG, W2T_h, W2T_l, NG,
                                               NBS, NG, NG, out, nullptr, b2);
    }
}

// Round 11
// 197.012 us; speedup vs baseline: 3.8664x; 1.0859x over previous
//
#include <hip/hip_runtime.h>
#include <hip/hip_bf16.h>

#define NV 50000
#define ND 300
#define NDP 320      // K of layer-1 padded to multiple of 32
#define NG 256
#define NE 1600000
#define NBS 4096     // B*S
#define NBUCK 196    // ceil(50000/256) buckets of 256 nodes (dst>>8)
#define EPB 8192     // edges per block in bucket_scatter
#define CPAD 16      // bucket counter pad: 16 ints = 64 B line per counter
#define GEMM1_BLOCKS 782   // ceil(50000/128) * (256/128)

typedef short short8 __attribute__((ext_vector_type(8)));
typedef float f32x4 __attribute__((ext_vector_type(4)));
typedef float f32x2 __attribute__((ext_vector_type(2)));
typedef _Float16 half4 __attribute__((ext_vector_type(4)));

__device__ __forceinline__ ushort f2bf(float f) {
    unsigned u = __builtin_bit_cast(unsigned, f);
    unsigned r = (u + 0x7fffu + ((u >> 16) & 1u)) >> 16;
    return (ushort)r;
}
__device__ __forceinline__ float bf2f(ushort h) {
    unsigned u = ((unsigned)h) << 16;
    return __builtin_bit_cast(float, u);
}

// ------- bucket-only histogram (LDS-aggregated, padded global counters) -------
__global__ __launch_bounds__(256) void hist_bucket(const int* __restrict__ dst,
                                                   int* __restrict__ bucket_count) {
    __shared__ int bh[NBUCK];
    int t = threadIdx.x;
    for (int b = t; b < NBUCK; b += 256) bh[b] = 0;
    __syncthreads();
    for (int i = blockIdx.x * 256 + t; i * 4 < NE; i += gridDim.x * 256) {
        int4 d = *(const int4*)(dst + i * 4);
        atomicAdd(&bh[d.x >> 8], 1);
        atomicAdd(&bh[d.y >> 8], 1);
        atomicAdd(&bh[d.z >> 8], 1);
        atomicAdd(&bh[d.w >> 8], 1);
    }
    __syncthreads();
    for (int b = t; b < NBUCK; b += 256)
        if (bh[b]) atomicAdd(&bucket_count[b * CPAD], bh[b]);
}

// ------- bucket scan: one block, Hillis-Steele over 196 padded counts -------
__global__ __launch_bounds__(256) void bucket_scan(const int* __restrict__ bucket_count,
                                                   int* __restrict__ bucket_base,
                                                   int* __restrict__ bucket_cursor) {
    __shared__ int s[256];
    int t = threadIdx.x;
    int v = (t < NBUCK) ? bucket_count[t * CPAD] : 0;
    s[t] = v;
    __syncthreads();
    for (int d = 1; d < 256; d <<= 1) {
        int x = (t >= d) ? s[t - d] : 0;
        __syncthreads();
        s[t] += x;
        __syncthreads();
    }
    int excl = s[t] - v;
    if (t < NBUCK) {
        bucket_base[t] = excl;
        bucket_cursor[t * CPAD] = excl;
    }
    if (t == 255) bucket_base[NBUCK] = s[255];  // = NE
}

// ---- both weight transposes+splits in one launch ----
__global__ __launch_bounds__(256) void splitw_all(const float* __restrict__ W1,
                                                  const float* __restrict__ W2,
                                                  ushort* __restrict__ W1Th,
                                                  ushort* __restrict__ W1Tl,
                                                  ushort* __restrict__ W2Th,
                                                  ushort* __restrict__ W2Tl) {
    int idx = blockIdx.x * 256 + threadIdx.x;
    if (idx < NG * NDP) {
        int n = idx / NDP, k = idx - n * NDP;
        float v = (k < ND) ? W1[(size_t)k * NG + n] : 0.f;
        ushort h = f2bf(v);
        W1Th[idx] = h;
        W1Tl[idx] = f2bf(v - bf2f(h));
    } else {
        int j = idx - NG * NDP;
        if (j >= NG * NG) return;
        int n = j / NG, k = j - n * NG;
        float v = W2[(size_t)k * NG + n];
        ushort h = f2bf(v);
        W2Th[j] = h;
        W2Tl[j] = f2bf(v - bf2f(h));
    }
}

// ===== FUSED: gemm1 (h1 = emb@W1 -> fp8) blocks [0,782) ∥ bucket_scatter blocks [782,978) =====
__global__ __launch_bounds__(256) void gemm1_scatter(const float* __restrict__ A,   // emb
                                                     const ushort* __restrict__ BTh,
                                                     const ushort* __restrict__ BTl,
                                                     unsigned char* __restrict__ C8,
                                                     const int* __restrict__ ei,
                                                     int* __restrict__ bucket_cursor,
                                                     unsigned* __restrict__ rec) {
    int t = threadIdx.x;
    if (blockIdx.x < GEMM1_BLOCKS) {
        // ---------------- GEMM part: 128x128 tile, A bf16 x (B_h + B_l) ----------------
        __shared__ short Ah[128][40];
        __shared__ short Bh[128][40];
        __shared__ short Bl[128][40];
        const int lda = ND, ldb = NDP, M = NV, K = ND, KP = NDP;
        int bid = blockIdx.x;
        int bm = (bid % 391) * 128;
        int bn = (bid / 391) * 128;
        int lane = t & 63, wv = t >> 6;
        int wm = (wv >> 1) * 64, wn = (wv & 1) * 64;
        int srow = t >> 1;
        int skq = (t & 1) * 16;
        f32x4 acc[4][4];
#pragma unroll
        for (int mi = 0; mi < 4; ++mi)
#pragma unroll
            for (int ni = 0; ni < 4; ++ni) acc[mi][ni] = (f32x4)0.0f;

        for (int k0 = 0; k0 < KP; k0 += 32) {
            int gk = k0 + skq;
            {
                int gr = bm + srow;
                short va[16];
                float v[16];
                if (gr < M && gk < K) {
                    if (gk + 16 <= K) {
#pragma unroll
                        for (int q = 0; q < 4; ++q) {
                            float4 p = *(const float4*)(A + (size_t)gr * lda + gk + q * 4);
                            v[q * 4 + 0] = p.x; v[q * 4 + 1] = p.y;
                            v[q * 4 + 2] = p.z; v[q * 4 + 3] = p.w;
                        }
                    } else {
#pragma unroll
                        for (int e = 0; e < 16; ++e)
                            v[e] = (gk + e < K) ? A[(size_t)gr * lda + gk + e] : 0.f;
                    }
                } else {
#pragma unroll
                    for (int e = 0; e < 16; ++e) v[e] = 0.f;
                }
#pragma unroll
                for (int e = 0; e < 16; ++e) va[e] = (short)f2bf(v[e]);
                *(short8*)&Ah[srow][skq] = *(short8*)&va[0];
                *(short8*)&Ah[srow][skq + 8] = *(short8*)&va[8];
            }
            {
                int nr = bn + srow;
                short8 bh0 = *(const short8*)(BTh + (size_t)nr * ldb + gk);
                short8 bh1 = *(const short8*)(BTh + (size_t)nr * ldb + gk + 8);
                short8 bl0 = *(const short8*)(BTl + (size_t)nr * ldb + gk);
                short8 bl1 = *(const short8*)(BTl + (size_t)nr * ldb + gk + 8);
                *(short8*)&Bh[srow][skq] = bh0;
                *(short8*)&Bh[srow][skq + 8] = bh1;
                *(short8*)&Bl[srow][skq] = bl0;
                *(short8*)&Bl[srow][skq + 8] = bl1;
            }
            __syncthreads();
            int m16 = lane & 15, kb = (lane >> 4) * 8;
            short8 a_h[4], b_h[4], b_l[4];
#pragma unroll
            for (int mi = 0; mi < 4; ++mi)
                a_h[mi] = *(const short8*)&Ah[wm + mi * 16 + m16][kb];
#pragma unroll
            for (int ni = 0; ni < 4; ++ni) {
                b_h[ni] = *(const short8*)&Bh[wn + ni * 16 + m16][kb];
                b_l[ni] = *(const short8*)&Bl[wn + ni * 16 + m16][kb];
            }
#pragma unroll
            for (int mi = 0; mi < 4; ++mi)
#pragma unroll
                for (int ni = 0; ni < 4; ++ni) {
                    acc[mi][ni] = __builtin_amdgcn_mfma_f32_16x16x32_bf16(a_h[mi], b_h[ni], acc[mi][ni], 0, 0, 0);
                    acc[mi][ni] = __builtin_amdgcn_mfma_f32_16x16x32_bf16(a_h[mi], b_l[ni], acc[mi][ni], 0, 0, 0);
                }
            __syncthreads();
        }
        int m16 = lane & 15, rq = lane >> 4;
#pragma unroll
        for (int mi = 0; mi < 4; ++mi)
#pragma unroll
            for (int ni = 0; ni < 4; ++ni) {
                int row0 = bm + wm + mi * 16 + rq * 4;
                int col = bn + wn + ni * 16 + m16;
                int p01 = __builtin_amdgcn_cvt_pk_fp8_f32(acc[mi][ni][0], acc[mi][ni][1], 0, false);
                int p23 = __builtin_amdgcn_cvt_pk_fp8_f32(acc[mi][ni][2], acc[mi][ni][3], 0, false);
                if (row0 + 0 < M) C8[(size_t)(row0 + 0) * NG + col] = (unsigned char)(p01 & 0xff);
                if (row0 + 1 < M) C8[(size_t)(row0 + 1) * NG + col] = (unsigned char)((p01 >> 8) & 0xff);
                if (row0 + 2 < M) C8[(size_t)(row0 + 2) * NG + col] = (unsigned char)(p23 & 0xff);
                if (row0 + 3 < M) C8[(size_t)(row0 + 3) * NG + col] = (unsigned char)((p23 >> 8) & 0xff);
            }
    } else {
        // ---------------- scatter part: edges -> coarse dst-buckets, 4 B records ----------------
        __shared__ int cnt[NBUCK];
        __shared__ int basel[NBUCK];
        int e0 = (blockIdx.x - GEMM1_BLOCKS) * EPB;
        for (int b = t; b < NBUCK; b += 256) cnt[b] = 0;
        __syncthreads();
        for (int q = 0; q < EPB / 1024; ++q) {
            int i4 = e0 + q * 1024 + t * 4;
            if (i4 < NE) {
                int4 d = *(const int4*)(ei + NE + i4);
                atomicAdd(&cnt[d.x >> 8], 1);
                atomicAdd(&cnt[d.y >> 8], 1);
                atomicAdd(&cnt[d.z >> 8], 1);
                atomicAdd(&cnt[d.w >> 8], 1);
            }
        }
        __syncthreads();
        for (int b = t; b < NBUCK; b += 256) {
            int c = cnt[b];
            basel[b] = c ? atomicAdd(&bucket_cursor[b * CPAD], c) : 0;
        }
        __syncthreads();
        for (int b = t; b < NBUCK; b += 256) cnt[b] = 0;
        __syncthreads();
        for (int q = 0; q < EPB / 1024; ++q) {
            int i4 = e0 + q * 1024 + t * 4;
            if (i4 < NE) {
                int4 s = *(const int4*)(ei + i4);
                int4 d = *(const int4*)(ei + NE + i4);
                int b0 = d.x >> 8, b1 = d.y >> 8, b2 = d.z >> 8, b3 = d.w >> 8;
                int r0 = atomicAdd(&cnt[b0], 1);
                rec[basel[b0] + r0] = (unsigned)s.x | ((unsigned)(d.x & 255) << 16);
                int r1 = atomicAdd(&cnt[b1], 1);
                rec[basel[b1] + r1] = (unsigned)s.y | ((unsigned)(d.y & 255) << 16);
                int r2 = atomicAdd(&cnt[b2], 1);
                rec[basel[b2] + r2] = (unsigned)s.z | ((unsigned)(d.z & 255) << 16);
                int r3 = atomicAdd(&cnt[b3], 1);
                rec[basel[b3] + r3] = (unsigned)s.w | ((unsigned)(d.w & 255) << 16);
            }
        }
    }
}

// ------- per bucket — LDS degree count + scan + place (fused) -------
__global__ __launch_bounds__(256) void csr_build(const unsigned* __restrict__ rec,
                                                 const int* __restrict__ bucket_base,
                                                 int* __restrict__ off,
                                                 float* __restrict__ inv_sqrt,
                                                 ushort* __restrict__ csr_src) {
    __shared__ int degl[256];
    __shared__ int s[256];
    int b = blockIdx.x, t = threadIdx.x;
    degl[t] = 0;
    __syncthreads();
    int r0 = bucket_base[b], r1 = bucket_base[b + 1];
    for (int i = r0 + t; i < r1; i += 256)
        atomicAdd(&degl[(rec[i] >> 16) & 255], 1);
    __syncthreads();
    int v = degl[t];
    s[t] = v;
    __syncthreads();
    for (int d = 1; d < 256; d <<= 1) {
        int x = (t >= d) ? s[t - d] : 0;
        __syncthreads();
        s[t] += x;
        __syncthreads();
    }
    int excl = s[t] - v + r0;
    int n = (b << 8) + t;
    if (n < NV) {
        off[n] = excl;
        inv_sqrt[n] = rsqrtf((float)(v + 1));  // deg = 1 (self loop) + in-degree
    }
    if (b == NBUCK - 1 && t == 0) off[NV] = NE;
    __syncthreads();
    degl[t] = excl;  // reuse as cursor
    __syncthreads();
    for (int i = r0 + t; i < r1; i += 256) {
        unsigned e = rec[i];
        int p = atomicAdd(&degl[(e >> 16) & 255], 1);
        csr_src[p] = (ushort)(e & 0xffff);
    }
}

// ---- standalone MFMA GEMM (used for out = y @ W2 + b2), fp32 out + bias ----
__global__ __launch_bounds__(256) void gemm_out(const float* __restrict__ A,
                                                int lda,
                                                const ushort* __restrict__ BTh,
                                                const ushort* __restrict__ BTl,
                                                int ldb,
                                                int M, int K, int KP,
                                                float* __restrict__ C32,
                                                const float* __restrict__ bias) {
    __shared__ short Ah[128][40];
    __shared__ short Bh[128][40];
    __shared__ short Bl[128][40];
    int t = threadIdx.x;
    int bm = blockIdx.x * 128;
    int bn = blockIdx.y * 128;
    int lane = t & 63, wv = t >> 6;
    int wm = (wv >> 1) * 64, wn = (wv & 1) * 64;
    int srow = t >> 1;
    int skq = (t & 1) * 16;
    f32x4 acc[4][4];
#pragma unroll
    for (int mi = 0; mi < 4; ++mi)
#pragma unroll
        for (int ni = 0; ni < 4; ++ni) acc[mi][ni] = (f32x4)0.0f;

    for (int k0 = 0; k0 < KP; k0 += 32) {
        int gk = k0 + skq;
        {
            int gr = bm + srow;
            short va[16];
            float v[16];
            if (gr < M && gk < K) {
#pragma unroll
                for (int q = 0; q < 4; ++q) {
                    float4 p = *(const float4*)(A + (size_t)gr * lda + gk + q * 4);
                    v[q * 4 + 0] = p.x; v[q * 4 + 1] = p.y;
                    v[q * 4 + 2] = p.z; v[q * 4 + 3] = p.w;
                }
            } else {
#pragma unroll
                for (int e = 0; e < 16; ++e) v[e] = 0.f;
            }
#pragma unroll
            for (int e = 0; e < 16; ++e) va[e] = (short)f2bf(v[e]);
            *(short8*)&Ah[srow][skq] = *(short8*)&va[0];
            *(short8*)&Ah[srow][skq + 8] = *(short8*)&va[8];
        }
        {
            int nr = bn + srow;
            short8 bh0 = *(const short8*)(BTh + (size_t)nr * ldb + gk);
            short8 bh1 = *(const short8*)(BTh + (size_t)nr * ldb + gk + 8);
            short8 bl0 = *(const short8*)(BTl + (size_t)nr * ldb + gk);
            short8 bl1 = *(const short8*)(BTl + (size_t)nr * ldb + gk + 8);
            *(short8*)&Bh[srow][skq] = bh0;
            *(short8*)&Bh[srow][skq + 8] = bh1;
            *(short8*)&Bl[srow][skq] = bl0;
            *(short8*)&Bl[srow][skq + 8] = bl1;
        }
        __syncthreads();
        int m16 = lane & 15, kb = (lane >> 4) * 8;
        short8 a_h[4], b_h[4], b_l[4];
#pragma unroll
        for (int mi = 0; mi < 4; ++mi)
            a_h[mi] = *(const short8*)&Ah[wm + mi * 16 + m16][kb];
#pragma unroll
        for (int ni = 0; ni < 4; ++ni) {
            b_h[ni] = *(const short8*)&Bh[wn + ni * 16 + m16][kb];
            b_l[ni] = *(const short8*)&Bl[wn + ni * 16 + m16][kb];
        }
#pragma unroll
        for (int mi = 0; mi < 4; ++mi)
#pragma unroll
            for (int ni = 0; ni < 4; ++ni) {
                acc[mi][ni] = __builtin_amdgcn_mfma_f32_16x16x32_bf16(a_h[mi], b_h[ni], acc[mi][ni], 0, 0, 0);
                acc[mi][ni] = __builtin_amdgcn_mfma_f32_16x16x32_bf16(a_h[mi], b_l[ni], acc[mi][ni], 0, 0, 0);
            }
        __syncthreads();
    }
    int m16 = lane & 15, rq = lane >> 4;
#pragma unroll
    for (int mi = 0; mi < 4; ++mi)
#pragma unroll
        for (int ni = 0; ni < 4; ++ni) {
#pragma unroll
            for (int r = 0; r < 4; ++r) {
                int row = bm + wm + mi * 16 + rq * 4 + r;
                int col = bn + wn + ni * 16 + m16;
                if (row < M)
                    C32[(size_t)row * NG + col] = acc[mi][ni][r] + bias[col];
            }
        }
}

// ---- layer-1 agg: wave per node, unroll-16 fp8 gather (HW cvt) ----
__global__ __launch_bounds__(256) void agg1_kernel(const unsigned char* __restrict__ h1f8,
                                                   const int* __restrict__ off,
                                                   const ushort* __restrict__ csr_src,
                                                   const float* __restrict__ inv_sqrt,
                                                   const float* __restrict__ b1,
                                                   _Float16* __restrict__ x1) {
    int wv = threadIdx.x >> 6, lane = threadIdx.x & 63;
    int i = blockIdx.x * 4 + wv;
    if (i >= NV) return;
    int c4 = lane * 4;
    int s0 = off[i], s1 = off[i + 1];
    float a0 = 0.f, a1 = 0.f, a2 = 0.f, a3 = 0.f;
    int j = s0;
    for (; j + 16 <= s1; j += 16) {
        int sx[16];
        float wx[16];
        unsigned pk[16];
#pragma unroll
        for (int u = 0; u < 16; ++u) sx[u] = csr_src[j + u];
#pragma unroll
        for (int u = 0; u < 16; ++u) {
            wx[u] = inv_sqrt[sx[u]];
            pk[u] = *(const unsigned*)(h1f8 + (size_t)sx[u] * NG + c4);
        }
#pragma unroll
        for (int u = 0; u < 16; ++u) {
            f32x2 v01 = __builtin_amdgcn_cvt_pk_f32_fp8(pk[u], false);
            f32x2 v23 = __builtin_amdgcn_cvt_pk_f32_fp8(pk[u], true);
            a0 += wx[u] * v01[0];
            a1 += wx[u] * v01[1];
            a2 += wx[u] * v23[0];
            a3 += wx[u] * v23[1];
        }
    }
    for (; j + 4 <= s1; j += 4) {
        int sx[4];
        float wx[4];
        unsigned pk[4];
#pragma unroll
        for (int u = 0; u < 4; ++u) sx[u] = csr_src[j + u];
#pragma unroll
        for (int u = 0; u < 4; ++u) {
            wx[u] = inv_sqrt[sx[u]];
            pk[u] = *(const unsigned*)(h1f8 + (size_t)sx[u] * NG + c4);
        }
#pragma unroll
        for (int u = 0; u < 4; ++u) {
            f32x2 v01 = __builtin_amdgcn_cvt_pk_f32_fp8(pk[u], false);
            f32x2 v23 = __builtin_amdgcn_cvt_pk_f32_fp8(pk[u], true);
            a0 += wx[u] * v01[0];
            a1 += wx[u] * v01[1];
            a2 += wx[u] * v23[0];
            a3 += wx[u] * v23[1];
        }
    }
    for (; j < s1; ++j) {
        int s = csr_src[j];
        float w = inv_sqrt[s];
        unsigned pk = *(const unsigned*)(h1f8 + (size_t)s * NG + c4);
        f32x2 v01 = __builtin_amdgcn_cvt_pk_f32_fp8(pk, false);
        f32x2 v23 = __builtin_amdgcn_cvt_pk_f32_fp8(pk, true);
        a0 += w * v01[0];
        a1 += w * v01[1];
        a2 += w * v23[0];
        a3 += w * v23[1];
    }
    float is = inv_sqrt[i], is2 = is * is;
    unsigned pks = *(const unsigned*)(h1f8 + (size_t)i * NG + c4);
    f32x2 s01 = __builtin_amdgcn_cvt_pk_f32_fp8(pks, false);
    f32x2 s23 = __builtin_amdgcn_cvt_pk_f32_fp8(pks, true);
    float4 bb = *(const float4*)(b1 + c4);
    half4 o;
    o[0] = (_Float16)fmaxf(is * a0 + s01[0] * is2 + bb.x, 0.f);
    o[1] = (_Float16)fmaxf(is * a1 + s01[1] * is2 + bb.y, 0.f);
    o[2] = (_Float16)fmaxf(is * a2 + s23[0] * is2 + bb.z, 0.f);
    o[3] = (_Float16)fmaxf(is * a3 + s23[1] * is2 + bb.w, 0.f);
    *(half4*)(x1 + (size_t)i * NG + c4) = o;
}

// ---- layer-2 agg on x1 at word positions only (W2 deferred), unroll-16 ----
__global__ __launch_bounds__(256) void agg2_kernel(const _Float16* __restrict__ x1,
                                                   const int* __restrict__ off,
                                                   const ushort* __restrict__ csr_src,
                                                   const float* __restrict__ inv_sqrt,
                                                   const int* __restrict__ word_ids,
                                                   float* __restrict__ y) {
    int wv = threadIdx.x >> 6, lane = threadIdx.x & 63;
    int p = blockIdx.x * 4 + wv;
    if (p >= NBS) return;
    int n = word_ids[p];
    int c4 = lane * 4;
    int s0 = off[n], s1 = off[n + 1];
    float a0 = 0.f, a1 = 0.f, a2 = 0.f, a3 = 0.f;
    int j = s0;
    for (; j + 16 <= s1; j += 16) {
        int sx[16];
        float wx[16];
        half4 vx[16];
#pragma unroll
        for (int u = 0; u < 16; ++u) sx[u] = csr_src[j + u];
#pragma unroll
        for (int u = 0; u < 16; ++u) {
            wx[u] = inv_sqrt[sx[u]];
            vx[u] = *(const half4*)(x1 + (size_t)sx[u] * NG + c4);
        }
#pragma unroll
        for (int u = 0; u < 16; ++u) {
            a0 += wx[u] * (float)vx[u][0];
            a1 += wx[u] * (float)vx[u][1];
            a2 += wx[u] * (float)vx[u][2];
            a3 += wx[u] * (float)vx[u][3];
        }
    }
    for (; j + 4 <= s1; j += 4) {
        int sx[4];
        float wx[4];
        half4 vx[4];
#pragma unroll
        for (int u = 0; u < 4; ++u) sx[u] = csr_src[j + u];
#pragma unroll
        for (int u = 0; u < 4; ++u) {
            wx[u] = inv_sqrt[sx[u]];
            vx[u] = *(const half4*)(x1 + (size_t)sx[u] * NG + c4);
        }
#pragma unroll
        for (int u = 0; u < 4; ++u) {
            a0 += wx[u] * (float)vx[u][0];
            a1 += wx[u] * (float)vx[u][1];
            a2 += wx[u] * (float)vx[u][2];
            a3 += wx[u] * (float)vx[u][3];
        }
    }
    for (; j < s1; ++j) {
        int s = csr_src[j];
        float w = inv_sqrt[s];
        half4 hv = *(const half4*)(x1 + (size_t)s * NG + c4);
        a0 += w * (float)hv[0];
        a1 += w * (float)hv[1];
        a2 += w * (float)hv[2];
        a3 += w * (float)hv[3];
    }
    float is = inv_sqrt[n], is2 = is * is;
    half4 sv = *(const half4*)(x1 + (size_t)n * NG + c4);
    float4 o;
    o.x = is * a0 + (float)sv[0] * is2;
    o.y = is * a1 + (float)sv[1] * is2;
    o.z = is * a2 + (float)sv[2] * is2;
    o.w = is * a3 + (float)sv[3] * is2;
    *(float4*)(y + (size_t)p * NG + c4) = o;
}

extern "C" void kernel_launch(void* const* d_in, const int* in_sizes, int n_in,
                              void* d_out, int out_size, void* d_ws, size_t ws_size,
                              hipStream_t stream) {
    const float* emb = (const float*)d_in[0];       // V x D
    const float* W1  = (const float*)d_in[1];       // D x G
    const float* b1  = (const float*)d_in[2];       // G
    const float* W2  = (const float*)d_in[3];       // G x G
    const float* b2  = (const float*)d_in[4];       // G
    const int*   ei  = (const int*)d_in[5];         // 2 x E
    const int*   wid = (const int*)d_in[6];         // B x S
    float* out = (float*)d_out;

    char* w = (char*)d_ws;
    auto alloc = [&](size_t bytes) {
        void* p = (void*)w;
        w += (bytes + 255) & ~(size_t)255;
        return p;
    };
    int*    off      = (int*)alloc((size_t)(NV + 1) * 4);
    float*  inv_sqrt = (float*)alloc((size_t)NV * 4);
    int*    bucket_count  = (int*)alloc((size_t)NBUCK * CPAD * 4);
    int*    bucket_base   = (int*)alloc((size_t)(NBUCK + 1) * 4);
    int*    bucket_cursor = (int*)alloc((size_t)NBUCK * CPAD * 4);
    ushort* csr_src  = (ushort*)alloc((size_t)NE * 2);
    unsigned* bucket_rec = (unsigned*)alloc((size_t)NE * 4);
    ushort* W1T_h    = (ushort*)alloc((size_t)NG * NDP * 2);
    ushort* W1T_l    = (ushort*)alloc((size_t)NG * NDP * 2);
    ushort* W2T_h    = (ushort*)alloc((size_t)NG * NG * 2);
    ushort* W2T_l    = (ushort*)alloc((size_t)NG * NG * 2);
    unsigned char* h1f8 = (unsigned char*)alloc((size_t)NV * NG);
    _Float16* x1     = (_Float16*)alloc((size_t)NV * NG * 2);
    float*  y        = (float*)alloc((size_t)NBS * NG * 4);

    hipMemsetAsync(bucket_count, 0, (size_t)NBUCK * CPAD * 4, stream);

    splitw_all<<<(NG * NDP + NG * NG + 255) / 256, 256, 0, stream>>>(W1, W2, W1T_h, W1T_l,
                                                                     W2T_h, W2T_l);
    hist_bucket<<<1024, 256, 0, stream>>>(ei + NE, bucket_count);
    bucket_scan<<<1, 256, 0, stream>>>(bucket_count, bucket_base, bucket_cursor);
    // fused: gemm1 (h1 = emb@W1 -> fp8) ∥ bucket_scatter
    gemm1_scatter<<<GEMM1_BLOCKS + NBUCK, 256, 0, stream>>>(emb, W1T_h, W1T_l, h1f8,
                                                            ei, bucket_cursor, bucket_rec);
    csr_build<<<NBUCK, 256, 0, stream>>>(bucket_rec, bucket_base, off, inv_sqrt, csr_src);

    // x1 = relu(norm-agg(h1) + b1)  (fp16 out)
    agg1_kernel<<<(NV + 3) / 4, 256, 0, stream>>>(h1f8, off, csr_src, inv_sqrt, b1, x1);
    // y = norm-agg(x1) at word positions (fp32)
    agg2_kernel<<<(NBS + 3) / 4, 256, 0, stream>>>(x1, off, csr_src, inv_sqrt, wid, y);
    // out = y @ W2 + b2  (fp32)
    {
        dim3 grid((NBS + 127) / 128, NG / 128);
        gemm_out<<<grid, 256, 0, stream>>>(y, NG, W2T_h, W2T_l, NG,
                                           NBS, NG, NG, out, b2);
    }
}

// Round 12
// 191.485 us; speedup vs baseline: 3.9780x; 1.0289x over previous
//
#include <hip/hip_runtime.h>
#include <hip/hip_bf16.h>

#define NV 50000
#define ND 300
#define NDP 320      // K of layer-1 padded to multiple of 32
#define NG 256
#define NE 1600000
#define NBS 4096     // B*S
#define NBUCK 196    // ceil(50000/256) buckets of 256 nodes (dst>>8)
#define EPB 8192     // edges per block in bucket_scatter
#define CPAD 16      // bucket counter pad: 16 ints = 64 B line per counter
#define GEMM1_BLOCKS 782   // ceil(50000/128) * (256/128)
// prep kernel block ranges
#define PREP_W1 320        // NG*NDP/256
#define PREP_W2 256        // NG*NG/256
#define PREP_HIST 1024

typedef short short8 __attribute__((ext_vector_type(8)));
typedef float f32x4 __attribute__((ext_vector_type(4)));
typedef float f32x2 __attribute__((ext_vector_type(2)));
typedef _Float16 half4 __attribute__((ext_vector_type(4)));

__device__ __forceinline__ ushort f2bf(float f) {
    unsigned u = __builtin_bit_cast(unsigned, f);
    unsigned r = (u + 0x7fffu + ((u >> 16) & 1u)) >> 16;
    return (ushort)r;
}
__device__ __forceinline__ float bf2f(ushort h) {
    unsigned u = ((unsigned)h) << 16;
    return __builtin_bit_cast(float, u);
}

// ===== PREP (fused): W1 transpose+split ∥ W2 transpose+split ∥ bucket histogram =====
__global__ __launch_bounds__(256) void prep_kernel(const float* __restrict__ W1,
                                                   const float* __restrict__ W2,
                                                   ushort* __restrict__ W1Th,
                                                   ushort* __restrict__ W1Tl,
                                                   ushort* __restrict__ W2Th,
                                                   ushort* __restrict__ W2Tl,
                                                   const int* __restrict__ dst,
                                                   int* __restrict__ bucket_count) {
    int t = threadIdx.x;
    if (blockIdx.x < PREP_W1) {
        int idx = blockIdx.x * 256 + t;       // < NG*NDP
        int n = idx / NDP, k = idx - n * NDP;
        float v = (k < ND) ? W1[(size_t)k * NG + n] : 0.f;
        ushort h = f2bf(v);
        W1Th[idx] = h;
        W1Tl[idx] = f2bf(v - bf2f(h));
    } else if (blockIdx.x < PREP_W1 + PREP_W2) {
        int j = (blockIdx.x - PREP_W1) * 256 + t;  // < NG*NG
        int n = j / NG, k = j - n * NG;
        float v = W2[(size_t)k * NG + n];
        ushort h = f2bf(v);
        W2Th[j] = h;
        W2Tl[j] = f2bf(v - bf2f(h));
    } else {
        __shared__ int bh[NBUCK];
        for (int b = t; b < NBUCK; b += 256) bh[b] = 0;
        __syncthreads();
        int blk = blockIdx.x - (PREP_W1 + PREP_W2);
        for (int i = blk * 256 + t; i * 4 < NE; i += PREP_HIST * 256) {
            int4 d = *(const int4*)(dst + i * 4);
            atomicAdd(&bh[d.x >> 8], 1);
            atomicAdd(&bh[d.y >> 8], 1);
            atomicAdd(&bh[d.z >> 8], 1);
            atomicAdd(&bh[d.w >> 8], 1);
        }
        __syncthreads();
        for (int b = t; b < NBUCK; b += 256)
            if (bh[b]) atomicAdd(&bucket_count[b * CPAD], bh[b]);
    }
}

// ------- bucket scan: one block, Hillis-Steele over 196 padded counts -------
__global__ __launch_bounds__(256) void bucket_scan(const int* __restrict__ bucket_count,
                                                   int* __restrict__ bucket_base,
                                                   int* __restrict__ bucket_cursor) {
    __shared__ int s[256];
    int t = threadIdx.x;
    int v = (t < NBUCK) ? bucket_count[t * CPAD] : 0;
    s[t] = v;
    __syncthreads();
    for (int d = 1; d < 256; d <<= 1) {
        int x = (t >= d) ? s[t - d] : 0;
        __syncthreads();
        s[t] += x;
        __syncthreads();
    }
    int excl = s[t] - v;
    if (t < NBUCK) {
        bucket_base[t] = excl;
        bucket_cursor[t * CPAD] = excl;
    }
    if (t == 255) bucket_base[NBUCK] = s[255];  // = NE
}

// ===== FUSED: gemm1 (h1 = emb@W1 -> fp8, single bf16 pass) ∥ bucket_scatter =====
// gemm1 block mapping: bm = bid>>1 (A-tile pairs adjacent -> L2/L3 reuse), bn = bid&1.
__global__ __launch_bounds__(256) void gemm1_scatter(const float* __restrict__ A,   // emb
                                                     const ushort* __restrict__ BTh,
                                                     unsigned char* __restrict__ C8,
                                                     const int* __restrict__ ei,
                                                     int* __restrict__ bucket_cursor,
                                                     unsigned* __restrict__ rec) {
    int t = threadIdx.x;
    if (blockIdx.x < GEMM1_BLOCKS) {
        __shared__ short Ah[128][40];
        __shared__ short Bh[128][40];
        const int lda = ND, ldb = NDP, M = NV, K = ND, KP = NDP;
        int bid = blockIdx.x;
        int bm = (bid >> 1) * 128;
        int bn = (bid & 1) * 128;
        int lane = t & 63, wv = t >> 6;
        int wm = (wv >> 1) * 64, wn = (wv & 1) * 64;
        int srow = t >> 1;
        int skq = (t & 1) * 16;
        f32x4 acc[4][4];
#pragma unroll
        for (int mi = 0; mi < 4; ++mi)
#pragma unroll
            for (int ni = 0; ni < 4; ++ni) acc[mi][ni] = (f32x4)0.0f;

        for (int k0 = 0; k0 < KP; k0 += 32) {
            int gk = k0 + skq;
            {
                int gr = bm + srow;
                short va[16];
                float v[16];
                if (gr < M && gk < K) {
                    if (gk + 16 <= K) {
#pragma unroll
                        for (int q = 0; q < 4; ++q) {
                            float4 p = *(const float4*)(A + (size_t)gr * lda + gk + q * 4);
                            v[q * 4 + 0] = p.x; v[q * 4 + 1] = p.y;
                            v[q * 4 + 2] = p.z; v[q * 4 + 3] = p.w;
                        }
                    } else {
#pragma unroll
                        for (int e = 0; e < 16; ++e)
                            v[e] = (gk + e < K) ? A[(size_t)gr * lda + gk + e] : 0.f;
                    }
                } else {
#pragma unroll
                    for (int e = 0; e < 16; ++e) v[e] = 0.f;
                }
#pragma unroll
                for (int e = 0; e < 16; ++e) va[e] = (short)f2bf(v[e]);
                *(short8*)&Ah[srow][skq] = *(short8*)&va[0];
                *(short8*)&Ah[srow][skq + 8] = *(short8*)&va[8];
            }
            {
                int nr = bn + srow;
                short8 bh0 = *(const short8*)(BTh + (size_t)nr * ldb + gk);
                short8 bh1 = *(const short8*)(BTh + (size_t)nr * ldb + gk + 8);
                *(short8*)&Bh[srow][skq] = bh0;
                *(short8*)&Bh[srow][skq + 8] = bh1;
            }
            __syncthreads();
            int m16 = lane & 15, kb = (lane >> 4) * 8;
            short8 a_h[4], b_h[4];
#pragma unroll
            for (int mi = 0; mi < 4; ++mi)
                a_h[mi] = *(const short8*)&Ah[wm + mi * 16 + m16][kb];
#pragma unroll
            for (int ni = 0; ni < 4; ++ni)
                b_h[ni] = *(const short8*)&Bh[wn + ni * 16 + m16][kb];
#pragma unroll
            for (int mi = 0; mi < 4; ++mi)
#pragma unroll
                for (int ni = 0; ni < 4; ++ni)
                    acc[mi][ni] = __builtin_amdgcn_mfma_f32_16x16x32_bf16(a_h[mi], b_h[ni], acc[mi][ni], 0, 0, 0);
            __syncthreads();
        }
        int m16 = lane & 15, rq = lane >> 4;
#pragma unroll
        for (int mi = 0; mi < 4; ++mi)
#pragma unroll
            for (int ni = 0; ni < 4; ++ni) {
                int row0 = bm + wm + mi * 16 + rq * 4;
                int col = bn + wn + ni * 16 + m16;
                int p01 = __builtin_amdgcn_cvt_pk_fp8_f32(acc[mi][ni][0], acc[mi][ni][1], 0, false);
                int p23 = __builtin_amdgcn_cvt_pk_fp8_f32(acc[mi][ni][2], acc[mi][ni][3], 0, false);
                if (row0 + 0 < M) C8[(size_t)(row0 + 0) * NG + col] = (unsigned char)(p01 & 0xff);
                if (row0 + 1 < M) C8[(size_t)(row0 + 1) * NG + col] = (unsigned char)((p01 >> 8) & 0xff);
                if (row0 + 2 < M) C8[(size_t)(row0 + 2) * NG + col] = (unsigned char)(p23 & 0xff);
                if (row0 + 3 < M) C8[(size_t)(row0 + 3) * NG + col] = (unsigned char)((p23 >> 8) & 0xff);
            }
    } else {
        // ---------------- scatter part: edges -> coarse dst-buckets, 4 B records ----------------
        __shared__ int cnt[NBUCK];
        __shared__ int basel[NBUCK];
        int e0 = (blockIdx.x - GEMM1_BLOCKS) * EPB;
        for (int b = t; b < NBUCK; b += 256) cnt[b] = 0;
        __syncthreads();
        for (int q = 0; q < EPB / 1024; ++q) {
            int i4 = e0 + q * 1024 + t * 4;
            if (i4 < NE) {
                int4 d = *(const int4*)(ei + NE + i4);
                atomicAdd(&cnt[d.x >> 8], 1);
                atomicAdd(&cnt[d.y >> 8], 1);
                atomicAdd(&cnt[d.z >> 8], 1);
                atomicAdd(&cnt[d.w >> 8], 1);
            }
        }
        __syncthreads();
        for (int b = t; b < NBUCK; b += 256) {
            int c = cnt[b];
            basel[b] = c ? atomicAdd(&bucket_cursor[b * CPAD], c) : 0;
        }
        __syncthreads();
        for (int b = t; b < NBUCK; b += 256) cnt[b] = 0;
        __syncthreads();
        for (int q = 0; q < EPB / 1024; ++q) {
            int i4 = e0 + q * 1024 + t * 4;
            if (i4 < NE) {
                int4 s = *(const int4*)(ei + i4);
                int4 d = *(const int4*)(ei + NE + i4);
                int b0 = d.x >> 8, b1 = d.y >> 8, b2 = d.z >> 8, b3 = d.w >> 8;
                int r0 = atomicAdd(&cnt[b0], 1);
                rec[basel[b0] + r0] = (unsigned)s.x | ((unsigned)(d.x & 255) << 16);
                int r1 = atomicAdd(&cnt[b1], 1);
                rec[basel[b1] + r1] = (unsigned)s.y | ((unsigned)(d.y & 255) << 16);
                int r2 = atomicAdd(&cnt[b2], 1);
                rec[basel[b2] + r2] = (unsigned)s.z | ((unsigned)(d.z & 255) << 16);
                int r3 = atomicAdd(&cnt[b3], 1);
                rec[basel[b3] + r3] = (unsigned)s.w | ((unsigned)(d.w & 255) << 16);
            }
        }
    }
}

// ------- per bucket — LDS degree count + scan + place (fused) -------
__global__ __launch_bounds__(256) void csr_build(const unsigned* __restrict__ rec,
                                                 const int* __restrict__ bucket_base,
                                                 int* __restrict__ off,
                                                 float* __restrict__ inv_sqrt,
                                                 ushort* __restrict__ csr_src) {
    __shared__ int degl[256];
    __shared__ int s[256];
    int b = blockIdx.x, t = threadIdx.x;
    degl[t] = 0;
    __syncthreads();
    int r0 = bucket_base[b], r1 = bucket_base[b + 1];
    for (int i = r0 + t; i < r1; i += 256)
        atomicAdd(&degl[(rec[i] >> 16) & 255], 1);
    __syncthreads();
    int v = degl[t];
    s[t] = v;
    __syncthreads();
    for (int d = 1; d < 256; d <<= 1) {
        int x = (t >= d) ? s[t - d] : 0;
        __syncthreads();
        s[t] += x;
        __syncthreads();
    }
    int excl = s[t] - v + r0;
    int n = (b << 8) + t;
    if (n < NV) {
        off[n] = excl;
        inv_sqrt[n] = rsqrtf((float)(v + 1));  // deg = 1 (self loop) + in-degree
    }
    if (b == NBUCK - 1 && t == 0) off[NV] = NE;
    __syncthreads();
    degl[t] = excl;  // reuse as cursor
    __syncthreads();
    for (int i = r0 + t; i < r1; i += 256) {
        unsigned e = rec[i];
        int p = atomicAdd(&degl[(e >> 16) & 255], 1);
        csr_src[p] = (ushort)(e & 0xffff);
    }
}

// ---- standalone MFMA GEMM (out = y @ W2 + b2), 2-pass split for accuracy ----
__global__ __launch_bounds__(256) void gemm_out(const float* __restrict__ A,
                                                int lda,
                                                const ushort* __restrict__ BTh,
                                                const ushort* __restrict__ BTl,
                                                int ldb,
                                                int M, int K, int KP,
                                                float* __restrict__ C32,
                                                const float* __restrict__ bias) {
    __shared__ short Ah[128][40];
    __shared__ short Bh[128][40];
    __shared__ short Bl[128][40];
    int t = threadIdx.x;
    int bm = blockIdx.x * 128;
    int bn = blockIdx.y * 128;
    int lane = t & 63, wv = t >> 6;
    int wm = (wv >> 1) * 64, wn = (wv & 1) * 64;
    int srow = t >> 1;
    int skq = (t & 1) * 16;
    f32x4 acc[4][4];
#pragma unroll
    for (int mi = 0; mi < 4; ++mi)
#pragma unroll
        for (int ni = 0; ni < 4; ++ni) acc[mi][ni] = (f32x4)0.0f;

    for (int k0 = 0; k0 < KP; k0 += 32) {
        int gk = k0 + skq;
        {
            int gr = bm + srow;
            short va[16];
            float v[16];
            if (gr < M && gk < K) {
#pragma unroll
                for (int q = 0; q < 4; ++q) {
                    float4 p = *(const float4*)(A + (size_t)gr * lda + gk + q * 4);
                    v[q * 4 + 0] = p.x; v[q * 4 + 1] = p.y;
                    v[q * 4 + 2] = p.z; v[q * 4 + 3] = p.w;
                }
            } else {
#pragma unroll
                for (int e = 0; e < 16; ++e) v[e] = 0.f;
            }
#pragma unroll
            for (int e = 0; e < 16; ++e) va[e] = (short)f2bf(v[e]);
            *(short8*)&Ah[srow][skq] = *(short8*)&va[0];
            *(short8*)&Ah[srow][skq + 8] = *(short8*)&va[8];
        }
        {
            int nr = bn + srow;
            short8 bh0 = *(const short8*)(BTh + (size_t)nr * ldb + gk);
            short8 bh1 = *(const short8*)(BTh + (size_t)nr * ldb + gk + 8);
            short8 bl0 = *(const short8*)(BTl + (size_t)nr * ldb + gk);
            short8 bl1 = *(const short8*)(BTl + (size_t)nr * ldb + gk + 8);
            *(short8*)&Bh[srow][skq] = bh0;
            *(short8*)&Bh[srow][skq + 8] = bh1;
            *(short8*)&Bl[srow][skq] = bl0;
            *(short8*)&Bl[srow][skq + 8] = bl1;
        }
        __syncthreads();
        int m16 = lane & 15, kb = (lane >> 4) * 8;
        short8 a_h[4], b_h[4], b_l[4];
#pragma unroll
        for (int mi = 0; mi < 4; ++mi)
            a_h[mi] = *(const short8*)&Ah[wm + mi * 16 + m16][kb];
#pragma unroll
        for (int ni = 0; ni < 4; ++ni) {
            b_h[ni] = *(const short8*)&Bh[wn + ni * 16 + m16][kb];
            b_l[ni] = *(const short8*)&Bl[wn + ni * 16 + m16][kb];
        }
#pragma unroll
        for (int mi = 0; mi < 4; ++mi)
#pragma unroll
            for (int ni = 0; ni < 4; ++ni) {
                acc[mi][ni] = __builtin_amdgcn_mfma_f32_16x16x32_bf16(a_h[mi], b_h[ni], acc[mi][ni], 0, 0, 0);
                acc[mi][ni] = __builtin_amdgcn_mfma_f32_16x16x32_bf16(a_h[mi], b_l[ni], acc[mi][ni], 0, 0, 0);
            }
        __syncthreads();
    }
    int m16 = lane & 15, rq = lane >> 4;
#pragma unroll
    for (int mi = 0; mi < 4; ++mi)
#pragma unroll
        for (int ni = 0; ni < 4; ++ni) {
#pragma unroll
            for (int r = 0; r < 4; ++r) {
                int row = bm + wm + mi * 16 + rq * 4 + r;
                int col = bn + wn + ni * 16 + m16;
                if (row < M)
                    C32[(size_t)row * NG + col] = acc[mi][ni][r] + bias[col];
            }
        }
}

// ---- layer-1 agg: wave per node, unroll-16 fp8 gather (HW cvt) ----
__global__ __launch_bounds__(256) void agg1_kernel(const unsigned char* __restrict__ h1f8,
                                                   const int* __restrict__ off,
                                                   const ushort* __restrict__ csr_src,
                                                   const float* __restrict__ inv_sqrt,
                                                   const float* __restrict__ b1,
                                                   _Float16* __restrict__ x1) {
    int wv = threadIdx.x >> 6, lane = threadIdx.x & 63;
    int i = blockIdx.x * 4 + wv;
    if (i >= NV) return;
    int c4 = lane * 4;
    int s0 = off[i], s1 = off[i + 1];
    float a0 = 0.f, a1 = 0.f, a2 = 0.f, a3 = 0.f;
    int j = s0;
    for (; j + 16 <= s1; j += 16) {
        int sx[16];
        float wx[16];
        unsigned pk[16];
#pragma unroll
        for (int u = 0; u < 16; ++u) sx[u] = csr_src[j + u];
#pragma unroll
        for (int u = 0; u < 16; ++u) {
            wx[u] = inv_sqrt[sx[u]];
            pk[u] = *(const unsigned*)(h1f8 + (size_t)sx[u] * NG + c4);
        }
#pragma unroll
        for (int u = 0; u < 16; ++u) {
            f32x2 v01 = __builtin_amdgcn_cvt_pk_f32_fp8(pk[u], false);
            f32x2 v23 = __builtin_amdgcn_cvt_pk_f32_fp8(pk[u], true);
            a0 += wx[u] * v01[0];
            a1 += wx[u] * v01[1];
            a2 += wx[u] * v23[0];
            a3 += wx[u] * v23[1];
        }
    }
    for (; j + 4 <= s1; j += 4) {
        int sx[4];
        float wx[4];
        unsigned pk[4];
#pragma unroll
        for (int u = 0; u < 4; ++u) sx[u] = csr_src[j + u];
#pragma unroll
        for (int u = 0; u < 4; ++u) {
            wx[u] = inv_sqrt[sx[u]];
            pk[u] = *(const unsigned*)(h1f8 + (size_t)sx[u] * NG + c4);
        }
#pragma unroll
        for (int u = 0; u < 4; ++u) {
            f32x2 v01 = __builtin_amdgcn_cvt_pk_f32_fp8(pk[u], false);
            f32x2 v23 = __builtin_amdgcn_cvt_pk_f32_fp8(pk[u], true);
            a0 += wx[u] * v01[0];
            a1 += wx[u] * v01[1];
            a2 += wx[u] * v23[0];
            a3 += wx[u] * v23[1];
        }
    }
    for (; j < s1; ++j) {
        int s = csr_src[j];
        float w = inv_sqrt[s];
        unsigned pk = *(const unsigned*)(h1f8 + (size_t)s * NG + c4);
        f32x2 v01 = __builtin_amdgcn_cvt_pk_f32_fp8(pk, false);
        f32x2 v23 = __builtin_amdgcn_cvt_pk_f32_fp8(pk, true);
        a0 += w * v01[0];
        a1 += w * v01[1];
        a2 += w * v23[0];
        a3 += w * v23[1];
    }
    float is = inv_sqrt[i], is2 = is * is;
    unsigned pks = *(const unsigned*)(h1f8 + (size_t)i * NG + c4);
    f32x2 s01 = __builtin_amdgcn_cvt_pk_f32_fp8(pks, false);
    f32x2 s23 = __builtin_amdgcn_cvt_pk_f32_fp8(pks, true);
    float4 bb = *(const float4*)(b1 + c4);
    half4 o;
    o[0] = (_Float16)fmaxf(is * a0 + s01[0] * is2 + bb.x, 0.f);
    o[1] = (_Float16)fmaxf(is * a1 + s01[1] * is2 + bb.y, 0.f);
    o[2] = (_Float16)fmaxf(is * a2 + s23[0] * is2 + bb.z, 0.f);
    o[3] = (_Float16)fmaxf(is * a3 + s23[1] * is2 + bb.w, 0.f);
    *(half4*)(x1 + (size_t)i * NG + c4) = o;
}

// ---- layer-2 agg on x1 at word positions only (W2 deferred), unroll-16 ----
__global__ __launch_bounds__(256) void agg2_kernel(const _Float16* __restrict__ x1,
                                                   const int* __restrict__ off,
                                                   const ushort* __restrict__ csr_src,
                                                   const float* __restrict__ inv_sqrt,
                                                   const int* __restrict__ word_ids,
                                                   float* __restrict__ y) {
    int wv = threadIdx.x >> 6, lane = threadIdx.x & 63;
    int p = blockIdx.x * 4 + wv;
    if (p >= NBS) return;
    int n = word_ids[p];
    int c4 = lane * 4;
    int s0 = off[n], s1 = off[n + 1];
    float a0 = 0.f, a1 = 0.f, a2 = 0.f, a3 = 0.f;
    int j = s0;
    for (; j + 16 <= s1; j += 16) {
        int sx[16];
        float wx[16];
        half4 vx[16];
#pragma unroll
        for (int u = 0; u < 16; ++u) sx[u] = csr_src[j + u];
#pragma unroll
        for (int u = 0; u < 16; ++u) {
            wx[u] = inv_sqrt[sx[u]];
            vx[u] = *(const half4*)(x1 + (size_t)sx[u] * NG + c4);
        }
#pragma unroll
        for (int u = 0; u < 16; ++u) {
            a0 += wx[u] * (float)vx[u][0];
            a1 += wx[u] * (float)vx[u][1];
            a2 += wx[u] * (float)vx[u][2];
            a3 += wx[u] * (float)vx[u][3];
        }
    }
    for (; j + 4 <= s1; j += 4) {
        int sx[4];
        float wx[4];
        half4 vx[4];
#pragma unroll
        for (int u = 0; u < 4; ++u) sx[u] = csr_src[j + u];
#pragma unroll
        for (int u = 0; u < 4; ++u) {
            wx[u] = inv_sqrt[sx[u]];
            vx[u] = *(const half4*)(x1 + (size_t)sx[u] * NG + c4);
        }
#pragma unroll
        for (int u = 0; u < 4; ++u) {
            a0 += wx[u] * (float)vx[u][0];
            a1 += wx[u] * (float)vx[u][1];
            a2 += wx[u] * (float)vx[u][2];
            a3 += wx[u] * (float)vx[u][3];
        }
    }
    for (; j < s1; ++j) {
        int s = csr_src[j];
        float w = inv_sqrt[s];
        half4 hv = *(const half4*)(x1 + (size_t)s * NG + c4);
        a0 += w * (float)hv[0];
        a1 += w * (float)hv[1];
        a2 += w * (float)hv[2];
        a3 += w * (float)hv[3];
    }
    float is = inv_sqrt[n], is2 = is * is;
    half4 sv = *(const half4*)(x1 + (size_t)n * NG + c4);
    float4 o;
    o.x = is * a0 + (float)sv[0] * is2;
    o.y = is * a1 + (float)sv[1] * is2;
    o.z = is * a2 + (float)sv[2] * is2;
    o.w = is * a3 + (float)sv[3] * is2;
    *(float4*)(y + (size_t)p * NG + c4) = o;
}

extern "C" void kernel_launch(void* const* d_in, const int* in_sizes, int n_in,
                              void* d_out, int out_size, void* d_ws, size_t ws_size,
                              hipStream_t stream) {
    const float* emb = (const float*)d_in[0];       // V x D
    const float* W1  = (const float*)d_in[1];       // D x G
    const float* b1  = (const float*)d_in[2];       // G
    const float* W2  = (const float*)d_in[3];       // G x G
    const float* b2  = (const float*)d_in[4];       // G
    const int*   ei  = (const int*)d_in[5];         // 2 x E
    const int*   wid = (const int*)d_in[6];         // B x S
    float* out = (float*)d_out;

    char* w = (char*)d_ws;
    auto alloc = [&](size_t bytes) {
        void* p = (void*)w;
        w += (bytes + 255) & ~(size_t)255;
        return p;
    };
    int*    off      = (int*)alloc((size_t)(NV + 1) * 4);
    float*  inv_sqrt = (float*)alloc((size_t)NV * 4);
    int*    bucket_count  = (int*)alloc((size_t)NBUCK * CPAD * 4);
    int*    bucket_base   = (int*)alloc((size_t)(NBUCK + 1) * 4);
    int*    bucket_cursor = (int*)alloc((size_t)NBUCK * CPAD * 4);
    ushort* csr_src  = (ushort*)alloc((size_t)NE * 2);
    unsigned* bucket_rec = (unsigned*)alloc((size_t)NE * 4);
    ushort* W1T_h    = (ushort*)alloc((size_t)NG * NDP * 2);
    ushort* W1T_l    = (ushort*)alloc((size_t)NG * NDP * 2);
    ushort* W2T_h    = (ushort*)alloc((size_t)NG * NG * 2);
    ushort* W2T_l    = (ushort*)alloc((size_t)NG * NG * 2);
    unsigned char* h1f8 = (unsigned char*)alloc((size_t)NV * NG);
    _Float16* x1     = (_Float16*)alloc((size_t)NV * NG * 2);
    float*  y        = (float*)alloc((size_t)NBS * NG * 4);

    hipMemsetAsync(bucket_count, 0, (size_t)NBUCK * CPAD * 4, stream);

    // prep: W1/W2 transpose+split ∥ bucket histogram (fused)
    prep_kernel<<<PREP_W1 + PREP_W2 + PREP_HIST, 256, 0, stream>>>(
        W1, W2, W1T_h, W1T_l, W2T_h, W2T_l, ei + NE, bucket_count);
    bucket_scan<<<1, 256, 0, stream>>>(bucket_count, bucket_base, bucket_cursor);
    // fused: gemm1 (h1 = emb@W1 -> fp8, single-pass) ∥ bucket_scatter
    gemm1_scatter<<<GEMM1_BLOCKS + NBUCK, 256, 0, stream>>>(emb, W1T_h, h1f8,
                                                            ei, bucket_cursor, bucket_rec);
    csr_build<<<NBUCK, 256, 0, stream>>>(bucket_rec, bucket_base, off, inv_sqrt, csr_src);

    // x1 = relu(norm-agg(h1) + b1)  (fp16 out)
    agg1_kernel<<<(NV + 3) / 4, 256, 0, stream>>>(h1f8, off, csr_src, inv_sqrt, b1, x1);
    // y = norm-agg(x1) at word positions (fp32)
    agg2_kernel<<<(NBS + 3) / 4, 256, 0, stream>>>(x1, off, csr_src, inv_sqrt, wid, y);
    // out = y @ W2 + b2  (fp32)
    {
        dim3 grid((NBS + 127) / 128, NG / 128);
        gemm_out<<<grid, 256, 0, stream>>>(y, NG, W2T_h, W2T_l, NG,
                                           NBS, NG, NG, out, b2);
    }
}